// Round 1
// baseline (3604.248 us; speedup 1.0000x reference)
//
#include <hip/hip_runtime.h>
#include <cstdint>

#define COMP4(v, c) ((c) == 0 ? (v).x : (c) == 1 ? (v).y : (c) == 2 ? (v).z : (v).w)

// ---------------- prep: softmax(rel) folded into combined weights ----------------
// W0c: [2][384][128]  (side 0=tx, 1=addr; rows 0-127: rw*Wl[tA]; 128-255: rw*Wl[tB];
//                      256-383: rw*Wr[tA]+rw*Wr[tB])
// b0c: [2][128]
// P:   [2][128][6]    (cols 0-1: rw1*Wl1[aggA]; 2-3: rw1*Wl1[srcB]; 4-5: combined Wr1)
// b1c: [2][2]
__global__ void k_prep(const float* __restrict__ Wl0, const float* __restrict__ bl0,
                       const float* __restrict__ Wr0, const float* __restrict__ rel0,
                       const float* __restrict__ Wl1, const float* __restrict__ bl1,
                       const float* __restrict__ Wr1, const float* __restrict__ rel1,
                       float* __restrict__ W0c, float* __restrict__ b0c,
                       float* __restrict__ P, float* __restrict__ b1c)
{
    float rw0[4], rw1[4];
    {
        float m0 = fmaxf(fmaxf(rel0[0], rel0[1]), fmaxf(rel0[2], rel0[3]));
        float m1 = fmaxf(fmaxf(rel1[0], rel1[1]), fmaxf(rel1[2], rel1[3]));
        float s0 = 0.f, s1 = 0.f;
        #pragma unroll
        for (int c = 0; c < 4; ++c) {
            rw0[c] = expf(rel0[c] - m0); s0 += rw0[c];
            rw1[c] = expf(rel1[c] - m1); s1 += rw1[c];
        }
        #pragma unroll
        for (int c = 0; c < 4; ++c) { rw0[c] /= s0; rw1[c] /= s1; }
    }
    const int i = blockIdx.x * blockDim.x + threadIdx.x;
    const int NW = 2 * 384 * 128;
    if (i < NW) {
        int side = i / (384 * 128);
        int rem  = i % (384 * 128);
        int row = rem / 128, col = rem % 128;
        int tA = side ? 1 : 0, tB = side ? 3 : 2;
        float v;
        if (row < 128)      v = rw0[tA] * Wl0[tA * 16384 + row * 128 + col];
        else if (row < 256) v = rw0[tB] * Wl0[tB * 16384 + (row - 128) * 128 + col];
        else                v = rw0[tA] * Wr0[tA * 16384 + (row - 256) * 128 + col]
                              + rw0[tB] * Wr0[tB * 16384 + (row - 256) * 128 + col];
        W0c[i] = v;
    } else if (i < NW + 256) {
        int ib = i - NW;
        int side = ib / 128, col = ib % 128;
        int tA = side ? 1 : 0, tB = side ? 3 : 2;
        b0c[ib] = rw0[tA] * bl0[tA * 128 + col] + rw0[tB] * bl0[tB * 128 + col];
    } else if (i < NW + 256 + 1536) {
        int ip = i - (NW + 256);
        int side = ip / 768, rem = ip % 768;
        int k = rem / 6, c = rem % 6;
        float v;
        if (side == 0) {
            if (c < 2)      v = rw1[0] * Wl1[0 * 256 + k * 2 + c];
            else if (c < 4) v = rw1[3] * Wl1[3 * 256 + k * 2 + (c - 2)];
            else            v = rw1[0] * Wr1[0 * 256 + k * 2 + (c - 4)]
                              + rw1[2] * Wr1[2 * 256 + k * 2 + (c - 4)];
        } else {
            if (c < 2)      v = rw1[1] * Wl1[1 * 256 + k * 2 + c];
            else if (c < 4) v = rw1[2] * Wl1[2 * 256 + k * 2 + (c - 2)];
            else            v = rw1[1] * Wr1[1 * 256 + k * 2 + (c - 4)]
                              + rw1[3] * Wr1[3 * 256 + k * 2 + (c - 4)];
        }
        P[ip] = v;
    } else if (i < NW + 256 + 1536 + 4) {
        int i4 = i - (NW + 256 + 1536);
        int side = i4 / 2, c = i4 % 2;
        b1c[i4] = side ? (rw1[1] * bl1[1 * 2 + c] + rw1[3] * bl1[3 * 2 + c])
                       : (rw1[0] * bl1[0 * 2 + c] + rw1[2] * bl1[2 * 2 + c]);
    }
}

// ---------------- CSR build ----------------
__global__ void k_hist(const int* __restrict__ dst, int* __restrict__ cnt, int E)
{
    int i = blockIdx.x * blockDim.x + threadIdx.x;
    if (i < E) atomicAdd(&cnt[dst[i]], 1);
}

__global__ void k_scan(const int* __restrict__ cnt, int* __restrict__ off,
                       int Nmax, int N_tx, int N_ad)
{
    const int t = blockIdx.x;
    const int N = (t & 1) ? N_ad : N_tx;
    cnt += (size_t)t * Nmax;
    off += (size_t)t * (Nmax + 1);
    const int tid = threadIdx.x;
    const int lane = tid & 63, wv = tid >> 6;
    __shared__ int wtot[16];
    __shared__ int woff[16];
    __shared__ int running;
    if (tid == 0) running = 0;
    __syncthreads();
    for (int base = 0; base < N; base += 1024) {
        int i = base + tid;
        int v = (i < N) ? cnt[i] : 0;
        int incl = v;
        #pragma unroll
        for (int s = 1; s < 64; s <<= 1) {
            int u = __shfl_up(incl, s, 64);
            if (lane >= s) incl += u;
        }
        if (lane == 63) wtot[wv] = incl;
        __syncthreads();
        if (tid == 0) {
            int r = running;
            #pragma unroll
            for (int w = 0; w < 16; ++w) { woff[w] = r; r += wtot[w]; }
            running = r;
        }
        __syncthreads();
        if (i < N) off[i] = woff[wv] + incl - v;
    }
    __syncthreads();
    if (tid == 0) off[N] = running;
}

__global__ void k_fill(const int* __restrict__ src, const int* __restrict__ dst,
                       const int* __restrict__ off, int* __restrict__ cur,
                       int* __restrict__ lst, int E)
{
    int i = blockIdx.x * blockDim.x + threadIdx.x;
    if (i < E) {
        int d = dst[i];
        int p = atomicAdd(&cur[d], 1);
        lst[off[d] + p] = src[i];
    }
}

// ---------------- mean aggregation over 128-dim features: 1 wave per dst ----------------
__global__ void k_agg_mean128(const float* __restrict__ x,
                              const int* __restrict__ off,
                              const int* __restrict__ lst,
                              float* __restrict__ buf, int N)
{
    const int wv = threadIdx.x >> 6;
    const int lane = threadIdx.x & 63;
    const int node = blockIdx.x * 4 + wv;
    if (node >= N) return;
    const int s0 = off[node], s1 = off[node + 1];
    const int d = lane * 2;
    float ax = 0.f, ay = 0.f, bx = 0.f, by = 0.f;
    int e = s0;
    for (; e + 2 <= s1; e += 2) {
        int sA = lst[e], sB = lst[e + 1];
        float2 vA = *reinterpret_cast<const float2*>(&x[(size_t)sA * 128 + d]);
        float2 vB = *reinterpret_cast<const float2*>(&x[(size_t)sB * 128 + d]);
        ax += vA.x; ay += vA.y; bx += vB.x; by += vB.y;
    }
    if (e < s1) {
        int sA = lst[e];
        float2 vA = *reinterpret_cast<const float2*>(&x[(size_t)sA * 128 + d]);
        ax += vA.x; ay += vA.y;
    }
    const int deg = s1 - s0;
    const float sc = 1.0f / (float)(deg > 0 ? deg : 1);
    float2 o; o.x = (ax + bx) * sc; o.y = (ay + by) * sc;
    *reinterpret_cast<float2*>(&buf[(size_t)node * 128 + d]) = o;
}

// ---------------- node update: out[n][0:128] (+)= in0[n]@W0 (+ in1[n]@W1) (+bias)(relu) ----
// 128 nodes/block, 256 threads: thread -> (node nl, nl+64) x 32 j's. W staged in LDS (64KB).
__global__ __launch_bounds__(256, 2) void k_node_mm(
    const float* __restrict__ in0, const float* __restrict__ W0,
    const float* __restrict__ in1, const float* __restrict__ W1,
    const float* __restrict__ bias, float* __restrict__ out,
    int N, int accum, int relu)
{
    __shared__ float Ws[128][128];
    const int t = threadIdx.x;
    const int base = blockIdx.x * 128;
    const int nl = t >> 2;
    const int jg = t & 3;
    const int n0 = base + nl;
    const int n1 = base + nl + 64;

    float acc0[32], acc1[32];
    #pragma unroll
    for (int i = 0; i < 32; ++i) { acc0[i] = 0.f; acc1[i] = 0.f; }

    #pragma unroll 1
    for (int ii = 0; ii < 2; ++ii) {
        const float* inp = ii ? in1 : in0;
        const float* W   = ii ? W1 : W0;
        if (inp == nullptr) break;
        __syncthreads();
        #pragma unroll
        for (int q = 0; q < 16; ++q) {
            int f = q * 256 + t;          // coalesced float4 staging
            int r = f >> 5, c4 = f & 31;
            *reinterpret_cast<float4*>(&Ws[r][c4 * 4]) =
                *reinterpret_cast<const float4*>(&W[r * 128 + c4 * 4]);
        }
        __syncthreads();
        #pragma unroll 1
        for (int kc = 0; kc < 4; ++kc) {
            float4 xv0[8], xv1[8];
            #pragma unroll
            for (int q = 0; q < 8; ++q) {
                xv0[q] = (n0 < N)
                    ? *reinterpret_cast<const float4*>(&inp[(size_t)n0 * 128 + kc * 32 + q * 4])
                    : make_float4(0.f, 0.f, 0.f, 0.f);
                xv1[q] = (n1 < N)
                    ? *reinterpret_cast<const float4*>(&inp[(size_t)n1 * 128 + kc * 32 + q * 4])
                    : make_float4(0.f, 0.f, 0.f, 0.f);
            }
            #pragma unroll
            for (int q = 0; q < 8; ++q) {
                #pragma unroll
                for (int c = 0; c < 4; ++c) {
                    const int k = kc * 32 + q * 4 + c;
                    const float a0 = COMP4(xv0[q], c);
                    const float a1 = COMP4(xv1[q], c);
                    #pragma unroll
                    for (int jj = 0; jj < 8; ++jj) {
                        const float4 w = *reinterpret_cast<const float4*>(&Ws[k][jg * 4 + jj * 16]);
                        acc0[jj * 4 + 0] += a0 * w.x; acc0[jj * 4 + 1] += a0 * w.y;
                        acc0[jj * 4 + 2] += a0 * w.z; acc0[jj * 4 + 3] += a0 * w.w;
                        acc1[jj * 4 + 0] += a1 * w.x; acc1[jj * 4 + 1] += a1 * w.y;
                        acc1[jj * 4 + 2] += a1 * w.z; acc1[jj * 4 + 3] += a1 * w.w;
                    }
                }
            }
        }
    }

    if (n0 < N) {
        #pragma unroll
        for (int jj = 0; jj < 8; ++jj) {
            int j = jg * 4 + jj * 16;
            float4 v = make_float4(acc0[jj * 4 + 0], acc0[jj * 4 + 1], acc0[jj * 4 + 2], acc0[jj * 4 + 3]);
            if (accum) { float4 o = *reinterpret_cast<const float4*>(&out[(size_t)n0 * 128 + j]);
                         v.x += o.x; v.y += o.y; v.z += o.z; v.w += o.w; }
            if (bias)  { float4 b = *reinterpret_cast<const float4*>(&bias[j]);
                         v.x += b.x; v.y += b.y; v.z += b.z; v.w += b.w; }
            if (relu)  { v.x = fmaxf(v.x, 0.f); v.y = fmaxf(v.y, 0.f);
                         v.z = fmaxf(v.z, 0.f); v.w = fmaxf(v.w, 0.f); }
            *reinterpret_cast<float4*>(&out[(size_t)n0 * 128 + j]) = v;
        }
    }
    if (n1 < N) {
        #pragma unroll
        for (int jj = 0; jj < 8; ++jj) {
            int j = jg * 4 + jj * 16;
            float4 v = make_float4(acc1[jj * 4 + 0], acc1[jj * 4 + 1], acc1[jj * 4 + 2], acc1[jj * 4 + 3]);
            if (accum) { float4 o = *reinterpret_cast<const float4*>(&out[(size_t)n1 * 128 + j]);
                         v.x += o.x; v.y += o.y; v.z += o.z; v.w += o.w; }
            if (bias)  { float4 b = *reinterpret_cast<const float4*>(&bias[j]);
                         v.x += b.x; v.y += b.y; v.z += b.z; v.w += b.w; }
            if (relu)  { v.x = fmaxf(v.x, 0.f); v.y = fmaxf(v.y, 0.f);
                         v.z = fmaxf(v.z, 0.f); v.w = fmaxf(v.w, 0.f); }
            *reinterpret_cast<float4*>(&out[(size_t)n1 * 128 + j]) = v;
        }
    }
}

// ---------------- layer-1 projection: h[n] @ P([128][6]) -> pA[2], pB[2], r[2]+b ---------
__global__ void k_proj(const float* __restrict__ h, const float* __restrict__ P,
                       const float* __restrict__ b2,
                       float* __restrict__ pA, float* __restrict__ pB,
                       float* __restrict__ r, int N)
{
    const int wv = threadIdx.x >> 6, lane = threadIdx.x & 63;
    const int node = blockIdx.x * 4 + wv;
    if (node >= N) return;
    const float2 hv = *reinterpret_cast<const float2*>(&h[(size_t)node * 128 + lane * 2]);
    float o[6];
    #pragma unroll
    for (int c = 0; c < 6; ++c)
        o[c] = hv.x * P[(lane * 2) * 6 + c] + hv.y * P[(lane * 2 + 1) * 6 + c];
    #pragma unroll
    for (int s = 32; s >= 1; s >>= 1) {
        #pragma unroll
        for (int c = 0; c < 6; ++c) o[c] += __shfl_xor(o[c], s, 64);
    }
    if (lane == 0) {
        *reinterpret_cast<float2*>(&pA[(size_t)node * 2]) = make_float2(o[0], o[1]);
        *reinterpret_cast<float2*>(&pB[(size_t)node * 2]) = make_float2(o[2], o[3]);
        *reinterpret_cast<float2*>(&r[(size_t)node * 2])  = make_float2(o[4] + b2[0], o[5] + b2[1]);
    }
}

// ---------------- final: out[n] = r[n] + mean_A(pA[src]) + mean_B(pB[src]) ----------------
__global__ void k_final(const float* __restrict__ r,
                        const float* __restrict__ pA, const int* __restrict__ offA,
                        const int* __restrict__ lstA,
                        const float* __restrict__ pB, const int* __restrict__ offB,
                        const int* __restrict__ lstB,
                        float* __restrict__ out, int N)
{
    const int n = blockIdx.x * blockDim.x + threadIdx.x;
    if (n >= N) return;
    float2 v = *reinterpret_cast<const float2*>(&r[(size_t)n * 2]);
    {
        int s0 = offA[n], s1 = offA[n + 1];
        float sx = 0.f, sy = 0.f;
        for (int e = s0; e < s1; ++e) {
            int s = lstA[e];
            float2 p = *reinterpret_cast<const float2*>(&pA[(size_t)s * 2]);
            sx += p.x; sy += p.y;
        }
        int d = s1 - s0; float sc = 1.0f / (float)(d > 0 ? d : 1);
        v.x += sx * sc; v.y += sy * sc;
    }
    {
        int s0 = offB[n], s1 = offB[n + 1];
        float sx = 0.f, sy = 0.f;
        for (int e = s0; e < s1; ++e) {
            int s = lstB[e];
            float2 p = *reinterpret_cast<const float2*>(&pB[(size_t)s * 2]);
            sx += p.x; sy += p.y;
        }
        int d = s1 - s0; float sc = 1.0f / (float)(d > 0 ? d : 1);
        v.x += sx * sc; v.y += sy * sc;
    }
    *reinterpret_cast<float2*>(&out[(size_t)n * 2]) = v;
}

extern "C" void kernel_launch(void* const* d_in, const int* in_sizes, int n_in,
                              void* d_out, int out_size, void* d_ws, size_t ws_size,
                              hipStream_t stream)
{
    const float* x_tx = (const float*)d_in[0];
    const float* x_ad = (const float*)d_in[1];
    const float* Wl0  = (const float*)d_in[2];
    const float* bl0  = (const float*)d_in[3];
    const float* Wr0  = (const float*)d_in[4];
    const float* rel0 = (const float*)d_in[5];
    const float* Wl1  = (const float*)d_in[6];
    const float* bl1  = (const float*)d_in[7];
    const float* Wr1  = (const float*)d_in[8];
    const float* rel1 = (const float*)d_in[9];
    const int* e_tt = (const int*)d_in[10];
    const int* e_aa = (const int*)d_in[11];
    const int* e_at = (const int*)d_in[12];
    const int* e_ta = (const int*)d_in[13];

    const int N_tx = in_sizes[0] / 128;
    const int N_ad = in_sizes[1] / 128;
    const int E    = in_sizes[10] / 2;
    const int Nmax = N_tx > N_ad ? N_tx : N_ad;
    float* out = (float*)d_out;
    (void)n_in; (void)out_size;

    char* wsb = (char*)d_ws;
    size_t off_b = 0;
    auto wsalloc = [&](size_t bytes) -> void* {
        void* p = (void*)(wsb + off_b);
        off_b += (bytes + 255) & ~(size_t)255;
        return p;
    };
    int* cnt  = (int*)wsalloc(sizeof(int) * 4 * (size_t)Nmax);
    int* cur  = (int*)wsalloc(sizeof(int) * 4 * (size_t)Nmax);
    int* offs = (int*)wsalloc(sizeof(int) * 4 * ((size_t)Nmax + 1));
    int* lst  = (int*)wsalloc(sizeof(int) * 4 * (size_t)E);
    float* bufA = (float*)wsalloc(sizeof(float) * (size_t)Nmax * 128);
    float* h_tx = (float*)wsalloc(sizeof(float) * (size_t)N_tx * 128);
    float* h_ad = (float*)wsalloc(sizeof(float) * (size_t)N_ad * 128);
    float* W0c  = (float*)wsalloc(sizeof(float) * 2 * 384 * 128);
    float* b0c  = (float*)wsalloc(sizeof(float) * 2 * 128);
    float* Pm   = (float*)wsalloc(sizeof(float) * 2 * 128 * 6);
    float* b1c  = (float*)wsalloc(sizeof(float) * 4);
    float* p_tt = (float*)wsalloc(sizeof(float) * (size_t)N_tx * 2);
    float* p_ta = (float*)wsalloc(sizeof(float) * (size_t)N_tx * 2);
    float* p_aa = (float*)wsalloc(sizeof(float) * (size_t)N_ad * 2);
    float* p_at = (float*)wsalloc(sizeof(float) * (size_t)N_ad * 2);
    float* r_tx = (float*)wsalloc(sizeof(float) * (size_t)N_tx * 2);
    float* r_ad = (float*)wsalloc(sizeof(float) * (size_t)N_ad * 2);
    if (off_b > ws_size) return;  // fail loudly (validation) rather than corrupt

    const int* offT[4] = { offs, offs + (size_t)(Nmax + 1), offs + 2 * (size_t)(Nmax + 1),
                           offs + 3 * (size_t)(Nmax + 1) };
    int* lstT[4] = { lst, lst + (size_t)E, lst + 2 * (size_t)E, lst + 3 * (size_t)E };
    const int* eP[4] = { e_tt, e_aa, e_at, e_ta };

    // 1. combined weights
    {
        int total = 2 * 384 * 128 + 2 * 128 + 2 * 128 * 6 + 4;
        k_prep<<<(total + 255) / 256, 256, 0, stream>>>(Wl0, bl0, Wr0, rel0,
                                                        Wl1, bl1, Wr1, rel1,
                                                        W0c, b0c, Pm, b1c);
    }
    // 2. CSR build for all 4 edge types
    hipMemsetAsync(cnt, 0, sizeof(int) * 4 * (size_t)Nmax, stream);
    hipMemsetAsync(cur, 0, sizeof(int) * 4 * (size_t)Nmax, stream);
    const int gE = (E + 255) / 256;
    for (int t = 0; t < 4; ++t)
        k_hist<<<gE, 256, 0, stream>>>(eP[t] + E, cnt + (size_t)t * Nmax, E);
    k_scan<<<4, 1024, 0, stream>>>(cnt, offs, Nmax, N_tx, N_ad);
    for (int t = 0; t < 4; ++t)
        k_fill<<<gE, 256, 0, stream>>>(eP[t], eP[t] + E, offT[t],
                                       cur + (size_t)t * Nmax, lstT[t], E);

    const int gAggTx = (N_tx + 3) / 4, gAggAd = (N_ad + 3) / 4;
    const int gMMTx = (N_tx + 127) / 128, gMMAd = (N_ad + 127) / 128;

    // 3. layer 0 — tx:  h_tx = relu(mean_tt(x_tx)@A + mean_at(x_ad)@B + x_tx@C + b)
    k_agg_mean128<<<gAggTx, 256, 0, stream>>>(x_tx, offT[0], lstT[0], bufA, N_tx);
    k_node_mm<<<gMMTx, 256, 0, stream>>>(bufA, W0c, nullptr, nullptr, nullptr,
                                         h_tx, N_tx, 0, 0);
    k_agg_mean128<<<gAggTx, 256, 0, stream>>>(x_ad, offT[2], lstT[2], bufA, N_tx);
    k_node_mm<<<gMMTx, 256, 0, stream>>>(bufA, W0c + 16384, x_tx, W0c + 32768, b0c,
                                         h_tx, N_tx, 1, 1);
    // 4. layer 0 — addr
    k_agg_mean128<<<gAggAd, 256, 0, stream>>>(x_ad, offT[1], lstT[1], bufA, N_ad);
    k_node_mm<<<gMMAd, 256, 0, stream>>>(bufA, W0c + 49152, nullptr, nullptr, nullptr,
                                         h_ad, N_ad, 0, 0);
    k_agg_mean128<<<gAggAd, 256, 0, stream>>>(x_tx, offT[3], lstT[3], bufA, N_ad);
    k_node_mm<<<gMMAd, 256, 0, stream>>>(bufA, W0c + 49152 + 16384, x_ad,
                                         W0c + 49152 + 32768, b0c + 128,
                                         h_ad, N_ad, 1, 1);

    // 5. layer 1 — project to 2-dim BEFORE aggregation (linearity of mean)
    k_proj<<<gAggTx, 256, 0, stream>>>(h_tx, Pm, b1c, p_tt, p_ta, r_tx, N_tx);
    k_proj<<<gAggAd, 256, 0, stream>>>(h_ad, Pm + 768, b1c + 2, p_aa, p_at, r_ad, N_ad);

    // 6. final 2-dim aggregation + combine
    k_final<<<(N_tx + 255) / 256, 256, 0, stream>>>(r_tx, p_tt, offT[0], lstT[0],
                                                    p_at, offT[2], lstT[2], out, N_tx);
    k_final<<<(N_ad + 255) / 256, 256, 0, stream>>>(r_ad, p_aa, offT[1], lstT[1],
                                                    p_ta, offT[3], lstT[3],
                                                    out + (size_t)N_tx * 2, N_ad);
}

// Round 2
// 1708.278 us; speedup vs baseline: 2.1099x; 2.1099x over previous
//
#include <hip/hip_runtime.h>
#include <cstdint>

#define COMP4(v, c) ((c) == 0 ? (v).x : (c) == 1 ? (v).y : (c) == 2 ? (v).z : (v).w)

// ---------------- prep: softmax(rel) folded into combined weights ----------------
// W0c: [2][384][128]  (side 0=tx, 1=addr; rows 0-127: rw*Wl[tA]; 128-255: rw*Wl[tB];
//                      256-383: rw*Wr[tA]+rw*Wr[tB])
// b0c: [2][128]
// P:   [2][128][6]    (cols 0-1: rw1*Wl1[aggA]; 2-3: rw1*Wl1[srcB]; 4-5: combined Wr1)
// b1c: [2][2]
__global__ void k_prep(const float* __restrict__ Wl0, const float* __restrict__ bl0,
                       const float* __restrict__ Wr0, const float* __restrict__ rel0,
                       const float* __restrict__ Wl1, const float* __restrict__ bl1,
                       const float* __restrict__ Wr1, const float* __restrict__ rel1,
                       float* __restrict__ W0c, float* __restrict__ b0c,
                       float* __restrict__ P, float* __restrict__ b1c)
{
    float rw0[4], rw1[4];
    {
        float m0 = fmaxf(fmaxf(rel0[0], rel0[1]), fmaxf(rel0[2], rel0[3]));
        float m1 = fmaxf(fmaxf(rel1[0], rel1[1]), fmaxf(rel1[2], rel1[3]));
        float s0 = 0.f, s1 = 0.f;
        #pragma unroll
        for (int c = 0; c < 4; ++c) {
            rw0[c] = expf(rel0[c] - m0); s0 += rw0[c];
            rw1[c] = expf(rel1[c] - m1); s1 += rw1[c];
        }
        #pragma unroll
        for (int c = 0; c < 4; ++c) { rw0[c] /= s0; rw1[c] /= s1; }
    }
    const int i = blockIdx.x * blockDim.x + threadIdx.x;
    const int NW = 2 * 384 * 128;
    if (i < NW) {
        int side = i / (384 * 128);
        int rem  = i % (384 * 128);
        int row = rem / 128, col = rem % 128;
        int tA = side ? 1 : 0, tB = side ? 3 : 2;
        float v;
        if (row < 128)      v = rw0[tA] * Wl0[tA * 16384 + row * 128 + col];
        else if (row < 256) v = rw0[tB] * Wl0[tB * 16384 + (row - 128) * 128 + col];
        else                v = rw0[tA] * Wr0[tA * 16384 + (row - 256) * 128 + col]
                              + rw0[tB] * Wr0[tB * 16384 + (row - 256) * 128 + col];
        W0c[i] = v;
    } else if (i < NW + 256) {
        int ib = i - NW;
        int side = ib / 128, col = ib % 128;
        int tA = side ? 1 : 0, tB = side ? 3 : 2;
        b0c[ib] = rw0[tA] * bl0[tA * 128 + col] + rw0[tB] * bl0[tB * 128 + col];
    } else if (i < NW + 256 + 1536) {
        int ip = i - (NW + 256);
        int side = ip / 768, rem = ip % 768;
        int k = rem / 6, c = rem % 6;
        float v;
        if (side == 0) {
            if (c < 2)      v = rw1[0] * Wl1[0 * 256 + k * 2 + c];
            else if (c < 4) v = rw1[3] * Wl1[3 * 256 + k * 2 + (c - 2)];
            else            v = rw1[0] * Wr1[0 * 256 + k * 2 + (c - 4)]
                              + rw1[2] * Wr1[2 * 256 + k * 2 + (c - 4)];
        } else {
            if (c < 2)      v = rw1[1] * Wl1[1 * 256 + k * 2 + c];
            else if (c < 4) v = rw1[2] * Wl1[2 * 256 + k * 2 + (c - 2)];
            else            v = rw1[1] * Wr1[1 * 256 + k * 2 + (c - 4)]
                              + rw1[3] * Wr1[3 * 256 + k * 2 + (c - 4)];
        }
        P[ip] = v;
    } else if (i < NW + 256 + 1536 + 4) {
        int i4 = i - (NW + 256 + 1536);
        int side = i4 / 2, c = i4 % 2;
        b1c[i4] = side ? (rw1[1] * bl1[1 * 2 + c] + rw1[3] * bl1[3 * 2 + c])
                       : (rw1[0] * bl1[0 * 2 + c] + rw1[2] * bl1[2 * 2 + c]);
    }
}

// ---------------- CSR build ----------------
__global__ void k_hist(const int* __restrict__ dst, int* __restrict__ cnt, int E)
{
    int i = blockIdx.x * blockDim.x + threadIdx.x;
    if (i < E) atomicAdd(&cnt[dst[i]], 1);
}

__global__ void k_scan(const int* __restrict__ cnt, int* __restrict__ off,
                       int Nmax, int N_tx, int N_ad)
{
    const int t = blockIdx.x;
    const int N = (t & 1) ? N_ad : N_tx;
    cnt += (size_t)t * Nmax;
    off += (size_t)t * (Nmax + 1);
    const int tid = threadIdx.x;
    const int lane = tid & 63, wv = tid >> 6;
    __shared__ int wtot[16];
    __shared__ int woff[16];
    __shared__ int running;
    if (tid == 0) running = 0;
    __syncthreads();
    for (int base = 0; base < N; base += 1024) {
        int i = base + tid;
        int v = (i < N) ? cnt[i] : 0;
        int incl = v;
        #pragma unroll
        for (int s = 1; s < 64; s <<= 1) {
            int u = __shfl_up(incl, s, 64);
            if (lane >= s) incl += u;
        }
        if (lane == 63) wtot[wv] = incl;
        __syncthreads();
        if (tid == 0) {
            int r = running;
            #pragma unroll
            for (int w = 0; w < 16; ++w) { woff[w] = r; r += wtot[w]; }
            running = r;
        }
        __syncthreads();
        if (i < N) off[i] = woff[wv] + incl - v;
        __syncthreads();
    }
    if (tid == 0) off[N] = running;
}

__global__ void k_fill(const int* __restrict__ src, const int* __restrict__ dst,
                       const int* __restrict__ off, int* __restrict__ cur,
                       int* __restrict__ lst, int E)
{
    int i = blockIdx.x * blockDim.x + threadIdx.x;
    if (i < E) {
        int d = dst[i];
        int p = atomicAdd(&cur[d], 1);
        lst[off[d] + p] = src[i];
    }
}

// ---------------- mean aggregation over 128-dim features: 1 wave per dst ----------------
__global__ void k_agg_mean128(const float* __restrict__ x,
                              const int* __restrict__ off,
                              const int* __restrict__ lst,
                              float* __restrict__ buf, int N)
{
    const int wv = threadIdx.x >> 6;
    const int lane = threadIdx.x & 63;
    const int node = blockIdx.x * 4 + wv;
    if (node >= N) return;
    const int s0 = off[node], s1 = off[node + 1];
    const int d = lane * 2;
    float ax = 0.f, ay = 0.f, bx = 0.f, by = 0.f;
    int e = s0;
    for (; e + 2 <= s1; e += 2) {
        int sA = lst[e], sB = lst[e + 1];
        float2 vA = *reinterpret_cast<const float2*>(&x[(size_t)sA * 128 + d]);
        float2 vB = *reinterpret_cast<const float2*>(&x[(size_t)sB * 128 + d]);
        ax += vA.x; ay += vA.y; bx += vB.x; by += vB.y;
    }
    if (e < s1) {
        int sA = lst[e];
        float2 vA = *reinterpret_cast<const float2*>(&x[(size_t)sA * 128 + d]);
        ax += vA.x; ay += vA.y;
    }
    const int deg = s1 - s0;
    const float sc = 1.0f / (float)(deg > 0 ? deg : 1);
    float2 o; o.x = (ax + bx) * sc; o.y = (ay + by) * sc;
    *reinterpret_cast<float2*>(&buf[(size_t)node * 128 + d]) = o;
}

// ---------------- fused node update ----------------
// out[n][0:128] (+)= [in0[n] | in1[n] | in2[n]] @ W  (+bias)(relu)
// W row offset for slot s is s*128 even when earlier slots are null.
// 128 nodes/block, 256 threads; thread -> (node nl, nl+64) x 32 cols.
// X staged per 32-k chunk in LDS (pitch 36 -> 2-way conflicts only = free);
// W staged per 32-k chunk (row stride 128 floats, broadcast reads, conflict-free).
// Live regs ~= 64 acc + 8 xv + addressing -> no spill (R1's k_node_mm spilled:
// WRITE_SIZE 1.58 GB vs 51 MB ideal).
__global__ __launch_bounds__(256, 2) void k_node_fused(
    const float* __restrict__ in0, const float* __restrict__ in1,
    const float* __restrict__ in2, const float* __restrict__ W,
    const float* __restrict__ bias, float* __restrict__ out,
    int N, int accum, int relu)
{
    __shared__ float Ws[32][128];
    __shared__ float Xs[128][36];
    const int t = threadIdx.x;
    const int base = blockIdx.x * 128;
    const int nl = t >> 2;        // 0..63
    const int jg = t & 3;         // 0..3
    const int n0 = base + nl;
    const int n1 = base + nl + 64;

    float acc0[32], acc1[32];
    #pragma unroll
    for (int i = 0; i < 32; ++i) { acc0[i] = 0.f; acc1[i] = 0.f; }

    #pragma unroll 1
    for (int slot = 0; slot < 3; ++slot) {
        const float* inp = slot == 0 ? in0 : (slot == 1 ? in1 : in2);
        if (!inp) continue;
        #pragma unroll 1
        for (int half = 0; half < 4; ++half) {     // 4 x 32-k chunks
            const float* Wseg = W + ((size_t)slot * 128 + half * 32) * 128;
            __syncthreads();
            #pragma unroll
            for (int q = 0; q < 4; ++q) {          // stage W chunk: 1024 float4
                int f = q * 256 + t;
                int r = f >> 5, c = f & 31;
                *reinterpret_cast<float4*>(&Ws[r][c * 4]) =
                    *reinterpret_cast<const float4*>(&Wseg[(size_t)r * 128 + c * 4]);
            }
            #pragma unroll
            for (int q = 0; q < 4; ++q) {          // stage X chunk: 1024 float4
                int f = q * 256 + t;
                int r = f >> 3, c = f & 7;         // r: node 0..127, c: float4 0..7
                int node = base + r;
                float4 v = (node < N)
                    ? *reinterpret_cast<const float4*>(&inp[(size_t)node * 128 + half * 32 + c * 4])
                    : make_float4(0.f, 0.f, 0.f, 0.f);
                *reinterpret_cast<float4*>(&Xs[r][c * 4]) = v;
            }
            __syncthreads();
            #pragma unroll
            for (int k4 = 0; k4 < 8; ++k4) {
                const float4 xa = *reinterpret_cast<const float4*>(&Xs[nl][k4 * 4]);
                const float4 xb = *reinterpret_cast<const float4*>(&Xs[nl + 64][k4 * 4]);
                #pragma unroll
                for (int c = 0; c < 4; ++c) {
                    const int k = k4 * 4 + c;
                    const float a0 = COMP4(xa, c);
                    const float a1 = COMP4(xb, c);
                    #pragma unroll
                    for (int jj = 0; jj < 8; ++jj) {
                        const float4 w = *reinterpret_cast<const float4*>(&Ws[k][jg * 4 + jj * 16]);
                        acc0[jj * 4 + 0] += a0 * w.x; acc0[jj * 4 + 1] += a0 * w.y;
                        acc0[jj * 4 + 2] += a0 * w.z; acc0[jj * 4 + 3] += a0 * w.w;
                        acc1[jj * 4 + 0] += a1 * w.x; acc1[jj * 4 + 1] += a1 * w.y;
                        acc1[jj * 4 + 2] += a1 * w.z; acc1[jj * 4 + 3] += a1 * w.w;
                    }
                }
            }
        }
    }

    if (n0 < N) {
        #pragma unroll
        for (int jj = 0; jj < 8; ++jj) {
            int j = jg * 4 + jj * 16;
            float4 v = make_float4(acc0[jj * 4 + 0], acc0[jj * 4 + 1], acc0[jj * 4 + 2], acc0[jj * 4 + 3]);
            if (accum) { float4 o = *reinterpret_cast<const float4*>(&out[(size_t)n0 * 128 + j]);
                         v.x += o.x; v.y += o.y; v.z += o.z; v.w += o.w; }
            if (bias)  { float4 b = *reinterpret_cast<const float4*>(&bias[j]);
                         v.x += b.x; v.y += b.y; v.z += b.z; v.w += b.w; }
            if (relu)  { v.x = fmaxf(v.x, 0.f); v.y = fmaxf(v.y, 0.f);
                         v.z = fmaxf(v.z, 0.f); v.w = fmaxf(v.w, 0.f); }
            *reinterpret_cast<float4*>(&out[(size_t)n0 * 128 + j]) = v;
        }
    }
    if (n1 < N) {
        #pragma unroll
        for (int jj = 0; jj < 8; ++jj) {
            int j = jg * 4 + jj * 16;
            float4 v = make_float4(acc1[jj * 4 + 0], acc1[jj * 4 + 1], acc1[jj * 4 + 2], acc1[jj * 4 + 3]);
            if (accum) { float4 o = *reinterpret_cast<const float4*>(&out[(size_t)n1 * 128 + j]);
                         v.x += o.x; v.y += o.y; v.z += o.z; v.w += o.w; }
            if (bias)  { float4 b = *reinterpret_cast<const float4*>(&bias[j]);
                         v.x += b.x; v.y += b.y; v.z += b.z; v.w += b.w; }
            if (relu)  { v.x = fmaxf(v.x, 0.f); v.y = fmaxf(v.y, 0.f);
                         v.z = fmaxf(v.z, 0.f); v.w = fmaxf(v.w, 0.f); }
            *reinterpret_cast<float4*>(&out[(size_t)n1 * 128 + j]) = v;
        }
    }
}

// ---------------- layer-1 projection: h[n] @ P([128][6]) -> pA[2], pB[2], r[2]+b ---------
__global__ void k_proj(const float* __restrict__ h, const float* __restrict__ P,
                       const float* __restrict__ b2,
                       float* __restrict__ pA, float* __restrict__ pB,
                       float* __restrict__ r, int N)
{
    const int wv = threadIdx.x >> 6, lane = threadIdx.x & 63;
    const int node = blockIdx.x * 4 + wv;
    if (node >= N) return;
    const float2 hv = *reinterpret_cast<const float2*>(&h[(size_t)node * 128 + lane * 2]);
    float o[6];
    #pragma unroll
    for (int c = 0; c < 6; ++c)
        o[c] = hv.x * P[(lane * 2) * 6 + c] + hv.y * P[(lane * 2 + 1) * 6 + c];
    #pragma unroll
    for (int s = 32; s >= 1; s >>= 1) {
        #pragma unroll
        for (int c = 0; c < 6; ++c) o[c] += __shfl_xor(o[c], s, 64);
    }
    if (lane == 0) {
        *reinterpret_cast<float2*>(&pA[(size_t)node * 2]) = make_float2(o[0], o[1]);
        *reinterpret_cast<float2*>(&pB[(size_t)node * 2]) = make_float2(o[2], o[3]);
        *reinterpret_cast<float2*>(&r[(size_t)node * 2])  = make_float2(o[4] + b2[0], o[5] + b2[1]);
    }
}

// ---------------- final: out[n] = r[n] + mean_A(pA[src]) + mean_B(pB[src]) ----------------
__global__ void k_final(const float* __restrict__ r,
                        const float* __restrict__ pA, const int* __restrict__ offA,
                        const int* __restrict__ lstA,
                        const float* __restrict__ pB, const int* __restrict__ offB,
                        const int* __restrict__ lstB,
                        float* __restrict__ out, int N)
{
    const int n = blockIdx.x * blockDim.x + threadIdx.x;
    if (n >= N) return;
    float2 v = *reinterpret_cast<const float2*>(&r[(size_t)n * 2]);
    {
        int s0 = offA[n], s1 = offA[n + 1];
        float sx = 0.f, sy = 0.f;
        for (int e = s0; e < s1; ++e) {
            int s = lstA[e];
            float2 p = *reinterpret_cast<const float2*>(&pA[(size_t)s * 2]);
            sx += p.x; sy += p.y;
        }
        int d = s1 - s0; float sc = 1.0f / (float)(d > 0 ? d : 1);
        v.x += sx * sc; v.y += sy * sc;
    }
    {
        int s0 = offB[n], s1 = offB[n + 1];
        float sx = 0.f, sy = 0.f;
        for (int e = s0; e < s1; ++e) {
            int s = lstB[e];
            float2 p = *reinterpret_cast<const float2*>(&pB[(size_t)s * 2]);
            sx += p.x; sy += p.y;
        }
        int d = s1 - s0; float sc = 1.0f / (float)(d > 0 ? d : 1);
        v.x += sx * sc; v.y += sy * sc;
    }
    *reinterpret_cast<float2*>(&out[(size_t)n * 2]) = v;
}

extern "C" void kernel_launch(void* const* d_in, const int* in_sizes, int n_in,
                              void* d_out, int out_size, void* d_ws, size_t ws_size,
                              hipStream_t stream)
{
    const float* x_tx = (const float*)d_in[0];
    const float* x_ad = (const float*)d_in[1];
    const float* Wl0  = (const float*)d_in[2];
    const float* bl0  = (const float*)d_in[3];
    const float* Wr0  = (const float*)d_in[4];
    const float* rel0 = (const float*)d_in[5];
    const float* Wl1  = (const float*)d_in[6];
    const float* bl1  = (const float*)d_in[7];
    const float* Wr1  = (const float*)d_in[8];
    const float* rel1 = (const float*)d_in[9];
    const int* e_tt = (const int*)d_in[10];
    const int* e_aa = (const int*)d_in[11];
    const int* e_at = (const int*)d_in[12];
    const int* e_ta = (const int*)d_in[13];

    const int N_tx = in_sizes[0] / 128;
    const int N_ad = in_sizes[1] / 128;
    const int E    = in_sizes[10] / 2;
    const int Nmax = N_tx > N_ad ? N_tx : N_ad;
    float* out = (float*)d_out;
    (void)n_in; (void)out_size;

    char* wsb = (char*)d_ws;
    size_t off_b = 0;
    auto wsalloc = [&](size_t bytes) -> void* {
        void* p = (void*)(wsb + off_b);
        off_b += (bytes + 255) & ~(size_t)255;
        return p;
    };
    int* cnt  = (int*)wsalloc(sizeof(int) * 4 * (size_t)Nmax);
    int* cur  = (int*)wsalloc(sizeof(int) * 4 * (size_t)Nmax);
    int* offs = (int*)wsalloc(sizeof(int) * 4 * ((size_t)Nmax + 1));
    int* lst  = (int*)wsalloc(sizeof(int) * 4 * (size_t)E);
    float* bufA = (float*)wsalloc(sizeof(float) * (size_t)Nmax * 128);
    float* h_tx = (float*)wsalloc(sizeof(float) * (size_t)N_tx * 128);
    float* h_ad = (float*)wsalloc(sizeof(float) * (size_t)N_ad * 128);
    float* W0c  = (float*)wsalloc(sizeof(float) * 2 * 384 * 128);
    float* b0c  = (float*)wsalloc(sizeof(float) * 2 * 128);
    float* Pm   = (float*)wsalloc(sizeof(float) * 2 * 128 * 6);
    float* b1c  = (float*)wsalloc(sizeof(float) * 4);
    float* p_tt = (float*)wsalloc(sizeof(float) * (size_t)N_tx * 2);
    float* p_ta = (float*)wsalloc(sizeof(float) * (size_t)N_tx * 2);
    float* p_aa = (float*)wsalloc(sizeof(float) * (size_t)N_ad * 2);
    float* p_at = (float*)wsalloc(sizeof(float) * (size_t)N_ad * 2);
    float* r_tx = (float*)wsalloc(sizeof(float) * (size_t)N_tx * 2);
    float* r_ad = (float*)wsalloc(sizeof(float) * (size_t)N_ad * 2);
    if (off_b > ws_size) return;
    // optional second agg buffer enables single fused GEMM per side
    size_t need_bufB = off_b + ((sizeof(float) * (size_t)Nmax * 128 + 255) & ~(size_t)255);
    float* bufB = (need_bufB <= ws_size) ? (float*)wsalloc(sizeof(float) * (size_t)Nmax * 128)
                                         : nullptr;

    const int* offT[4] = { offs, offs + (size_t)(Nmax + 1), offs + 2 * (size_t)(Nmax + 1),
                           offs + 3 * (size_t)(Nmax + 1) };
    int* lstT[4] = { lst, lst + (size_t)E, lst + 2 * (size_t)E, lst + 3 * (size_t)E };
    const int* eP[4] = { e_tt, e_aa, e_at, e_ta };

    // 1. combined weights
    {
        int total = 2 * 384 * 128 + 2 * 128 + 2 * 128 * 6 + 4;
        k_prep<<<(total + 255) / 256, 256, 0, stream>>>(Wl0, bl0, Wr0, rel0,
                                                        Wl1, bl1, Wr1, rel1,
                                                        W0c, b0c, Pm, b1c);
    }
    // 2. CSR build for all 4 edge types
    hipMemsetAsync(cnt, 0, sizeof(int) * 4 * (size_t)Nmax, stream);
    hipMemsetAsync(cur, 0, sizeof(int) * 4 * (size_t)Nmax, stream);
    const int gE = (E + 255) / 256;
    for (int t = 0; t < 4; ++t)
        k_hist<<<gE, 256, 0, stream>>>(eP[t] + E, cnt + (size_t)t * Nmax, E);
    k_scan<<<4, 1024, 0, stream>>>(cnt, offs, Nmax, N_tx, N_ad);
    for (int t = 0; t < 4; ++t)
        k_fill<<<gE, 256, 0, stream>>>(eP[t], eP[t] + E, offT[t],
                                       cur + (size_t)t * Nmax, lstT[t], E);

    const int gAggTx = (N_tx + 3) / 4, gAggAd = (N_ad + 3) / 4;
    const int gMMTx = (N_tx + 127) / 128, gMMAd = (N_ad + 127) / 128;

    if (bufB) {
        // 3. layer 0 — tx: h_tx = relu([agg_tt(x_tx) | agg_at(x_ad) | x_tx] @ W + b)
        k_agg_mean128<<<gAggTx, 256, 0, stream>>>(x_tx, offT[0], lstT[0], bufA, N_tx);
        k_agg_mean128<<<gAggTx, 256, 0, stream>>>(x_ad, offT[2], lstT[2], bufB, N_tx);
        k_node_fused<<<gMMTx, 256, 0, stream>>>(bufA, bufB, x_tx, W0c, b0c,
                                                h_tx, N_tx, 0, 1);
        // 4. layer 0 — addr
        k_agg_mean128<<<gAggAd, 256, 0, stream>>>(x_ad, offT[1], lstT[1], bufA, N_ad);
        k_agg_mean128<<<gAggAd, 256, 0, stream>>>(x_tx, offT[3], lstT[3], bufB, N_ad);
        k_node_fused<<<gMMAd, 256, 0, stream>>>(bufA, bufB, x_ad, W0c + 49152, b0c + 128,
                                                h_ad, N_ad, 0, 1);
    } else {
        // fallback: reuse bufA sequentially, accumulate into h
        k_agg_mean128<<<gAggTx, 256, 0, stream>>>(x_tx, offT[0], lstT[0], bufA, N_tx);
        k_node_fused<<<gMMTx, 256, 0, stream>>>(bufA, nullptr, nullptr, W0c, nullptr,
                                                h_tx, N_tx, 0, 0);
        k_agg_mean128<<<gAggTx, 256, 0, stream>>>(x_ad, offT[2], lstT[2], bufA, N_tx);
        k_node_fused<<<gMMTx, 256, 0, stream>>>(nullptr, bufA, x_tx, W0c, b0c,
                                                h_tx, N_tx, 1, 1);
        k_agg_mean128<<<gAggAd, 256, 0, stream>>>(x_ad, offT[1], lstT[1], bufA, N_ad);
        k_node_fused<<<gMMAd, 256, 0, stream>>>(bufA, nullptr, nullptr, W0c + 49152, nullptr,
                                                h_ad, N_ad, 0, 0);
        k_agg_mean128<<<gAggAd, 256, 0, stream>>>(x_tx, offT[3], lstT[3], bufA, N_ad);
        k_node_fused<<<gMMAd, 256, 0, stream>>>(nullptr, bufA, x_ad, W0c + 49152, b0c + 128,
                                                h_ad, N_ad, 1, 1);
    }

    // 5. layer 1 — project to 2-dim BEFORE aggregation (linearity of mean)
    k_proj<<<gAggTx, 256, 0, stream>>>(h_tx, Pm, b1c, p_tt, p_ta, r_tx, N_tx);
    k_proj<<<gAggAd, 256, 0, stream>>>(h_ad, Pm + 768, b1c + 2, p_aa, p_at, r_ad, N_ad);

    // 6. final 2-dim aggregation + combine
    k_final<<<(N_tx + 255) / 256, 256, 0, stream>>>(r_tx, p_tt, offT[0], lstT[0],
                                                    p_at, offT[2], lstT[2], out, N_tx);
    k_final<<<(N_ad + 255) / 256, 256, 0, stream>>>(r_ad, p_aa, offT[1], lstT[1],
                                                    p_ta, offT[3], lstT[3],
                                                    out + (size_t)N_tx * 2, N_ad);
}

// Round 3
// 1295.664 us; speedup vs baseline: 2.7818x; 1.3185x over previous
//
#include <hip/hip_runtime.h>
#include <cstdint>

typedef __attribute__((ext_vector_type(4))) float f32x4;
typedef __attribute__((ext_vector_type(8))) short bf16x8;
typedef __attribute__((ext_vector_type(8))) uint16_t u16x8;

static __device__ __forceinline__ float bf2f(uint16_t u) {
    union { uint32_t i; float f; } v; v.i = ((uint32_t)u) << 16; return v.f;
}
// round-to-nearest-even f32 -> bf16 (bit-exact with HW cvt for normal values)
static __device__ __forceinline__ uint16_t f2bf(float f) {
    uint32_t x = __float_as_uint(f);
    uint32_t r = (x + 0x7fffu + ((x >> 16) & 1u)) >> 16;
    return (uint16_t)r;
}

// ---------------- prep (small): softmax-folded bias + layer-1 proj matrices ----------------
// b0c: [2][128] fp32; P: [2][128][6] fp32; b1c: [2][2] fp32
__global__ void k_prep_small(const float* __restrict__ bl0, const float* __restrict__ rel0,
                             const float* __restrict__ Wl1, const float* __restrict__ bl1,
                             const float* __restrict__ Wr1, const float* __restrict__ rel1,
                             float* __restrict__ b0c, float* __restrict__ P,
                             float* __restrict__ b1c)
{
    float rw0[4], rw1[4];
    {
        float m0 = fmaxf(fmaxf(rel0[0], rel0[1]), fmaxf(rel0[2], rel0[3]));
        float m1 = fmaxf(fmaxf(rel1[0], rel1[1]), fmaxf(rel1[2], rel1[3]));
        float s0 = 0.f, s1 = 0.f;
        #pragma unroll
        for (int c = 0; c < 4; ++c) {
            rw0[c] = expf(rel0[c] - m0); s0 += rw0[c];
            rw1[c] = expf(rel1[c] - m1); s1 += rw1[c];
        }
        #pragma unroll
        for (int c = 0; c < 4; ++c) { rw0[c] /= s0; rw1[c] /= s1; }
    }
    const int i = blockIdx.x * blockDim.x + threadIdx.x;
    if (i < 256) {
        int side = i / 128, col = i % 128;
        int tA = side ? 1 : 0, tB = side ? 3 : 2;
        b0c[i] = rw0[tA] * bl0[tA * 128 + col] + rw0[tB] * bl0[tB * 128 + col];
    } else if (i < 256 + 1536) {
        int ip = i - 256;
        int side = ip / 768, rem = ip % 768;
        int k = rem / 6, c = rem % 6;
        float v;
        if (side == 0) {
            if (c < 2)      v = rw1[0] * Wl1[0 * 256 + k * 2 + c];
            else if (c < 4) v = rw1[3] * Wl1[3 * 256 + k * 2 + (c - 2)];
            else            v = rw1[0] * Wr1[0 * 256 + k * 2 + (c - 4)]
                              + rw1[2] * Wr1[2 * 256 + k * 2 + (c - 4)];
        } else {
            if (c < 2)      v = rw1[1] * Wl1[1 * 256 + k * 2 + c];
            else if (c < 4) v = rw1[2] * Wl1[2 * 256 + k * 2 + (c - 2)];
            else            v = rw1[1] * Wr1[1 * 256 + k * 2 + (c - 4)]
                              + rw1[3] * Wr1[3 * 256 + k * 2 + (c - 4)];
        }
        P[ip] = v;
    } else if (i < 256 + 1536 + 4) {
        int i4 = i - (256 + 1536);
        int side = i4 / 2, c = i4 % 2;
        b1c[i4] = side ? (rw1[1] * bl1[1 * 2 + c] + rw1[3] * bl1[3 * 2 + c])
                       : (rw1[0] * bl1[0 * 2 + c] + rw1[2] * bl1[2 * 2 + c]);
    }
}

// ---------------- prep: combined layer-0 weights, bf16, TRANSPOSED + padded -------------
// Wt[side][half][col][k'] bf16, pitch 200 (192 ks + 8 pad). col stride = 400 B
// (== 16 mod 128 B -> uniform bank spread for the b128 fragment reads).
__global__ void k_prep_Wt(const float* __restrict__ Wl0, const float* __restrict__ Wr0,
                          const float* __restrict__ rel0, uint16_t* __restrict__ Wt)
{
    float rw0[4];
    {
        float m0 = fmaxf(fmaxf(rel0[0], rel0[1]), fmaxf(rel0[2], rel0[3]));
        float s0 = 0.f;
        #pragma unroll
        for (int c = 0; c < 4; ++c) { rw0[c] = expf(rel0[c] - m0); s0 += rw0[c]; }
        #pragma unroll
        for (int c = 0; c < 4; ++c) rw0[c] /= s0;
    }
    const int i = blockIdx.x * blockDim.x + threadIdx.x;   // side*49152 + col*384 + k
    if (i >= 2 * 128 * 384) return;
    const int side = i / 49152;
    const int rem  = i % 49152;
    const int col = rem / 384, k = rem % 384;
    const int tA = side ? 1 : 0, tB = side ? 3 : 2;
    float v;
    if (k < 128)      v = rw0[tA] * Wl0[tA * 16384 + k * 128 + col];
    else if (k < 256) v = rw0[tB] * Wl0[tB * 16384 + (k - 128) * 128 + col];
    else              v = rw0[tA] * Wr0[tA * 16384 + (k - 256) * 128 + col]
                        + rw0[tB] * Wr0[tB * 16384 + (k - 256) * 128 + col];
    const int half = (k >= 192) ? 1 : 0;
    const int kp = k - half * 192;
    Wt[((size_t)(side * 2 + half) * 128 + col) * 200 + kp] = f2bf(v);
}

// ---------------- fp32 -> bf16 table conversion (8 elems/thread, 16B stores) -----------
__global__ void k_cvt_bf16(const float* __restrict__ x, uint16_t* __restrict__ y, int n8)
{
    const int i = blockIdx.x * blockDim.x + threadIdx.x;
    if (i >= n8) return;
    const float4* p = reinterpret_cast<const float4*>(x + (size_t)i * 8);
    float4 a = p[0], b = p[1];
    u16x8 o;
    o[0] = f2bf(a.x); o[1] = f2bf(a.y); o[2] = f2bf(a.z); o[3] = f2bf(a.w);
    o[4] = f2bf(b.x); o[5] = f2bf(b.y); o[6] = f2bf(b.z); o[7] = f2bf(b.w);
    *reinterpret_cast<u16x8*>(y + (size_t)i * 8) = o;
}

// ---------------- CSR build ----------------
__global__ void k_hist(const int* __restrict__ dst, int* __restrict__ cnt, int E)
{
    int i = blockIdx.x * blockDim.x + threadIdx.x;
    if (i < E) atomicAdd(&cnt[dst[i]], 1);
}

__global__ void k_scan(const int* __restrict__ cnt, int* __restrict__ off,
                       int Nmax, int N_tx, int N_ad)
{
    const int t = blockIdx.x;
    const int N = (t & 1) ? N_ad : N_tx;
    cnt += (size_t)t * Nmax;
    off += (size_t)t * (Nmax + 1);
    const int tid = threadIdx.x;
    const int lane = tid & 63, wv = tid >> 6;
    __shared__ int wtot[16];
    __shared__ int woff[16];
    __shared__ int running;
    if (tid == 0) running = 0;
    __syncthreads();
    for (int base = 0; base < N; base += 1024) {
        int i = base + tid;
        int v = (i < N) ? cnt[i] : 0;
        int incl = v;
        #pragma unroll
        for (int s = 1; s < 64; s <<= 1) {
            int u = __shfl_up(incl, s, 64);
            if (lane >= s) incl += u;
        }
        if (lane == 63) wtot[wv] = incl;
        __syncthreads();
        if (tid == 0) {
            int r = running;
            #pragma unroll
            for (int w = 0; w < 16; ++w) { woff[w] = r; r += wtot[w]; }
            running = r;
        }
        __syncthreads();
        if (i < N) off[i] = woff[wv] + incl - v;
        __syncthreads();
    }
    if (tid == 0) off[N] = running;
}

__global__ void k_fill(const int* __restrict__ src, const int* __restrict__ dst,
                       const int* __restrict__ off, int* __restrict__ cur,
                       int* __restrict__ lst, int E)
{
    int i = blockIdx.x * blockDim.x + threadIdx.x;
    if (i < E) {
        int d = dst[i];
        int p = atomicAdd(&cur[d], 1);
        lst[off[d] + p] = src[i];
    }
}

// ---------------- mean aggregation, bf16 in / bf16 out, fp32 accumulate ----------------
// 1 wave per dst node; lane covers 2 dims (4 B gather per lane -> 256 B per edge).
__global__ void k_agg_bf16(const uint16_t* __restrict__ x,
                           const int* __restrict__ off, const int* __restrict__ lst,
                           uint16_t* __restrict__ buf, int N)
{
    const int wv = threadIdx.x >> 6;
    const int lane = threadIdx.x & 63;
    const int node = blockIdx.x * 4 + wv;
    if (node >= N) return;
    const int s0 = off[node], s1 = off[node + 1];
    const int d = lane * 2;
    float ax = 0.f, ay = 0.f, bx = 0.f, by = 0.f;
    int e = s0;
    for (; e + 2 <= s1; e += 2) {
        const uint32_t uA = *reinterpret_cast<const uint32_t*>(x + (size_t)lst[e] * 128 + d);
        const uint32_t uB = *reinterpret_cast<const uint32_t*>(x + (size_t)lst[e + 1] * 128 + d);
        ax += bf2f((uint16_t)(uA & 0xffff)); ay += bf2f((uint16_t)(uA >> 16));
        bx += bf2f((uint16_t)(uB & 0xffff)); by += bf2f((uint16_t)(uB >> 16));
    }
    if (e < s1) {
        const uint32_t uA = *reinterpret_cast<const uint32_t*>(x + (size_t)lst[e] * 128 + d);
        ax += bf2f((uint16_t)(uA & 0xffff)); ay += bf2f((uint16_t)(uA >> 16));
    }
    const int deg = s1 - s0;
    const float sc = 1.0f / (float)(deg > 0 ? deg : 1);
    const uint32_t o = (uint32_t)f2bf((ax + bx) * sc) | ((uint32_t)f2bf((ay + by) * sc) << 16);
    *reinterpret_cast<uint32_t*>(buf + (size_t)node * 128 + d) = o;
}

// ---------------- MFMA GEMM: h = relu([A0|A1|A2] @ W + bias), bf16 in, bf16 out --------
// Block: 256 thr = 4 waves; 128 rows/block, wave = 32 rows x 128 cols.
// W (one side) staged K-half at a time: 128 cols x 200-pitch bf16 = 51200 B LDS,
// via global_load_lds dwordx4. A fragments loaded straight from global (16 B/lane).
// mfma_f32_16x16x32_bf16: A lane: row=l&15, k=(l>>4)*8+j ; B lane: col=l&15, same k;
// C lane: col=l&15, row=(l>>4)*4+r  [learn_hip m89].
__global__ __launch_bounds__(256, 2) void k_gemm_bf16(
    const uint16_t* __restrict__ A0, const uint16_t* __restrict__ A1,
    const uint16_t* __restrict__ A2, const uint16_t* __restrict__ Wt,
    const float* __restrict__ bias, uint16_t* __restrict__ h, int N)
{
    __shared__ uint16_t Wlds[128 * 200];
    const int tid = threadIdx.x;
    const int wv = tid >> 6, lane = tid & 63;
    const int l15 = lane & 15, lg = lane >> 4;
    const int wrow = blockIdx.x * 128 + wv * 32;

    f32x4 acc[2][8];
    #pragma unroll
    for (int a = 0; a < 2; ++a)
        #pragma unroll
        for (int b = 0; b < 8; ++b) acc[a][b] = (f32x4){0.f, 0.f, 0.f, 0.f};

    const uint16_t* const Aslot[3] = { A0, A1, A2 };

    #pragma unroll 1
    for (int half = 0; half < 2; ++half) {
        __syncthreads();            // previous LDS tile fully consumed
        const char* src = (const char*)(Wt + (size_t)half * 25600);
        char* dstbase = (char*)Wlds + wv * 1024;
        #pragma unroll
        for (int it = 0; it < 13; ++it) {
            const int off = it * 4096 + tid * 16;
            if (off < 51200)
                __builtin_amdgcn_global_load_lds((const uint32_t*)(src + off),
                                                 (uint32_t*)(dstbase + it * 4096),
                                                 16, 0, 0);
        }
        asm volatile("s_waitcnt vmcnt(0)" ::: "memory");
        __syncthreads();
        #pragma unroll
        for (int ks = 0; ks < 6; ++ks) {
            const int kg = half * 192 + ks * 32;
            const uint16_t* Ap = Aslot[kg >> 7];
            const int kl = (kg & 127) + lg * 8;
            const int r0 = wrow + l15;
            const int r1 = r0 + 16;
            const int c0 = (r0 < N) ? r0 : (N - 1);   // clamped rows: garbage acc
            const int c1 = (r1 < N) ? r1 : (N - 1);   // for OOB rows, never stored
            const bf16x8 af0 = *reinterpret_cast<const bf16x8*>(Ap + (size_t)c0 * 128 + kl);
            const bf16x8 af1 = *reinterpret_cast<const bf16x8*>(Ap + (size_t)c1 * 128 + kl);
            #pragma unroll
            for (int cb = 0; cb < 8; ++cb) {
                const bf16x8 bf = *reinterpret_cast<const bf16x8*>(
                    Wlds + (size_t)(cb * 16 + l15) * 200 + ks * 32 + lg * 8);
                acc[0][cb] = __builtin_amdgcn_mfma_f32_16x16x32_bf16(af0, bf, acc[0][cb], 0, 0, 0);
                acc[1][cb] = __builtin_amdgcn_mfma_f32_16x16x32_bf16(af1, bf, acc[1][cb], 0, 0, 0);
            }
        }
    }
    // epilogue: bias + relu, store bf16
    #pragma unroll
    for (int cb = 0; cb < 8; ++cb) {
        const int col = cb * 16 + l15;
        const float bcol = bias[col];
        #pragma unroll
        for (int rb = 0; rb < 2; ++rb) {
            #pragma unroll
            for (int r = 0; r < 4; ++r) {
                const int row = wrow + rb * 16 + lg * 4 + r;
                if (row < N)
                    h[(size_t)row * 128 + col] = f2bf(fmaxf(acc[rb][cb][r] + bcol, 0.f));
            }
        }
    }
}

// ---------------- layer-1 projection: h(bf16)[n] @ P([128][6]) -> pA, pB, r ------------
__global__ void k_proj(const uint16_t* __restrict__ h, const float* __restrict__ P,
                       const float* __restrict__ b2,
                       float* __restrict__ pA, float* __restrict__ pB,
                       float* __restrict__ r, int N)
{
    const int wv = threadIdx.x >> 6, lane = threadIdx.x & 63;
    const int node = blockIdx.x * 4 + wv;
    if (node >= N) return;
    const uint32_t u = *reinterpret_cast<const uint32_t*>(h + (size_t)node * 128 + lane * 2);
    const float hx = bf2f((uint16_t)(u & 0xffff));
    const float hy = bf2f((uint16_t)(u >> 16));
    float o[6];
    #pragma unroll
    for (int c = 0; c < 6; ++c)
        o[c] = hx * P[(lane * 2) * 6 + c] + hy * P[(lane * 2 + 1) * 6 + c];
    #pragma unroll
    for (int s = 32; s >= 1; s >>= 1) {
        #pragma unroll
        for (int c = 0; c < 6; ++c) o[c] += __shfl_xor(o[c], s, 64);
    }
    if (lane == 0) {
        *reinterpret_cast<float2*>(&pA[(size_t)node * 2]) = make_float2(o[0], o[1]);
        *reinterpret_cast<float2*>(&pB[(size_t)node * 2]) = make_float2(o[2], o[3]);
        *reinterpret_cast<float2*>(&r[(size_t)node * 2])  = make_float2(o[4] + b2[0], o[5] + b2[1]);
    }
}

// ---------------- final: out[n] = r[n] + mean_A(pA[src]) + mean_B(pB[src]) -------------
__global__ void k_final(const float* __restrict__ r,
                        const float* __restrict__ pA, const int* __restrict__ offA,
                        const int* __restrict__ lstA,
                        const float* __restrict__ pB, const int* __restrict__ offB,
                        const int* __restrict__ lstB,
                        float* __restrict__ out, int N)
{
    const int n = blockIdx.x * blockDim.x + threadIdx.x;
    if (n >= N) return;
    float2 v = *reinterpret_cast<const float2*>(&r[(size_t)n * 2]);
    {
        int s0 = offA[n], s1 = offA[n + 1];
        float sx = 0.f, sy = 0.f;
        for (int e = s0; e < s1; ++e) {
            float2 p = *reinterpret_cast<const float2*>(&pA[(size_t)lstA[e] * 2]);
            sx += p.x; sy += p.y;
        }
        int d = s1 - s0; float sc = 1.0f / (float)(d > 0 ? d : 1);
        v.x += sx * sc; v.y += sy * sc;
    }
    {
        int s0 = offB[n], s1 = offB[n + 1];
        float sx = 0.f, sy = 0.f;
        for (int e = s0; e < s1; ++e) {
            float2 p = *reinterpret_cast<const float2*>(&pB[(size_t)lstB[e] * 2]);
            sx += p.x; sy += p.y;
        }
        int d = s1 - s0; float sc = 1.0f / (float)(d > 0 ? d : 1);
        v.x += sx * sc; v.y += sy * sc;
    }
    *reinterpret_cast<float2*>(&out[(size_t)n * 2]) = v;
}

extern "C" void kernel_launch(void* const* d_in, const int* in_sizes, int n_in,
                              void* d_out, int out_size, void* d_ws, size_t ws_size,
                              hipStream_t stream)
{
    const float* x_tx = (const float*)d_in[0];
    const float* x_ad = (const float*)d_in[1];
    const float* Wl0  = (const float*)d_in[2];
    const float* bl0  = (const float*)d_in[3];
    const float* Wr0  = (const float*)d_in[4];
    const float* rel0 = (const float*)d_in[5];
    const float* Wl1  = (const float*)d_in[6];
    const float* bl1  = (const float*)d_in[7];
    const float* Wr1  = (const float*)d_in[8];
    const float* rel1 = (const float*)d_in[9];
    const int* e_tt = (const int*)d_in[10];
    const int* e_aa = (const int*)d_in[11];
    const int* e_at = (const int*)d_in[12];
    const int* e_ta = (const int*)d_in[13];

    const int N_tx = in_sizes[0] / 128;
    const int N_ad = in_sizes[1] / 128;
    const int E    = in_sizes[10] / 2;
    const int Nmax = N_tx > N_ad ? N_tx : N_ad;
    float* out = (float*)d_out;
    (void)n_in; (void)out_size;

    char* wsb = (char*)d_ws;
    size_t off_b = 0;
    auto wsalloc = [&](size_t bytes) -> void* {
        void* p = (void*)(wsb + off_b);
        off_b += (bytes + 255) & ~(size_t)255;
        return p;
    };
    int* cnt  = (int*)wsalloc(sizeof(int) * 4 * (size_t)Nmax);
    int* cur  = (int*)wsalloc(sizeof(int) * 4 * (size_t)Nmax);
    int* offs = (int*)wsalloc(sizeof(int) * 4 * ((size_t)Nmax + 1));
    int* lst  = (int*)wsalloc(sizeof(int) * 4 * (size_t)E);
    uint16_t* xbf_tx = (uint16_t*)wsalloc(sizeof(uint16_t) * (size_t)N_tx * 128);
    uint16_t* xbf_ad = (uint16_t*)wsalloc(sizeof(uint16_t) * (size_t)N_ad * 128);
    uint16_t* bufA = (uint16_t*)wsalloc(sizeof(uint16_t) * (size_t)Nmax * 128);
    uint16_t* bufB = (uint16_t*)wsalloc(sizeof(uint16_t) * (size_t)Nmax * 128);
    uint16_t* h_tx = (uint16_t*)wsalloc(sizeof(uint16_t) * (size_t)N_tx * 128);
    uint16_t* h_ad = (uint16_t*)wsalloc(sizeof(uint16_t) * (size_t)N_ad * 128);
    uint16_t* Wt   = (uint16_t*)wsalloc(sizeof(uint16_t) * 2 * 2 * 128 * 200);
    float* b0c  = (float*)wsalloc(sizeof(float) * 2 * 128);
    float* Pm   = (float*)wsalloc(sizeof(float) * 2 * 128 * 6);
    float* b1c  = (float*)wsalloc(sizeof(float) * 4);
    float* p_tt = (float*)wsalloc(sizeof(float) * (size_t)N_tx * 2);
    float* p_ta = (float*)wsalloc(sizeof(float) * (size_t)N_tx * 2);
    float* p_aa = (float*)wsalloc(sizeof(float) * (size_t)N_ad * 2);
    float* p_at = (float*)wsalloc(sizeof(float) * (size_t)N_ad * 2);
    float* r_tx = (float*)wsalloc(sizeof(float) * (size_t)N_tx * 2);
    float* r_ad = (float*)wsalloc(sizeof(float) * (size_t)N_ad * 2);
    if (off_b > ws_size) return;

    const int* offT[4] = { offs, offs + (size_t)(Nmax + 1), offs + 2 * (size_t)(Nmax + 1),
                           offs + 3 * (size_t)(Nmax + 1) };
    int* lstT[4] = { lst, lst + (size_t)E, lst + 2 * (size_t)E, lst + 3 * (size_t)E };
    const int* eP[4] = { e_tt, e_aa, e_at, e_ta };

    // 1. prep: biases / proj matrices / transposed bf16 combined W
    k_prep_small<<<8, 256, 0, stream>>>(bl0, rel0, Wl1, bl1, Wr1, rel1, b0c, Pm, b1c);
    k_prep_Wt<<<(2 * 128 * 384 + 255) / 256, 256, 0, stream>>>(Wl0, Wr0, rel0, Wt);

    // 2. bf16 feature tables
    k_cvt_bf16<<<((N_tx * 128 / 8) + 255) / 256, 256, 0, stream>>>(x_tx, xbf_tx, N_tx * 128 / 8);
    k_cvt_bf16<<<((N_ad * 128 / 8) + 255) / 256, 256, 0, stream>>>(x_ad, xbf_ad, N_ad * 128 / 8);

    // 3. CSR build for all 4 edge types
    hipMemsetAsync(cnt, 0, sizeof(int) * 4 * (size_t)Nmax, stream);
    hipMemsetAsync(cur, 0, sizeof(int) * 4 * (size_t)Nmax, stream);
    const int gE = (E + 255) / 256;
    for (int t = 0; t < 4; ++t)
        k_hist<<<gE, 256, 0, stream>>>(eP[t] + E, cnt + (size_t)t * Nmax, E);
    k_scan<<<4, 1024, 0, stream>>>(cnt, offs, Nmax, N_tx, N_ad);
    for (int t = 0; t < 4; ++t)
        k_fill<<<gE, 256, 0, stream>>>(eP[t], eP[t] + E, offT[t],
                                       cur + (size_t)t * Nmax, lstT[t], E);

    const int gAggTx = (N_tx + 3) / 4, gAggAd = (N_ad + 3) / 4;
    const int gMMTx = (N_tx + 127) / 128, gMMAd = (N_ad + 127) / 128;

    // 4. layer 0 — tx: h_tx = relu([agg_tt(x_tx) | agg_at(x_ad) | x_tx] @ W + b)
    k_agg_bf16<<<gAggTx, 256, 0, stream>>>(xbf_tx, offT[0], lstT[0], bufA, N_tx);
    k_agg_bf16<<<gAggTx, 256, 0, stream>>>(xbf_ad, offT[2], lstT[2], bufB, N_tx);
    k_gemm_bf16<<<gMMTx, 256, 0, stream>>>(bufA, bufB, xbf_tx, Wt, b0c, h_tx, N_tx);
    // 5. layer 0 — addr
    k_agg_bf16<<<gAggAd, 256, 0, stream>>>(xbf_ad, offT[1], lstT[1], bufA, N_ad);
    k_agg_bf16<<<gAggAd, 256, 0, stream>>>(xbf_tx, offT[3], lstT[3], bufB, N_ad);
    k_gemm_bf16<<<gMMAd, 256, 0, stream>>>(bufA, bufB, xbf_ad, Wt + 2 * 128 * 200,
                                           b0c + 128, h_ad, N_ad);

    // 6. layer 1 — project to 2-dim BEFORE aggregation (linearity of mean)
    k_proj<<<gAggTx, 256, 0, stream>>>(h_tx, Pm, b1c, p_tt, p_ta, r_tx, N_tx);
    k_proj<<<gAggAd, 256, 0, stream>>>(h_ad, Pm + 768, b1c + 2, p_aa, p_at, r_ad, N_ad);

    // 7. final 2-dim aggregation + combine
    k_final<<<(N_tx + 255) / 256, 256, 0, stream>>>(r_tx, p_tt, offT[0], lstT[0],
                                                    p_at, offT[2], lstT[2], out, N_tx);
    k_final<<<(N_ad + 255) / 256, 256, 0, stream>>>(r_ad, p_aa, offT[1], lstT[1],
                                                    p_ta, offT[3], lstT[3],
                                                    out + (size_t)N_tx * 2, N_ad);
}

// Round 4
// 1122.675 us; speedup vs baseline: 3.2104x; 1.1541x over previous
//
#include <hip/hip_runtime.h>
#include <cstdint>

typedef __attribute__((ext_vector_type(4))) float f32x4;
typedef __attribute__((ext_vector_type(8))) short bf16x8;
typedef __attribute__((ext_vector_type(8))) uint16_t u16x8;

static __device__ __forceinline__ float bf2f(uint16_t u) {
    union { uint32_t i; float f; } v; v.i = ((uint32_t)u) << 16; return v.f;
}
// round-to-nearest-even f32 -> bf16
static __device__ __forceinline__ uint16_t f2bf(float f) {
    uint32_t x = __float_as_uint(f);
    uint32_t r = (x + 0x7fffu + ((x >> 16) & 1u)) >> 16;
    return (uint16_t)r;
}

// ---------------- prep (small): softmax-folded bias + layer-1 proj matrices ------------
__global__ void k_prep_small(const float* __restrict__ bl0, const float* __restrict__ rel0,
                             const float* __restrict__ Wl1, const float* __restrict__ bl1,
                             const float* __restrict__ Wr1, const float* __restrict__ rel1,
                             float* __restrict__ b0c, float* __restrict__ P,
                             float* __restrict__ b1c)
{
    float rw0[4], rw1[4];
    {
        float m0 = fmaxf(fmaxf(rel0[0], rel0[1]), fmaxf(rel0[2], rel0[3]));
        float m1 = fmaxf(fmaxf(rel1[0], rel1[1]), fmaxf(rel1[2], rel1[3]));
        float s0 = 0.f, s1 = 0.f;
        #pragma unroll
        for (int c = 0; c < 4; ++c) {
            rw0[c] = expf(rel0[c] - m0); s0 += rw0[c];
            rw1[c] = expf(rel1[c] - m1); s1 += rw1[c];
        }
        #pragma unroll
        for (int c = 0; c < 4; ++c) { rw0[c] /= s0; rw1[c] /= s1; }
    }
    const int i = blockIdx.x * blockDim.x + threadIdx.x;
    if (i < 256) {
        int side = i / 128, col = i % 128;
        int tA = side ? 1 : 0, tB = side ? 3 : 2;
        b0c[i] = rw0[tA] * bl0[tA * 128 + col] + rw0[tB] * bl0[tB * 128 + col];
    } else if (i < 256 + 1536) {
        int ip = i - 256;
        int side = ip / 768, rem = ip % 768;
        int k = rem / 6, c = rem % 6;
        float v;
        if (side == 0) {
            if (c < 2)      v = rw1[0] * Wl1[0 * 256 + k * 2 + c];
            else if (c < 4) v = rw1[3] * Wl1[3 * 256 + k * 2 + (c - 2)];
            else            v = rw1[0] * Wr1[0 * 256 + k * 2 + (c - 4)]
                              + rw1[2] * Wr1[2 * 256 + k * 2 + (c - 4)];
        } else {
            if (c < 2)      v = rw1[1] * Wl1[1 * 256 + k * 2 + c];
            else if (c < 4) v = rw1[2] * Wl1[2 * 256 + k * 2 + (c - 2)];
            else            v = rw1[1] * Wr1[1 * 256 + k * 2 + (c - 4)]
                              + rw1[3] * Wr1[3 * 256 + k * 2 + (c - 4)];
        }
        P[ip] = v;
    } else if (i < 256 + 1536 + 4) {
        int i4 = i - (256 + 1536);
        int side = i4 / 2, c = i4 % 2;
        b1c[i4] = side ? (rw1[1] * bl1[1 * 2 + c] + rw1[3] * bl1[3 * 2 + c])
                       : (rw1[0] * bl1[0 * 2 + c] + rw1[2] * bl1[2 * 2 + c]);
    }
}

// ---------------- prep: combined layer-0 weights, bf16, TRANSPOSED + padded ------------
// Wt[side][half][col][k'] bf16, pitch 200 (192 ks + 8 pad).
__global__ void k_prep_Wt(const float* __restrict__ Wl0, const float* __restrict__ Wr0,
                          const float* __restrict__ rel0, uint16_t* __restrict__ Wt)
{
    float rw0[4];
    {
        float m0 = fmaxf(fmaxf(rel0[0], rel0[1]), fmaxf(rel0[2], rel0[3]));
        float s0 = 0.f;
        #pragma unroll
        for (int c = 0; c < 4; ++c) { rw0[c] = expf(rel0[c] - m0); s0 += rw0[c]; }
        #pragma unroll
        for (int c = 0; c < 4; ++c) rw0[c] /= s0;
    }
    const int i = blockIdx.x * blockDim.x + threadIdx.x;   // side*49152 + col*384 + k
    if (i >= 2 * 128 * 384) return;
    const int side = i / 49152;
    const int rem  = i % 49152;
    const int col = rem / 384, k = rem % 384;
    const int tA = side ? 1 : 0, tB = side ? 3 : 2;
    float v;
    if (k < 128)      v = rw0[tA] * Wl0[tA * 16384 + k * 128 + col];
    else if (k < 256) v = rw0[tB] * Wl0[tB * 16384 + (k - 128) * 128 + col];
    else              v = rw0[tA] * Wr0[tA * 16384 + (k - 256) * 128 + col]
                        + rw0[tB] * Wr0[tB * 16384 + (k - 256) * 128 + col];
    const int half = (k >= 192) ? 1 : 0;
    const int kp = k - half * 192;
    Wt[((size_t)(side * 2 + half) * 128 + col) * 200 + kp] = f2bf(v);
}

// ---------------- fp32 -> bf16 table conversion ----------------------------------------
__global__ void k_cvt_bf16(const float* __restrict__ x, uint16_t* __restrict__ y, int n8)
{
    const int i = blockIdx.x * blockDim.x + threadIdx.x;
    if (i >= n8) return;
    const float4* p = reinterpret_cast<const float4*>(x + (size_t)i * 8);
    float4 a = p[0], b = p[1];
    u16x8 o;
    o[0] = f2bf(a.x); o[1] = f2bf(a.y); o[2] = f2bf(a.z); o[3] = f2bf(a.w);
    o[4] = f2bf(b.x); o[5] = f2bf(b.y); o[6] = f2bf(b.z); o[7] = f2bf(b.w);
    *reinterpret_cast<u16x8*>(y + (size_t)i * 8) = o;
}

// ---------------- CSR build: 4 edge types in one dispatch (blockIdx.y = type) ----------
__global__ void k_hist4(const int* __restrict__ d0, const int* __restrict__ d1,
                        const int* __restrict__ d2, const int* __restrict__ d3,
                        int* __restrict__ cnt, int Nmax, int E)
{
    const int t = blockIdx.y;
    const int* dst = t == 0 ? d0 : (t == 1 ? d1 : (t == 2 ? d2 : d3));
    const int i = blockIdx.x * blockDim.x + threadIdx.x;
    if (i < E) atomicAdd(&cnt[(size_t)t * Nmax + dst[i]], 1);
}

__global__ void k_fill4(const int* __restrict__ e0, const int* __restrict__ e1,
                        const int* __restrict__ e2, const int* __restrict__ e3,
                        const int* __restrict__ off, int* __restrict__ cur,
                        int* __restrict__ lst, int Nmax, int E)
{
    const int t = blockIdx.y;
    const int* ep = t == 0 ? e0 : (t == 1 ? e1 : (t == 2 ? e2 : e3));
    const int i = blockIdx.x * blockDim.x + threadIdx.x;
    if (i < E) {
        const int s = ep[i];
        const int d = ep[E + i];
        const int p = atomicAdd(&cur[(size_t)t * Nmax + d], 1);
        lst[(size_t)t * E + off[(size_t)t * (Nmax + 1) + d] + p] = s;
    }
}

__global__ void k_scan(const int* __restrict__ cnt, int* __restrict__ off,
                       int Nmax, int N_tx, int N_ad)
{
    const int t = blockIdx.x;
    const int N = (t & 1) ? N_ad : N_tx;
    cnt += (size_t)t * Nmax;
    off += (size_t)t * (Nmax + 1);
    const int tid = threadIdx.x;
    const int lane = tid & 63, wv = tid >> 6;
    __shared__ int wtot[16];
    __shared__ int woff[16];
    __shared__ int running;
    if (tid == 0) running = 0;
    __syncthreads();
    for (int base = 0; base < N; base += 1024) {
        int i = base + tid;
        int v = (i < N) ? cnt[i] : 0;
        int incl = v;
        #pragma unroll
        for (int s = 1; s < 64; s <<= 1) {
            int u = __shfl_up(incl, s, 64);
            if (lane >= s) incl += u;
        }
        if (lane == 63) wtot[wv] = incl;
        __syncthreads();
        if (tid == 0) {
            int r = running;
            #pragma unroll
            for (int w = 0; w < 16; ++w) { woff[w] = r; r += wtot[w]; }
            running = r;
        }
        __syncthreads();
        if (i < N) off[i] = woff[wv] + incl - v;
        __syncthreads();
    }
    if (tid == 0) off[N] = running;
}

// ---------------- mean aggregation, bf16, latency-optimized ----------------------------
// 1 wave/node. Indices loaded 64-at-a-time coalesced, shfl-broadcast; 4 independent
// gathers in flight (R3 was 2-deep with a dependent index load -> latency-bound at
// 27% BW). Lane covers 2 dims (one dword per gather).
__global__ void k_agg_bf16(const uint16_t* __restrict__ x,
                           const int* __restrict__ off, const int* __restrict__ lst,
                           uint16_t* __restrict__ buf, int N)
{
    const int wv = threadIdx.x >> 6;
    const int lane = threadIdx.x & 63;
    const int node = blockIdx.x * 4 + wv;
    if (node >= N) return;
    const int s0 = off[node], s1 = off[node + 1];
    const int d = lane * 2;
    float ax = 0.f, ay = 0.f, bx = 0.f, by = 0.f;
    for (int base = s0; base < s1; base += 64) {
        const int cnt = min(64, s1 - base);
        int idx = 0;
        if (lane < cnt) idx = lst[base + lane];
        int j = 0;
        for (; j + 4 <= cnt; j += 4) {
            const int sA = __shfl(idx, j);
            const int sB = __shfl(idx, j + 1);
            const int sC = __shfl(idx, j + 2);
            const int sD = __shfl(idx, j + 3);
            const uint32_t uA = *reinterpret_cast<const uint32_t*>(x + ((size_t)sA << 7) + d);
            const uint32_t uB = *reinterpret_cast<const uint32_t*>(x + ((size_t)sB << 7) + d);
            const uint32_t uC = *reinterpret_cast<const uint32_t*>(x + ((size_t)sC << 7) + d);
            const uint32_t uD = *reinterpret_cast<const uint32_t*>(x + ((size_t)sD << 7) + d);
            ax += bf2f((uint16_t)(uA & 0xffff)); ay += bf2f((uint16_t)(uA >> 16));
            bx += bf2f((uint16_t)(uB & 0xffff)); by += bf2f((uint16_t)(uB >> 16));
            ax += bf2f((uint16_t)(uC & 0xffff)); ay += bf2f((uint16_t)(uC >> 16));
            bx += bf2f((uint16_t)(uD & 0xffff)); by += bf2f((uint16_t)(uD >> 16));
        }
        for (; j < cnt; ++j) {
            const int sA = __shfl(idx, j);
            const uint32_t uA = *reinterpret_cast<const uint32_t*>(x + ((size_t)sA << 7) + d);
            ax += bf2f((uint16_t)(uA & 0xffff)); ay += bf2f((uint16_t)(uA >> 16));
        }
    }
    const int deg = s1 - s0;
    const float sc = 1.0f / (float)(deg > 0 ? deg : 1);
    const uint32_t o = (uint32_t)f2bf((ax + bx) * sc) | ((uint32_t)f2bf((ay + by) * sc) << 16);
    *reinterpret_cast<uint32_t*>(buf + (size_t)node * 128 + d) = o;
}

// ---------------- MFMA GEMM: h = relu([A0|A1|A2] @ W + bias), bf16 in/out --------------
__global__ __launch_bounds__(256, 2) void k_gemm_bf16(
    const uint16_t* __restrict__ A0, const uint16_t* __restrict__ A1,
    const uint16_t* __restrict__ A2, const uint16_t* __restrict__ Wt,
    const float* __restrict__ bias, uint16_t* __restrict__ h, int N)
{
    __shared__ uint16_t Wlds[128 * 200];
    const int tid = threadIdx.x;
    const int wv = tid >> 6, lane = tid & 63;
    const int l15 = lane & 15, lg = lane >> 4;
    const int wrow = blockIdx.x * 128 + wv * 32;

    f32x4 acc[2][8];
    #pragma unroll
    for (int a = 0; a < 2; ++a)
        #pragma unroll
        for (int b = 0; b < 8; ++b) acc[a][b] = (f32x4){0.f, 0.f, 0.f, 0.f};

    const uint16_t* const Aslot[3] = { A0, A1, A2 };

    #pragma unroll 1
    for (int half = 0; half < 2; ++half) {
        __syncthreads();
        const char* src = (const char*)(Wt + (size_t)half * 25600);
        char* dstbase = (char*)Wlds + wv * 1024;
        #pragma unroll
        for (int it = 0; it < 13; ++it) {
            const int off = it * 4096 + tid * 16;
            if (off < 51200)
                __builtin_amdgcn_global_load_lds((const uint32_t*)(src + off),
                                                 (uint32_t*)(dstbase + it * 4096),
                                                 16, 0, 0);
        }
        asm volatile("s_waitcnt vmcnt(0)" ::: "memory");
        __syncthreads();
        #pragma unroll
        for (int ks = 0; ks < 6; ++ks) {
            const int kg = half * 192 + ks * 32;
            const uint16_t* Ap = Aslot[kg >> 7];
            const int kl = (kg & 127) + lg * 8;
            const int r0 = wrow + l15;
            const int r1 = r0 + 16;
            const int c0 = (r0 < N) ? r0 : (N - 1);
            const int c1 = (r1 < N) ? r1 : (N - 1);
            const bf16x8 af0 = *reinterpret_cast<const bf16x8*>(Ap + (size_t)c0 * 128 + kl);
            const bf16x8 af1 = *reinterpret_cast<const bf16x8*>(Ap + (size_t)c1 * 128 + kl);
            #pragma unroll
            for (int cb = 0; cb < 8; ++cb) {
                const bf16x8 bf = *reinterpret_cast<const bf16x8*>(
                    Wlds + (size_t)(cb * 16 + l15) * 200 + ks * 32 + lg * 8);
                acc[0][cb] = __builtin_amdgcn_mfma_f32_16x16x32_bf16(af0, bf, acc[0][cb], 0, 0, 0);
                acc[1][cb] = __builtin_amdgcn_mfma_f32_16x16x32_bf16(af1, bf, acc[1][cb], 0, 0, 0);
            }
        }
    }
    #pragma unroll
    for (int cb = 0; cb < 8; ++cb) {
        const int col = cb * 16 + l15;
        const float bcol = bias[col];
        #pragma unroll
        for (int rb = 0; rb < 2; ++rb) {
            #pragma unroll
            for (int r = 0; r < 4; ++r) {
                const int row = wrow + rb * 16 + lg * 4 + r;
                if (row < N)
                    h[(size_t)row * 128 + col] = f2bf(fmaxf(acc[rb][cb][r] + bcol, 0.f));
            }
        }
    }
}

// ---------------- layer-1 projection: h(bf16)[n] @ P([128][6]) -> pA, pB, r ------------
__global__ void k_proj(const uint16_t* __restrict__ h, const float* __restrict__ P,
                       const float* __restrict__ b2,
                       float* __restrict__ pA, float* __restrict__ pB,
                       float* __restrict__ r, int N)
{
    const int wv = threadIdx.x >> 6, lane = threadIdx.x & 63;
    const int node = blockIdx.x * 4 + wv;
    if (node >= N) return;
    const uint32_t u = *reinterpret_cast<const uint32_t*>(h + (size_t)node * 128 + lane * 2);
    const float hx = bf2f((uint16_t)(u & 0xffff));
    const float hy = bf2f((uint16_t)(u >> 16));
    float o[6];
    #pragma unroll
    for (int c = 0; c < 6; ++c)
        o[c] = hx * P[(lane * 2) * 6 + c] + hy * P[(lane * 2 + 1) * 6 + c];
    #pragma unroll
    for (int s = 32; s >= 1; s >>= 1) {
        #pragma unroll
        for (int c = 0; c < 6; ++c) o[c] += __shfl_xor(o[c], s, 64);
    }
    if (lane == 0) {
        *reinterpret_cast<float2*>(&pA[(size_t)node * 2]) = make_float2(o[0], o[1]);
        *reinterpret_cast<float2*>(&pB[(size_t)node * 2]) = make_float2(o[2], o[3]);
        *reinterpret_cast<float2*>(&r[(size_t)node * 2])  = make_float2(o[4] + b2[0], o[5] + b2[1]);
    }
}

// ---------------- final: out[n] = r[n] + mean_A(pA[src]) + mean_B(pB[src]) -------------
__global__ void k_final(const float* __restrict__ r,
                        const float* __restrict__ pA, const int* __restrict__ offA,
                        const int* __restrict__ lstA,
                        const float* __restrict__ pB, const int* __restrict__ offB,
                        const int* __restrict__ lstB,
                        float* __restrict__ out, int N)
{
    const int n = blockIdx.x * blockDim.x + threadIdx.x;
    if (n >= N) return;
    float2 v = *reinterpret_cast<const float2*>(&r[(size_t)n * 2]);
    {
        int s0 = offA[n], s1 = offA[n + 1];
        float sx = 0.f, sy = 0.f;
        for (int e = s0; e < s1; ++e) {
            float2 p = *reinterpret_cast<const float2*>(&pA[(size_t)lstA[e] * 2]);
            sx += p.x; sy += p.y;
        }
        int d = s1 - s0; float sc = 1.0f / (float)(d > 0 ? d : 1);
        v.x += sx * sc; v.y += sy * sc;
    }
    {
        int s0 = offB[n], s1 = offB[n + 1];
        float sx = 0.f, sy = 0.f;
        for (int e = s0; e < s1; ++e) {
            float2 p = *reinterpret_cast<const float2*>(&pB[(size_t)lstB[e] * 2]);
            sx += p.x; sy += p.y;
        }
        int d = s1 - s0; float sc = 1.0f / (float)(d > 0 ? d : 1);
        v.x += sx * sc; v.y += sy * sc;
    }
    *reinterpret_cast<float2*>(&out[(size_t)n * 2]) = v;
}

extern "C" void kernel_launch(void* const* d_in, const int* in_sizes, int n_in,
                              void* d_out, int out_size, void* d_ws, size_t ws_size,
                              hipStream_t stream)
{
    const float* x_tx = (const float*)d_in[0];
    const float* x_ad = (const float*)d_in[1];
    const float* Wl0  = (const float*)d_in[2];
    const float* bl0  = (const float*)d_in[3];
    const float* Wr0  = (const float*)d_in[4];
    const float* rel0 = (const float*)d_in[5];
    const float* Wl1  = (const float*)d_in[6];
    const float* bl1  = (const float*)d_in[7];
    const float* Wr1  = (const float*)d_in[8];
    const float* rel1 = (const float*)d_in[9];
    const int* e_tt = (const int*)d_in[10];
    const int* e_aa = (const int*)d_in[11];
    const int* e_at = (const int*)d_in[12];
    const int* e_ta = (const int*)d_in[13];

    const int N_tx = in_sizes[0] / 128;
    const int N_ad = in_sizes[1] / 128;
    const int E    = in_sizes[10] / 2;
    const int Nmax = N_tx > N_ad ? N_tx : N_ad;
    float* out = (float*)d_out;
    (void)n_in; (void)out_size;

    char* wsb = (char*)d_ws;
    size_t off_b = 0;
    auto wsalloc = [&](size_t bytes) -> void* {
        void* p = (void*)(wsb + off_b);
        off_b += (bytes + 255) & ~(size_t)255;
        return p;
    };
    int* cnt  = (int*)wsalloc(sizeof(int) * 4 * (size_t)Nmax);
    int* cur  = (int*)wsalloc(sizeof(int) * 4 * (size_t)Nmax);
    int* offs = (int*)wsalloc(sizeof(int) * 4 * ((size_t)Nmax + 1));
    int* lst  = (int*)wsalloc(sizeof(int) * 4 * (size_t)E);
    uint16_t* xbf_tx = (uint16_t*)wsalloc(sizeof(uint16_t) * (size_t)N_tx * 128);
    uint16_t* xbf_ad = (uint16_t*)wsalloc(sizeof(uint16_t) * (size_t)N_ad * 128);
    uint16_t* bufA = (uint16_t*)wsalloc(sizeof(uint16_t) * (size_t)Nmax * 128);
    uint16_t* bufB = (uint16_t*)wsalloc(sizeof(uint16_t) * (size_t)Nmax * 128);
    uint16_t* h_tx = (uint16_t*)wsalloc(sizeof(uint16_t) * (size_t)N_tx * 128);
    uint16_t* h_ad = (uint16_t*)wsalloc(sizeof(uint16_t) * (size_t)N_ad * 128);
    uint16_t* Wt   = (uint16_t*)wsalloc(sizeof(uint16_t) * 2 * 2 * 128 * 200);
    float* b0c  = (float*)wsalloc(sizeof(float) * 2 * 128);
    float* Pm   = (float*)wsalloc(sizeof(float) * 2 * 128 * 6);
    float* b1c  = (float*)wsalloc(sizeof(float) * 4);
    float* p_tt = (float*)wsalloc(sizeof(float) * (size_t)N_tx * 2);
    float* p_ta = (float*)wsalloc(sizeof(float) * (size_t)N_tx * 2);
    float* p_aa = (float*)wsalloc(sizeof(float) * (size_t)N_ad * 2);
    float* p_at = (float*)wsalloc(sizeof(float) * (size_t)N_ad * 2);
    float* r_tx = (float*)wsalloc(sizeof(float) * (size_t)N_tx * 2);
    float* r_ad = (float*)wsalloc(sizeof(float) * (size_t)N_ad * 2);
    if (off_b > ws_size) return;

    const int* offT[4] = { offs, offs + (size_t)(Nmax + 1), offs + 2 * (size_t)(Nmax + 1),
                           offs + 3 * (size_t)(Nmax + 1) };
    int* lstT[4] = { lst, lst + (size_t)E, lst + 2 * (size_t)E, lst + 3 * (size_t)E };

    // 1. prep
    k_prep_small<<<8, 256, 0, stream>>>(bl0, rel0, Wl1, bl1, Wr1, rel1, b0c, Pm, b1c);
    k_prep_Wt<<<(2 * 128 * 384 + 255) / 256, 256, 0, stream>>>(Wl0, Wr0, rel0, Wt);

    // 2. bf16 feature tables
    k_cvt_bf16<<<((N_tx * 128 / 8) + 255) / 256, 256, 0, stream>>>(x_tx, xbf_tx, N_tx * 128 / 8);
    k_cvt_bf16<<<((N_ad * 128 / 8) + 255) / 256, 256, 0, stream>>>(x_ad, xbf_ad, N_ad * 128 / 8);

    // 3. CSR build (4 types per dispatch)
    hipMemsetAsync(cnt, 0, sizeof(int) * 4 * (size_t)Nmax, stream);
    hipMemsetAsync(cur, 0, sizeof(int) * 4 * (size_t)Nmax, stream);
    const int gE = (E + 255) / 256;
    k_hist4<<<dim3(gE, 4), 256, 0, stream>>>(e_tt + E, e_aa + E, e_at + E, e_ta + E,
                                             cnt, Nmax, E);
    k_scan<<<4, 1024, 0, stream>>>(cnt, offs, Nmax, N_tx, N_ad);
    k_fill4<<<dim3(gE, 4), 256, 0, stream>>>(e_tt, e_aa, e_at, e_ta,
                                             offs, cur, lst, Nmax, E);

    const int gAggTx = (N_tx + 3) / 4, gAggAd = (N_ad + 3) / 4;
    const int gMMTx = (N_tx + 127) / 128, gMMAd = (N_ad + 127) / 128;

    // 4. layer 0 — tx
    k_agg_bf16<<<gAggTx, 256, 0, stream>>>(xbf_tx, offT[0], lstT[0], bufA, N_tx);
    k_agg_bf16<<<gAggTx, 256, 0, stream>>>(xbf_ad, offT[2], lstT[2], bufB, N_tx);
    k_gemm_bf16<<<gMMTx, 256, 0, stream>>>(bufA, bufB, xbf_tx, Wt, b0c, h_tx, N_tx);
    // 5. layer 0 — addr
    k_agg_bf16<<<gAggAd, 256, 0, stream>>>(xbf_ad, offT[1], lstT[1], bufA, N_ad);
    k_agg_bf16<<<gAggAd, 256, 0, stream>>>(xbf_tx, offT[3], lstT[3], bufB, N_ad);
    k_gemm_bf16<<<gMMAd, 256, 0, stream>>>(bufA, bufB, xbf_ad, Wt + 2 * 128 * 200,
                                           b0c + 128, h_ad, N_ad);

    // 6. layer 1 projection
    k_proj<<<gAggTx, 256, 0, stream>>>(h_tx, Pm, b1c, p_tt, p_ta, r_tx, N_tx);
    k_proj<<<gAggAd, 256, 0, stream>>>(h_ad, Pm + 768, b1c + 2, p_aa, p_at, r_ad, N_ad);

    // 7. final 2-dim aggregation + combine
    k_final<<<(N_tx + 255) / 256, 256, 0, stream>>>(r_tx, p_tt, offT[0], lstT[0],
                                                    p_at, offT[2], lstT[2], out, N_tx);
    k_final<<<(N_ad + 255) / 256, 256, 0, stream>>>(r_ad, p_aa, offT[1], lstT[1],
                                                    p_ta, offT[3], lstT[3],
                                                    out + (size_t)N_tx * 2, N_ad);
}

// Round 5
// 764.639 us; speedup vs baseline: 4.7137x; 1.4682x over previous
//
#include <hip/hip_runtime.h>
#include <cstdint>

typedef __attribute__((ext_vector_type(4))) float f32x4;
typedef __attribute__((ext_vector_type(8))) short bf16x8;
typedef __attribute__((ext_vector_type(8))) uint16_t u16x8;

#define BUCKET_SH 10
#define NBMAX 128

static __device__ __forceinline__ float bf2f(uint16_t u) {
    union { uint32_t i; float f; } v; v.i = ((uint32_t)u) << 16; return v.f;
}
// round-to-nearest-even f32 -> bf16
static __device__ __forceinline__ uint16_t f2bf(float f) {
    uint32_t x = __float_as_uint(f);
    uint32_t r = (x + 0x7fffu + ((x >> 16) & 1u)) >> 16;
    return (uint16_t)r;
}

// ---------------- prep (small): softmax-folded bias + layer-1 proj matrices ------------
__global__ void k_prep_small(const float* __restrict__ bl0, const float* __restrict__ rel0,
                             const float* __restrict__ Wl1, const float* __restrict__ bl1,
                             const float* __restrict__ Wr1, const float* __restrict__ rel1,
                             float* __restrict__ b0c, float* __restrict__ P,
                             float* __restrict__ b1c)
{
    float rw0[4], rw1[4];
    {
        float m0 = fmaxf(fmaxf(rel0[0], rel0[1]), fmaxf(rel0[2], rel0[3]));
        float m1 = fmaxf(fmaxf(rel1[0], rel1[1]), fmaxf(rel1[2], rel1[3]));
        float s0 = 0.f, s1 = 0.f;
        #pragma unroll
        for (int c = 0; c < 4; ++c) {
            rw0[c] = expf(rel0[c] - m0); s0 += rw0[c];
            rw1[c] = expf(rel1[c] - m1); s1 += rw1[c];
        }
        #pragma unroll
        for (int c = 0; c < 4; ++c) { rw0[c] /= s0; rw1[c] /= s1; }
    }
    const int i = blockIdx.x * blockDim.x + threadIdx.x;
    if (i < 256) {
        int side = i / 128, col = i % 128;
        int tA = side ? 1 : 0, tB = side ? 3 : 2;
        b0c[i] = rw0[tA] * bl0[tA * 128 + col] + rw0[tB] * bl0[tB * 128 + col];
    } else if (i < 256 + 1536) {
        int ip = i - 256;
        int side = ip / 768, rem = ip % 768;
        int k = rem / 6, c = rem % 6;
        float v;
        if (side == 0) {
            if (c < 2)      v = rw1[0] * Wl1[0 * 256 + k * 2 + c];
            else if (c < 4) v = rw1[3] * Wl1[3 * 256 + k * 2 + (c - 2)];
            else            v = rw1[0] * Wr1[0 * 256 + k * 2 + (c - 4)]
                              + rw1[2] * Wr1[2 * 256 + k * 2 + (c - 4)];
        } else {
            if (c < 2)      v = rw1[1] * Wl1[1 * 256 + k * 2 + c];
            else if (c < 4) v = rw1[2] * Wl1[2 * 256 + k * 2 + (c - 2)];
            else            v = rw1[1] * Wr1[1 * 256 + k * 2 + (c - 4)]
                              + rw1[3] * Wr1[3 * 256 + k * 2 + (c - 4)];
        }
        P[ip] = v;
    } else if (i < 256 + 1536 + 4) {
        int i4 = i - (256 + 1536);
        int side = i4 / 2, c = i4 % 2;
        b1c[i4] = side ? (rw1[1] * bl1[1 * 2 + c] + rw1[3] * bl1[3 * 2 + c])
                       : (rw1[0] * bl1[0 * 2 + c] + rw1[2] * bl1[2 * 2 + c]);
    }
}

// ---------------- prep: combined layer-0 weights, bf16, TRANSPOSED + padded ------------
__global__ void k_prep_Wt(const float* __restrict__ Wl0, const float* __restrict__ Wr0,
                          const float* __restrict__ rel0, uint16_t* __restrict__ Wt)
{
    float rw0[4];
    {
        float m0 = fmaxf(fmaxf(rel0[0], rel0[1]), fmaxf(rel0[2], rel0[3]));
        float s0 = 0.f;
        #pragma unroll
        for (int c = 0; c < 4; ++c) { rw0[c] = expf(rel0[c] - m0); s0 += rw0[c]; }
        #pragma unroll
        for (int c = 0; c < 4; ++c) rw0[c] /= s0;
    }
    const int i = blockIdx.x * blockDim.x + threadIdx.x;   // side*49152 + col*384 + k
    if (i >= 2 * 128 * 384) return;
    const int side = i / 49152;
    const int rem  = i % 49152;
    const int col = rem / 384, k = rem % 384;
    const int tA = side ? 1 : 0, tB = side ? 3 : 2;
    float v;
    if (k < 128)      v = rw0[tA] * Wl0[tA * 16384 + k * 128 + col];
    else if (k < 256) v = rw0[tB] * Wl0[tB * 16384 + (k - 128) * 128 + col];
    else              v = rw0[tA] * Wr0[tA * 16384 + (k - 256) * 128 + col]
                        + rw0[tB] * Wr0[tB * 16384 + (k - 256) * 128 + col];
    const int half = (k >= 192) ? 1 : 0;
    const int kp = k - half * 192;
    Wt[((size_t)(side * 2 + half) * 128 + col) * 200 + kp] = f2bf(v);
}

// ---------------- fp32 -> bf16 table conversion ----------------------------------------
__global__ void k_cvt_bf16(const float* __restrict__ x, uint16_t* __restrict__ y, int n8)
{
    const int i = blockIdx.x * blockDim.x + threadIdx.x;
    if (i >= n8) return;
    const float4* p = reinterpret_cast<const float4*>(x + (size_t)i * 8);
    float4 a = p[0], b = p[1];
    u16x8 o;
    o[0] = f2bf(a.x); o[1] = f2bf(a.y); o[2] = f2bf(a.z); o[3] = f2bf(a.w);
    o[4] = f2bf(b.x); o[5] = f2bf(b.y); o[6] = f2bf(b.z); o[7] = f2bf(b.w);
    *reinterpret_cast<u16x8*>(y + (size_t)i * 8) = o;
}

// ================= bucket-sorted CSR build =================
// R4's k_fill4 wrote 429 MB for 25.6 MB payload (random 4B scatter -> full-line
// writeback per store). Fix: counting-sort edges into 1024-node buckets so all
// node-level scatters are confined to small cache-resident windows.

// 1) bucket histogram: 1 LDS atomic/edge + 1 global add/bucket/block
__global__ void k_bhist(const int* __restrict__ d0, const int* __restrict__ d1,
                        const int* __restrict__ d2, const int* __restrict__ d3,
                        int* __restrict__ bhist, int E)
{
    const int t = blockIdx.y;
    const int* dst = t == 0 ? d0 : (t == 1 ? d1 : (t == 2 ? d2 : d3));
    __shared__ int h[NBMAX];
    const int tid = threadIdx.x;
    if (tid < NBMAX) h[tid] = 0;
    __syncthreads();
    const int base = blockIdx.x * 2048;
    #pragma unroll
    for (int q = 0; q < 8; ++q) {
        const int i = base + q * 256 + tid;
        if (i < E) atomicAdd(&h[dst[i] >> BUCKET_SH], 1);
    }
    __syncthreads();
    if (tid < NBMAX && h[tid]) atomicAdd(&bhist[t * NBMAX + tid], h[tid]);
}

// 2) tiny scan over 4 x NBMAX buckets -> bbase (exclusive) + gcur (running cursors)
__global__ void k_bscan(const int* __restrict__ bhist, int* __restrict__ bbase,
                        int* __restrict__ gcur)
{
    const int t = threadIdx.x;
    if (t >= 4) return;
    int run = 0;
    for (int b = 0; b < NBMAX; ++b) {
        bbase[t * (NBMAX + 1) + b] = run;
        gcur[t * NBMAX + b] = run;
        run += bhist[t * NBMAX + b];
    }
    bbase[t * (NBMAX + 1) + NBMAX] = run;
}

// 3) scatter (src,dst) pairs to bucket-contiguous storage; rank via LDS atomics,
//    per-(block,bucket) chunk reservation -> ~line-sized contiguous writes
__global__ void k_bscatter(const int* __restrict__ e0, const int* __restrict__ e1,
                           const int* __restrict__ e2, const int* __restrict__ e3,
                           int* __restrict__ gcur, uint2* __restrict__ pairs, int E)
{
    const int t = blockIdx.y;
    const int* ep = t == 0 ? e0 : (t == 1 ? e1 : (t == 2 ? e2 : e3));
    __shared__ int rank[NBMAX];
    __shared__ int chunk[NBMAX];
    const int tid = threadIdx.x;
    if (tid < NBMAX) rank[tid] = 0;
    __syncthreads();
    const int base = blockIdx.x * 2048;
    int s[8], d[8], r[8], b[8];
    #pragma unroll
    for (int q = 0; q < 8; ++q) {
        const int i = base + q * 256 + tid;
        if (i < E) {
            s[q] = ep[i];
            d[q] = ep[E + i];
            b[q] = d[q] >> BUCKET_SH;
            r[q] = atomicAdd(&rank[b[q]], 1);
        } else b[q] = -1;
    }
    __syncthreads();
    if (tid < NBMAX && rank[tid]) chunk[tid] = atomicAdd(&gcur[t * NBMAX + tid], rank[tid]);
    __syncthreads();
    #pragma unroll
    for (int q = 0; q < 8; ++q) {
        if (b[q] >= 0) {
            uint2 pr; pr.x = (uint32_t)s[q]; pr.y = (uint32_t)d[q];
            pairs[(size_t)t * E + chunk[b[q]] + r[q]] = pr;
        }
    }
}

// 4) per-node histogram, one block per bucket: pure LDS counters, coalesced writeout
__global__ void k_bnodehist(const uint2* __restrict__ pairs, const int* __restrict__ bbase,
                            int* __restrict__ cnt, int Nmax, int E, int N_tx, int N_ad)
{
    const int t = blockIdx.y, b = blockIdx.x;
    const int Nt = (t & 1) ? N_ad : N_tx;
    const int dlo = b << BUCKET_SH;
    if (dlo >= Nt) return;
    __shared__ int h[1 << BUCKET_SH];
    const int tid = threadIdx.x;
    #pragma unroll
    for (int q = 0; q < (1 << BUCKET_SH) / 256; ++q) h[tid + q * 256] = 0;
    __syncthreads();
    const int i0 = bbase[t * (NBMAX + 1) + b], i1 = bbase[t * (NBMAX + 1) + b + 1];
    for (int i = i0 + tid; i < i1; i += 256)
        atomicAdd(&h[pairs[(size_t)t * E + i].y - dlo], 1);
    __syncthreads();
    const int lim = min(1 << BUCKET_SH, Nt - dlo);
    #pragma unroll
    for (int q = 0; q < (1 << BUCKET_SH) / 256; ++q) {
        const int idx = tid + q * 256;
        if (idx < lim) cnt[(size_t)t * Nmax + dlo + idx] = h[idx];
    }
}

// 5) per-node exclusive scan (unchanged)
__global__ void k_scan(const int* __restrict__ cnt, int* __restrict__ off,
                       int Nmax, int N_tx, int N_ad)
{
    const int t = blockIdx.x;
    const int N = (t & 1) ? N_ad : N_tx;
    cnt += (size_t)t * Nmax;
    off += (size_t)t * (Nmax + 1);
    const int tid = threadIdx.x;
    const int lane = tid & 63, wv = tid >> 6;
    __shared__ int wtot[16];
    __shared__ int woff[16];
    __shared__ int running;
    if (tid == 0) running = 0;
    __syncthreads();
    for (int base = 0; base < N; base += 1024) {
        int i = base + tid;
        int v = (i < N) ? cnt[i] : 0;
        int incl = v;
        #pragma unroll
        for (int s = 1; s < 64; s <<= 1) {
            int u = __shfl_up(incl, s, 64);
            if (lane >= s) incl += u;
        }
        if (lane == 63) wtot[wv] = incl;
        __syncthreads();
        if (tid == 0) {
            int r = running;
            #pragma unroll
            for (int w = 0; w < 16; ++w) { woff[w] = r; r += wtot[w]; }
            running = r;
        }
        __syncthreads();
        if (i < N) off[i] = woff[wv] + incl - v;
        __syncthreads();
    }
    if (tid == 0) off[N] = running;
}

// 6) final fill, one block per bucket: LDS cursor, lst writes confined to ~64KB window
__global__ void k_bfill(const uint2* __restrict__ pairs, const int* __restrict__ bbase,
                        const int* __restrict__ off, int* __restrict__ lst,
                        int Nmax, int E, int N_tx, int N_ad)
{
    const int t = blockIdx.y, b = blockIdx.x;
    const int Nt = (t & 1) ? N_ad : N_tx;
    const int dlo = b << BUCKET_SH;
    if (dlo >= Nt) return;
    __shared__ int curl[1 << BUCKET_SH];
    const int tid = threadIdx.x;
    #pragma unroll
    for (int q = 0; q < (1 << BUCKET_SH) / 256; ++q) curl[tid + q * 256] = 0;
    __syncthreads();
    const int i0 = bbase[t * (NBMAX + 1) + b], i1 = bbase[t * (NBMAX + 1) + b + 1];
    const int* offT = off + (size_t)t * (Nmax + 1);
    int* lstT = lst + (size_t)t * E;
    for (int i = i0 + tid; i < i1; i += 256) {
        const uint2 pr = pairs[(size_t)t * E + i];
        const int d = (int)pr.y;
        const int p = atomicAdd(&curl[d - dlo], 1);
        lstT[offT[d] + p] = (int)pr.x;
    }
}

// ---------------- fallback CSR build (if pairs buffer doesn't fit ws) ------------------
__global__ void k_hist4(const int* __restrict__ d0, const int* __restrict__ d1,
                        const int* __restrict__ d2, const int* __restrict__ d3,
                        int* __restrict__ cnt, int Nmax, int E)
{
    const int t = blockIdx.y;
    const int* dst = t == 0 ? d0 : (t == 1 ? d1 : (t == 2 ? d2 : d3));
    const int i = blockIdx.x * blockDim.x + threadIdx.x;
    if (i < E) atomicAdd(&cnt[(size_t)t * Nmax + dst[i]], 1);
}

__global__ void k_fill4(const int* __restrict__ e0, const int* __restrict__ e1,
                        const int* __restrict__ e2, const int* __restrict__ e3,
                        const int* __restrict__ off, int* __restrict__ cur,
                        int* __restrict__ lst, int Nmax, int E)
{
    const int t = blockIdx.y;
    const int* ep = t == 0 ? e0 : (t == 1 ? e1 : (t == 2 ? e2 : e3));
    const int i = blockIdx.x * blockDim.x + threadIdx.x;
    if (i < E) {
        const int s = ep[i];
        const int d = ep[E + i];
        const int p = atomicAdd(&cur[(size_t)t * Nmax + d], 1);
        lst[(size_t)t * E + off[(size_t)t * (Nmax + 1) + d] + p] = s;
    }
}

// ---------------- mean aggregation, bf16, latency-optimized ----------------------------
__global__ void k_agg_bf16(const uint16_t* __restrict__ x,
                           const int* __restrict__ off, const int* __restrict__ lst,
                           uint16_t* __restrict__ buf, int N)
{
    const int wv = threadIdx.x >> 6;
    const int lane = threadIdx.x & 63;
    const int node = blockIdx.x * 4 + wv;
    if (node >= N) return;
    const int s0 = off[node], s1 = off[node + 1];
    const int d = lane * 2;
    float ax = 0.f, ay = 0.f, bx = 0.f, by = 0.f;
    for (int base = s0; base < s1; base += 64) {
        const int cnt = min(64, s1 - base);
        int idx = 0;
        if (lane < cnt) idx = lst[base + lane];
        int j = 0;
        for (; j + 4 <= cnt; j += 4) {
            const int sA = __shfl(idx, j);
            const int sB = __shfl(idx, j + 1);
            const int sC = __shfl(idx, j + 2);
            const int sD = __shfl(idx, j + 3);
            const uint32_t uA = *reinterpret_cast<const uint32_t*>(x + ((size_t)sA << 7) + d);
            const uint32_t uB = *reinterpret_cast<const uint32_t*>(x + ((size_t)sB << 7) + d);
            const uint32_t uC = *reinterpret_cast<const uint32_t*>(x + ((size_t)sC << 7) + d);
            const uint32_t uD = *reinterpret_cast<const uint32_t*>(x + ((size_t)sD << 7) + d);
            ax += bf2f((uint16_t)(uA & 0xffff)); ay += bf2f((uint16_t)(uA >> 16));
            bx += bf2f((uint16_t)(uB & 0xffff)); by += bf2f((uint16_t)(uB >> 16));
            ax += bf2f((uint16_t)(uC & 0xffff)); ay += bf2f((uint16_t)(uC >> 16));
            bx += bf2f((uint16_t)(uD & 0xffff)); by += bf2f((uint16_t)(uD >> 16));
        }
        for (; j < cnt; ++j) {
            const int sA = __shfl(idx, j);
            const uint32_t uA = *reinterpret_cast<const uint32_t*>(x + ((size_t)sA << 7) + d);
            ax += bf2f((uint16_t)(uA & 0xffff)); ay += bf2f((uint16_t)(uA >> 16));
        }
    }
    const int deg = s1 - s0;
    const float sc = 1.0f / (float)(deg > 0 ? deg : 1);
    const uint32_t o = (uint32_t)f2bf((ax + bx) * sc) | ((uint32_t)f2bf((ay + by) * sc) << 16);
    *reinterpret_cast<uint32_t*>(buf + (size_t)node * 128 + d) = o;
}

// ---------------- MFMA GEMM: h = relu([A0|A1|A2] @ W + bias), bf16 in/out --------------
__global__ __launch_bounds__(256, 2) void k_gemm_bf16(
    const uint16_t* __restrict__ A0, const uint16_t* __restrict__ A1,
    const uint16_t* __restrict__ A2, const uint16_t* __restrict__ Wt,
    const float* __restrict__ bias, uint16_t* __restrict__ h, int N)
{
    __shared__ uint16_t Wlds[128 * 200];
    const int tid = threadIdx.x;
    const int wv = tid >> 6, lane = tid & 63;
    const int l15 = lane & 15, lg = lane >> 4;
    const int wrow = blockIdx.x * 128 + wv * 32;

    f32x4 acc[2][8];
    #pragma unroll
    for (int a = 0; a < 2; ++a)
        #pragma unroll
        for (int b = 0; b < 8; ++b) acc[a][b] = (f32x4){0.f, 0.f, 0.f, 0.f};

    const uint16_t* const Aslot[3] = { A0, A1, A2 };

    #pragma unroll 1
    for (int half = 0; half < 2; ++half) {
        __syncthreads();
        const char* src = (const char*)(Wt + (size_t)half * 25600);
        char* dstbase = (char*)Wlds + wv * 1024;
        #pragma unroll
        for (int it = 0; it < 13; ++it) {
            const int off = it * 4096 + tid * 16;
            if (off < 51200)
                __builtin_amdgcn_global_load_lds((const uint32_t*)(src + off),
                                                 (uint32_t*)(dstbase + it * 4096),
                                                 16, 0, 0);
        }
        asm volatile("s_waitcnt vmcnt(0)" ::: "memory");
        __syncthreads();
        #pragma unroll
        for (int ks = 0; ks < 6; ++ks) {
            const int kg = half * 192 + ks * 32;
            const uint16_t* Ap = Aslot[kg >> 7];
            const int kl = (kg & 127) + lg * 8;
            const int r0 = wrow + l15;
            const int r1 = r0 + 16;
            const int c0 = (r0 < N) ? r0 : (N - 1);
            const int c1 = (r1 < N) ? r1 : (N - 1);
            const bf16x8 af0 = *reinterpret_cast<const bf16x8*>(Ap + (size_t)c0 * 128 + kl);
            const bf16x8 af1 = *reinterpret_cast<const bf16x8*>(Ap + (size_t)c1 * 128 + kl);
            #pragma unroll
            for (int cb = 0; cb < 8; ++cb) {
                const bf16x8 bf = *reinterpret_cast<const bf16x8*>(
                    Wlds + (size_t)(cb * 16 + l15) * 200 + ks * 32 + lg * 8);
                acc[0][cb] = __builtin_amdgcn_mfma_f32_16x16x32_bf16(af0, bf, acc[0][cb], 0, 0, 0);
                acc[1][cb] = __builtin_amdgcn_mfma_f32_16x16x32_bf16(af1, bf, acc[1][cb], 0, 0, 0);
            }
        }
    }
    #pragma unroll
    for (int cb = 0; cb < 8; ++cb) {
        const int col = cb * 16 + l15;
        const float bcol = bias[col];
        #pragma unroll
        for (int rb = 0; rb < 2; ++rb) {
            #pragma unroll
            for (int r = 0; r < 4; ++r) {
                const int row = wrow + rb * 16 + lg * 4 + r;
                if (row < N)
                    h[(size_t)row * 128 + col] = f2bf(fmaxf(acc[rb][cb][r] + bcol, 0.f));
            }
        }
    }
}

// ---------------- layer-1 projection: h(bf16)[n] @ P([128][6]) -> pA, pB, r ------------
__global__ void k_proj(const uint16_t* __restrict__ h, const float* __restrict__ P,
                       const float* __restrict__ b2,
                       float* __restrict__ pA, float* __restrict__ pB,
                       float* __restrict__ r, int N)
{
    const int wv = threadIdx.x >> 6, lane = threadIdx.x & 63;
    const int node = blockIdx.x * 4 + wv;
    if (node >= N) return;
    const uint32_t u = *reinterpret_cast<const uint32_t*>(h + (size_t)node * 128 + lane * 2);
    const float hx = bf2f((uint16_t)(u & 0xffff));
    const float hy = bf2f((uint16_t)(u >> 16));
    float o[6];
    #pragma unroll
    for (int c = 0; c < 6; ++c)
        o[c] = hx * P[(lane * 2) * 6 + c] + hy * P[(lane * 2 + 1) * 6 + c];
    #pragma unroll
    for (int s = 32; s >= 1; s >>= 1) {
        #pragma unroll
        for (int c = 0; c < 6; ++c) o[c] += __shfl_xor(o[c], s, 64);
    }
    if (lane == 0) {
        *reinterpret_cast<float2*>(&pA[(size_t)node * 2]) = make_float2(o[0], o[1]);
        *reinterpret_cast<float2*>(&pB[(size_t)node * 2]) = make_float2(o[2], o[3]);
        *reinterpret_cast<float2*>(&r[(size_t)node * 2])  = make_float2(o[4] + b2[0], o[5] + b2[1]);
    }
}

// ---------------- final: out[n] = r[n] + mean_A(pA[src]) + mean_B(pB[src]) -------------
__global__ void k_final(const float* __restrict__ r,
                        const float* __restrict__ pA, const int* __restrict__ offA,
                        const int* __restrict__ lstA,
                        const float* __restrict__ pB, const int* __restrict__ offB,
                        const int* __restrict__ lstB,
                        float* __restrict__ out, int N)
{
    const int n = blockIdx.x * blockDim.x + threadIdx.x;
    if (n >= N) return;
    float2 v = *reinterpret_cast<const float2*>(&r[(size_t)n * 2]);
    {
        int s0 = offA[n], s1 = offA[n + 1];
        float sx = 0.f, sy = 0.f;
        for (int e = s0; e < s1; ++e) {
            float2 p = *reinterpret_cast<const float2*>(&pA[(size_t)lstA[e] * 2]);
            sx += p.x; sy += p.y;
        }
        int d = s1 - s0; float sc = 1.0f / (float)(d > 0 ? d : 1);
        v.x += sx * sc; v.y += sy * sc;
    }
    {
        int s0 = offB[n], s1 = offB[n + 1];
        float sx = 0.f, sy = 0.f;
        for (int e = s0; e < s1; ++e) {
            float2 p = *reinterpret_cast<const float2*>(&pB[(size_t)lstB[e] * 2]);
            sx += p.x; sy += p.y;
        }
        int d = s1 - s0; float sc = 1.0f / (float)(d > 0 ? d : 1);
        v.x += sx * sc; v.y += sy * sc;
    }
    *reinterpret_cast<float2*>(&out[(size_t)n * 2]) = v;
}

extern "C" void kernel_launch(void* const* d_in, const int* in_sizes, int n_in,
                              void* d_out, int out_size, void* d_ws, size_t ws_size,
                              hipStream_t stream)
{
    const float* x_tx = (const float*)d_in[0];
    const float* x_ad = (const float*)d_in[1];
    const float* Wl0  = (const float*)d_in[2];
    const float* bl0  = (const float*)d_in[3];
    const float* Wr0  = (const float*)d_in[4];
    const float* rel0 = (const float*)d_in[5];
    const float* Wl1  = (const float*)d_in[6];
    const float* bl1  = (const float*)d_in[7];
    const float* Wr1  = (const float*)d_in[8];
    const float* rel1 = (const float*)d_in[9];
    const int* e_tt = (const int*)d_in[10];
    const int* e_aa = (const int*)d_in[11];
    const int* e_at = (const int*)d_in[12];
    const int* e_ta = (const int*)d_in[13];

    const int N_tx = in_sizes[0] / 128;
    const int N_ad = in_sizes[1] / 128;
    const int E    = in_sizes[10] / 2;
    const int Nmax = N_tx > N_ad ? N_tx : N_ad;
    float* out = (float*)d_out;
    (void)n_in; (void)out_size;

    char* wsb = (char*)d_ws;
    size_t off_b = 0;
    auto wsalloc = [&](size_t bytes) -> void* {
        void* p = (void*)(wsb + off_b);
        off_b += (bytes + 255) & ~(size_t)255;
        return p;
    };
    int* cnt  = (int*)wsalloc(sizeof(int) * 4 * (size_t)Nmax);
    int* cur  = (int*)wsalloc(sizeof(int) * 4 * (size_t)Nmax);
    int* offs = (int*)wsalloc(sizeof(int) * 4 * ((size_t)Nmax + 1));
    int* lst  = (int*)wsalloc(sizeof(int) * 4 * (size_t)E);
    uint16_t* xbf_tx = (uint16_t*)wsalloc(sizeof(uint16_t) * (size_t)N_tx * 128);
    uint16_t* xbf_ad = (uint16_t*)wsalloc(sizeof(uint16_t) * (size_t)N_ad * 128);
    uint16_t* bufA = (uint16_t*)wsalloc(sizeof(uint16_t) * (size_t)Nmax * 128);
    uint16_t* bufB = (uint16_t*)wsalloc(sizeof(uint16_t) * (size_t)Nmax * 128);
    uint16_t* h_tx = (uint16_t*)wsalloc(sizeof(uint16_t) * (size_t)N_tx * 128);
    uint16_t* h_ad = (uint16_t*)wsalloc(sizeof(uint16_t) * (size_t)N_ad * 128);
    uint16_t* Wt   = (uint16_t*)wsalloc(sizeof(uint16_t) * 2 * 2 * 128 * 200);
    float* b0c  = (float*)wsalloc(sizeof(float) * 2 * 128);
    float* Pm   = (float*)wsalloc(sizeof(float) * 2 * 128 * 6);
    float* b1c  = (float*)wsalloc(sizeof(float) * 4);
    float* p_tt = (float*)wsalloc(sizeof(float) * (size_t)N_tx * 2);
    float* p_ta = (float*)wsalloc(sizeof(float) * (size_t)N_tx * 2);
    float* p_aa = (float*)wsalloc(sizeof(float) * (size_t)N_ad * 2);
    float* p_at = (float*)wsalloc(sizeof(float) * (size_t)N_ad * 2);
    float* r_tx = (float*)wsalloc(sizeof(float) * (size_t)N_tx * 2);
    float* r_ad = (float*)wsalloc(sizeof(float) * (size_t)N_ad * 2);
    int* bhist = (int*)wsalloc(sizeof(int) * 4 * NBMAX);
    int* bbase = (int*)wsalloc(sizeof(int) * 4 * (NBMAX + 1));
    int* gcur  = (int*)wsalloc(sizeof(int) * 4 * NBMAX);
    if (off_b > ws_size) return;
    // bucket-sort pairs buffer (51 MB) — fall back to direct fill if it doesn't fit
    size_t need_pairs = off_b + ((sizeof(uint2) * 4 * (size_t)E + 255) & ~(size_t)255);
    uint2* pairs = (need_pairs <= ws_size && Nmax <= (NBMAX << BUCKET_SH))
                 ? (uint2*)wsalloc(sizeof(uint2) * 4 * (size_t)E) : nullptr;

    const int* offT[4] = { offs, offs + (size_t)(Nmax + 1), offs + 2 * (size_t)(Nmax + 1),
                           offs + 3 * (size_t)(Nmax + 1) };
    int* lstT[4] = { lst, lst + (size_t)E, lst + 2 * (size_t)E, lst + 3 * (size_t)E };

    // 1. prep
    k_prep_small<<<8, 256, 0, stream>>>(bl0, rel0, Wl1, bl1, Wr1, rel1, b0c, Pm, b1c);
    k_prep_Wt<<<(2 * 128 * 384 + 255) / 256, 256, 0, stream>>>(Wl0, Wr0, rel0, Wt);

    // 2. bf16 feature tables
    k_cvt_bf16<<<((N_tx * 128 / 8) + 255) / 256, 256, 0, stream>>>(x_tx, xbf_tx, N_tx * 128 / 8);
    k_cvt_bf16<<<((N_ad * 128 / 8) + 255) / 256, 256, 0, stream>>>(x_ad, xbf_ad, N_ad * 128 / 8);

    // 3. CSR build
    if (pairs) {
        const int gEb = (E + 2047) / 2048;
        hipMemsetAsync(bhist, 0, sizeof(int) * 4 * NBMAX, stream);
        k_bhist<<<dim3(gEb, 4), 256, 0, stream>>>(e_tt + E, e_aa + E, e_at + E, e_ta + E,
                                                  bhist, E);
        k_bscan<<<1, 4, 0, stream>>>(bhist, bbase, gcur);
        k_bscatter<<<dim3(gEb, 4), 256, 0, stream>>>(e_tt, e_aa, e_at, e_ta,
                                                     gcur, pairs, E);
        k_bnodehist<<<dim3(NBMAX, 4), 256, 0, stream>>>(pairs, bbase, cnt, Nmax, E,
                                                        N_tx, N_ad);
        k_scan<<<4, 1024, 0, stream>>>(cnt, offs, Nmax, N_tx, N_ad);
        k_bfill<<<dim3(NBMAX, 4), 256, 0, stream>>>(pairs, bbase, offs, lst, Nmax, E,
                                                    N_tx, N_ad);
    } else {
        hipMemsetAsync(cnt, 0, sizeof(int) * 4 * (size_t)Nmax, stream);
        hipMemsetAsync(cur, 0, sizeof(int) * 4 * (size_t)Nmax, stream);
        const int gE = (E + 255) / 256;
        k_hist4<<<dim3(gE, 4), 256, 0, stream>>>(e_tt + E, e_aa + E, e_at + E, e_ta + E,
                                                 cnt, Nmax, E);
        k_scan<<<4, 1024, 0, stream>>>(cnt, offs, Nmax, N_tx, N_ad);
        k_fill4<<<dim3(gE, 4), 256, 0, stream>>>(e_tt, e_aa, e_at, e_ta,
                                                 offs, cur, lst, Nmax, E);
    }

    const int gAggTx = (N_tx + 3) / 4, gAggAd = (N_ad + 3) / 4;
    const int gMMTx = (N_tx + 127) / 128, gMMAd = (N_ad + 127) / 128;

    // 4. layer 0 — tx
    k_agg_bf16<<<gAggTx, 256, 0, stream>>>(xbf_tx, offT[0], lstT[0], bufA, N_tx);
    k_agg_bf16<<<gAggTx, 256, 0, stream>>>(xbf_ad, offT[2], lstT[2], bufB, N_tx);
    k_gemm_bf16<<<gMMTx, 256, 0, stream>>>(bufA, bufB, xbf_tx, Wt, b0c, h_tx, N_tx);
    // 5. layer 0 — addr
    k_agg_bf16<<<gAggAd, 256, 0, stream>>>(xbf_ad, offT[1], lstT[1], bufA, N_ad);
    k_agg_bf16<<<gAggAd, 256, 0, stream>>>(xbf_tx, offT[3], lstT[3], bufB, N_ad);
    k_gemm_bf16<<<gMMAd, 256, 0, stream>>>(bufA, bufB, xbf_ad, Wt + 2 * 128 * 200,
                                           b0c + 128, h_ad, N_ad);

    // 6. layer 1 projection
    k_proj<<<gAggTx, 256, 0, stream>>>(h_tx, Pm, b1c, p_tt, p_ta, r_tx, N_tx);
    k_proj<<<gAggAd, 256, 0, stream>>>(h_ad, Pm + 768, b1c + 2, p_aa, p_at, r_ad, N_ad);

    // 7. final 2-dim aggregation + combine
    k_final<<<(N_tx + 255) / 256, 256, 0, stream>>>(r_tx, p_tt, offT[0], lstT[0],
                                                    p_at, offT[2], lstT[2], out, N_tx);
    k_final<<<(N_ad + 255) / 256, 256, 0, stream>>>(r_ad, p_aa, offT[1], lstT[1],
                                                    p_ta, offT[3], lstT[3],
                                                    out + (size_t)N_tx * 2, N_ad);
}

// Round 6
// 671.967 us; speedup vs baseline: 5.3637x; 1.1379x over previous
//
#include <hip/hip_runtime.h>
#include <cstdint>

typedef __attribute__((ext_vector_type(4))) float f32x4;
typedef __attribute__((ext_vector_type(8))) short bf16x8;
typedef __attribute__((ext_vector_type(8))) uint16_t u16x8;

#define BUCKET_SH 10
#define NBMAX 128

static __device__ __forceinline__ float bf2f(uint16_t u) {
    union { uint32_t i; float f; } v; v.i = ((uint32_t)u) << 16; return v.f;
}
// round-to-nearest-even f32 -> bf16
static __device__ __forceinline__ uint16_t f2bf(float f) {
    uint32_t x = __float_as_uint(f);
    uint32_t r = (x + 0x7fffu + ((x >> 16) & 1u)) >> 16;
    return (uint16_t)r;
}

// ---------------- prep (small): softmax-folded bias + layer-1 proj matrices ------------
__global__ void k_prep_small(const float* __restrict__ bl0, const float* __restrict__ rel0,
                             const float* __restrict__ Wl1, const float* __restrict__ bl1,
                             const float* __restrict__ Wr1, const float* __restrict__ rel1,
                             float* __restrict__ b0c, float* __restrict__ P,
                             float* __restrict__ b1c)
{
    float rw0[4], rw1[4];
    {
        float m0 = fmaxf(fmaxf(rel0[0], rel0[1]), fmaxf(rel0[2], rel0[3]));
        float m1 = fmaxf(fmaxf(rel1[0], rel1[1]), fmaxf(rel1[2], rel1[3]));
        float s0 = 0.f, s1 = 0.f;
        #pragma unroll
        for (int c = 0; c < 4; ++c) {
            rw0[c] = expf(rel0[c] - m0); s0 += rw0[c];
            rw1[c] = expf(rel1[c] - m1); s1 += rw1[c];
        }
        #pragma unroll
        for (int c = 0; c < 4; ++c) { rw0[c] /= s0; rw1[c] /= s1; }
    }
    const int i = blockIdx.x * blockDim.x + threadIdx.x;
    if (i < 256) {
        int side = i / 128, col = i % 128;
        int tA = side ? 1 : 0, tB = side ? 3 : 2;
        b0c[i] = rw0[tA] * bl0[tA * 128 + col] + rw0[tB] * bl0[tB * 128 + col];
    } else if (i < 256 + 1536) {
        int ip = i - 256;
        int side = ip / 768, rem = ip % 768;
        int k = rem / 6, c = rem % 6;
        float v;
        if (side == 0) {
            if (c < 2)      v = rw1[0] * Wl1[0 * 256 + k * 2 + c];
            else if (c < 4) v = rw1[3] * Wl1[3 * 256 + k * 2 + (c - 2)];
            else            v = rw1[0] * Wr1[0 * 256 + k * 2 + (c - 4)]
                              + rw1[2] * Wr1[2 * 256 + k * 2 + (c - 4)];
        } else {
            if (c < 2)      v = rw1[1] * Wl1[1 * 256 + k * 2 + c];
            else if (c < 4) v = rw1[2] * Wl1[2 * 256 + k * 2 + (c - 2)];
            else            v = rw1[1] * Wr1[1 * 256 + k * 2 + (c - 4)]
                              + rw1[3] * Wr1[3 * 256 + k * 2 + (c - 4)];
        }
        P[ip] = v;
    } else if (i < 256 + 1536 + 4) {
        int i4 = i - (256 + 1536);
        int side = i4 / 2, c = i4 % 2;
        b1c[i4] = side ? (rw1[1] * bl1[1 * 2 + c] + rw1[3] * bl1[3 * 2 + c])
                       : (rw1[0] * bl1[0 * 2 + c] + rw1[2] * bl1[2 * 2 + c]);
    }
}

// ---------------- prep: combined layer-0 weights, bf16, TRANSPOSED + padded ------------
__global__ void k_prep_Wt(const float* __restrict__ Wl0, const float* __restrict__ Wr0,
                          const float* __restrict__ rel0, uint16_t* __restrict__ Wt)
{
    float rw0[4];
    {
        float m0 = fmaxf(fmaxf(rel0[0], rel0[1]), fmaxf(rel0[2], rel0[3]));
        float s0 = 0.f;
        #pragma unroll
        for (int c = 0; c < 4; ++c) { rw0[c] = expf(rel0[c] - m0); s0 += rw0[c]; }
        #pragma unroll
        for (int c = 0; c < 4; ++c) rw0[c] /= s0;
    }
    const int i = blockIdx.x * blockDim.x + threadIdx.x;   // side*49152 + col*384 + k
    if (i >= 2 * 128 * 384) return;
    const int side = i / 49152;
    const int rem  = i % 49152;
    const int col = rem / 384, k = rem % 384;
    const int tA = side ? 1 : 0, tB = side ? 3 : 2;
    float v;
    if (k < 128)      v = rw0[tA] * Wl0[tA * 16384 + k * 128 + col];
    else if (k < 256) v = rw0[tB] * Wl0[tB * 16384 + (k - 128) * 128 + col];
    else              v = rw0[tA] * Wr0[tA * 16384 + (k - 256) * 128 + col]
                        + rw0[tB] * Wr0[tB * 16384 + (k - 256) * 128 + col];
    const int half = (k >= 192) ? 1 : 0;
    const int kp = k - half * 192;
    Wt[((size_t)(side * 2 + half) * 128 + col) * 200 + kp] = f2bf(v);
}

// ---------------- fp32 -> bf16 table conversion ----------------------------------------
__global__ void k_cvt_bf16(const float* __restrict__ x, uint16_t* __restrict__ y, int n8)
{
    const int i = blockIdx.x * blockDim.x + threadIdx.x;
    if (i >= n8) return;
    const float4* p = reinterpret_cast<const float4*>(x + (size_t)i * 8);
    float4 a = p[0], b = p[1];
    u16x8 o;
    o[0] = f2bf(a.x); o[1] = f2bf(a.y); o[2] = f2bf(a.z); o[3] = f2bf(a.w);
    o[4] = f2bf(b.x); o[5] = f2bf(b.y); o[6] = f2bf(b.z); o[7] = f2bf(b.w);
    *reinterpret_cast<u16x8*>(y + (size_t)i * 8) = o;
}

// ================= bucket-sorted CSR build =================
// Edges counting-sorted into 1024-node buckets; all node-level scatters confined to
// cache-resident windows. Pairs packed to 32 bits: src(<=17b) << 10 | dst_local(10b).

// 1) bucket histogram: 1 LDS atomic/edge + 1 global add/bucket/block
__global__ void k_bhist(const int* __restrict__ d0, const int* __restrict__ d1,
                        const int* __restrict__ d2, const int* __restrict__ d3,
                        int* __restrict__ bhist, int E)
{
    const int t = blockIdx.y;
    const int* dst = t == 0 ? d0 : (t == 1 ? d1 : (t == 2 ? d2 : d3));
    __shared__ int h[NBMAX];
    const int tid = threadIdx.x;
    if (tid < NBMAX) h[tid] = 0;
    __syncthreads();
    const int base = blockIdx.x * 2048;
    #pragma unroll
    for (int q = 0; q < 8; ++q) {
        const int i = base + q * 256 + tid;
        if (i < E) atomicAdd(&h[dst[i] >> BUCKET_SH], 1);
    }
    __syncthreads();
    if (tid < NBMAX && h[tid]) atomicAdd(&bhist[t * NBMAX + tid], h[tid]);
}

// 2) tiny scan over 4 x NBMAX buckets -> bbase (exclusive) + gcur (running cursors)
__global__ void k_bscan(const int* __restrict__ bhist, int* __restrict__ bbase,
                        int* __restrict__ gcur)
{
    const int t = threadIdx.x;
    if (t >= 4) return;
    int run = 0;
    for (int b = 0; b < NBMAX; ++b) {
        bbase[t * (NBMAX + 1) + b] = run;
        gcur[t * NBMAX + b] = run;
        run += bhist[t * NBMAX + b];
    }
    bbase[t * (NBMAX + 1) + NBMAX] = run;
}

// 3) scatter packed (src,dst_local) to bucket-contiguous storage
__global__ void k_bscatter(const int* __restrict__ e0, const int* __restrict__ e1,
                           const int* __restrict__ e2, const int* __restrict__ e3,
                           int* __restrict__ gcur, uint32_t* __restrict__ pairs, int E)
{
    const int t = blockIdx.y;
    const int* ep = t == 0 ? e0 : (t == 1 ? e1 : (t == 2 ? e2 : e3));
    __shared__ int rank[NBMAX];
    __shared__ int chunk[NBMAX];
    const int tid = threadIdx.x;
    if (tid < NBMAX) rank[tid] = 0;
    __syncthreads();
    const int base = blockIdx.x * 2048;
    int s[8], d[8], r[8], b[8];
    #pragma unroll
    for (int q = 0; q < 8; ++q) {
        const int i = base + q * 256 + tid;
        if (i < E) {
            s[q] = ep[i];
            d[q] = ep[E + i];
            b[q] = d[q] >> BUCKET_SH;
            r[q] = atomicAdd(&rank[b[q]], 1);
        } else b[q] = -1;
    }
    __syncthreads();
    if (tid < NBMAX && rank[tid]) chunk[tid] = atomicAdd(&gcur[t * NBMAX + tid], rank[tid]);
    __syncthreads();
    #pragma unroll
    for (int q = 0; q < 8; ++q) {
        if (b[q] >= 0)
            pairs[(size_t)t * E + chunk[b[q]] + r[q]] =
                ((uint32_t)s[q] << BUCKET_SH) | ((uint32_t)d[q] & ((1u << BUCKET_SH) - 1));
    }
}

// 4) per-node histogram, one block per bucket: pure LDS counters, coalesced writeout
__global__ void k_bnodehist(const uint32_t* __restrict__ pairs, const int* __restrict__ bbase,
                            int* __restrict__ cnt, int Nmax, int E, int N_tx, int N_ad)
{
    const int t = blockIdx.y, b = blockIdx.x;
    const int Nt = (t & 1) ? N_ad : N_tx;
    const int dlo = b << BUCKET_SH;
    if (dlo >= Nt) return;
    __shared__ int h[1 << BUCKET_SH];
    const int tid = threadIdx.x;
    #pragma unroll
    for (int q = 0; q < (1 << BUCKET_SH) / 256; ++q) h[tid + q * 256] = 0;
    __syncthreads();
    const int i0 = bbase[t * (NBMAX + 1) + b], i1 = bbase[t * (NBMAX + 1) + b + 1];
    for (int i = i0 + tid; i < i1; i += 256)
        atomicAdd(&h[pairs[(size_t)t * E + i] & ((1u << BUCKET_SH) - 1)], 1);
    __syncthreads();
    const int lim = min(1 << BUCKET_SH, Nt - dlo);
    #pragma unroll
    for (int q = 0; q < (1 << BUCKET_SH) / 256; ++q) {
        const int idx = tid + q * 256;
        if (idx < lim) cnt[(size_t)t * Nmax + dlo + idx] = h[idx];
    }
}

// 5) per-node offsets WITHOUT a global scan: off[d] = bbase[bucket] + in-bucket
//    exclusive scan of cnt. One block per bucket, fully parallel (replaces R5's
//    4-block serial k_scan: 82 us at 0.7% occupancy).
__global__ void k_bscanoff(const int* __restrict__ cnt, const int* __restrict__ bbase,
                           int* __restrict__ off, int Nmax, int N_tx, int N_ad)
{
    const int t = blockIdx.y, b = blockIdx.x;
    const int Nt = (t & 1) ? N_ad : N_tx;
    const int dlo = b << BUCKET_SH;
    if (dlo >= Nt) return;
    const int tid = threadIdx.x;                 // 1024 threads
    const int lane = tid & 63, wv = tid >> 6;
    __shared__ int wtot[16];
    __shared__ int woff[16];
    const int lim = min(1 << BUCKET_SH, Nt - dlo);
    int v = (tid < lim) ? cnt[(size_t)t * Nmax + dlo + tid] : 0;
    int incl = v;
    #pragma unroll
    for (int s = 1; s < 64; s <<= 1) {
        int u = __shfl_up(incl, s, 64);
        if (lane >= s) incl += u;
    }
    if (lane == 63) wtot[wv] = incl;
    __syncthreads();
    if (tid == 0) {
        int r = 0;
        #pragma unroll
        for (int w = 0; w < 16; ++w) { woff[w] = r; r += wtot[w]; }
    }
    __syncthreads();
    const int base = bbase[t * (NBMAX + 1) + b];
    if (tid < lim)
        off[(size_t)t * (Nmax + 1) + dlo + tid] = base + woff[wv] + incl - v;
    if (tid == 0 && dlo + lim == Nt)
        off[(size_t)t * (Nmax + 1) + Nt] = bbase[t * (NBMAX + 1) + NBMAX];
}

// 6) final fill, one block per bucket: LDS cursor, lst writes confined to ~64KB window
__global__ void k_bfill(const uint32_t* __restrict__ pairs, const int* __restrict__ bbase,
                        const int* __restrict__ off, int* __restrict__ lst,
                        int Nmax, int E, int N_tx, int N_ad)
{
    const int t = blockIdx.y, b = blockIdx.x;
    const int Nt = (t & 1) ? N_ad : N_tx;
    const int dlo = b << BUCKET_SH;
    if (dlo >= Nt) return;
    __shared__ int curl[1 << BUCKET_SH];
    const int tid = threadIdx.x;
    #pragma unroll
    for (int q = 0; q < (1 << BUCKET_SH) / 256; ++q) curl[tid + q * 256] = 0;
    __syncthreads();
    const int i0 = bbase[t * (NBMAX + 1) + b], i1 = bbase[t * (NBMAX + 1) + b + 1];
    const int* offT = off + (size_t)t * (Nmax + 1);
    int* lstT = lst + (size_t)t * E;
    for (int i = i0 + tid; i < i1; i += 256) {
        const uint32_t pr = pairs[(size_t)t * E + i];
        const int dl = (int)(pr & ((1u << BUCKET_SH) - 1));
        const int p = atomicAdd(&curl[dl], 1);
        lstT[offT[dlo + dl] + p] = (int)(pr >> BUCKET_SH);
    }
}

// ---------------- fallback CSR build (if pairs buffer doesn't fit ws) ------------------
__global__ void k_hist4(const int* __restrict__ d0, const int* __restrict__ d1,
                        const int* __restrict__ d2, const int* __restrict__ d3,
                        int* __restrict__ cnt, int Nmax, int E)
{
    const int t = blockIdx.y;
    const int* dst = t == 0 ? d0 : (t == 1 ? d1 : (t == 2 ? d2 : d3));
    const int i = blockIdx.x * blockDim.x + threadIdx.x;
    if (i < E) atomicAdd(&cnt[(size_t)t * Nmax + dst[i]], 1);
}

__global__ void k_fill4(const int* __restrict__ e0, const int* __restrict__ e1,
                        const int* __restrict__ e2, const int* __restrict__ e3,
                        const int* __restrict__ off, int* __restrict__ cur,
                        int* __restrict__ lst, int Nmax, int E)
{
    const int t = blockIdx.y;
    const int* ep = t == 0 ? e0 : (t == 1 ? e1 : (t == 2 ? e2 : e3));
    const int i = blockIdx.x * blockDim.x + threadIdx.x;
    if (i < E) {
        const int s = ep[i];
        const int d = ep[E + i];
        const int p = atomicAdd(&cur[(size_t)t * Nmax + d], 1);
        lst[(size_t)t * E + off[(size_t)t * (Nmax + 1) + d] + p] = s;
    }
}

__global__ void k_scan(const int* __restrict__ cnt, int* __restrict__ off,
                       int Nmax, int N_tx, int N_ad)
{
    const int t = blockIdx.x;
    const int N = (t & 1) ? N_ad : N_tx;
    cnt += (size_t)t * Nmax;
    off += (size_t)t * (Nmax + 1);
    const int tid = threadIdx.x;
    const int lane = tid & 63, wv = tid >> 6;
    __shared__ int wtot[16];
    __shared__ int woff[16];
    __shared__ int running;
    if (tid == 0) running = 0;
    __syncthreads();
    for (int base = 0; base < N; base += 1024) {
        int i = base + tid;
        int v = (i < N) ? cnt[i] : 0;
        int incl = v;
        #pragma unroll
        for (int s = 1; s < 64; s <<= 1) {
            int u = __shfl_up(incl, s, 64);
            if (lane >= s) incl += u;
        }
        if (lane == 63) wtot[wv] = incl;
        __syncthreads();
        if (tid == 0) {
            int r = running;
            #pragma unroll
            for (int w = 0; w < 16; ++w) { woff[w] = r; r += wtot[w]; }
            running = r;
        }
        __syncthreads();
        if (i < N) off[i] = woff[wv] + incl - v;
        __syncthreads();
    }
    if (tid == 0) off[N] = running;
}

// ---------------- mean aggregation, bf16, latency-optimized; y selects stream ----------
__global__ void k_agg2(const uint16_t* __restrict__ xA, const int* __restrict__ offA,
                       const int* __restrict__ lstA, uint16_t* __restrict__ bufA,
                       const uint16_t* __restrict__ xB, const int* __restrict__ offB,
                       const int* __restrict__ lstB, uint16_t* __restrict__ bufB,
                       int N)
{
    const uint16_t* x; const int* off; const int* lst; uint16_t* buf;
    if (blockIdx.y == 0) { x = xA; off = offA; lst = lstA; buf = bufA; }
    else                 { x = xB; off = offB; lst = lstB; buf = bufB; }
    const int wv = threadIdx.x >> 6;
    const int lane = threadIdx.x & 63;
    const int node = blockIdx.x * 4 + wv;
    if (node >= N) return;
    const int s0 = off[node], s1 = off[node + 1];
    const int d = lane * 2;
    float ax = 0.f, ay = 0.f, bx = 0.f, by = 0.f;
    for (int base = s0; base < s1; base += 64) {
        const int cnt = min(64, s1 - base);
        int idx = 0;
        if (lane < cnt) idx = lst[base + lane];
        int j = 0;
        for (; j + 4 <= cnt; j += 4) {
            const int sA = __shfl(idx, j);
            const int sB = __shfl(idx, j + 1);
            const int sC = __shfl(idx, j + 2);
            const int sD = __shfl(idx, j + 3);
            const uint32_t uA = *reinterpret_cast<const uint32_t*>(x + ((size_t)sA << 7) + d);
            const uint32_t uB = *reinterpret_cast<const uint32_t*>(x + ((size_t)sB << 7) + d);
            const uint32_t uC = *reinterpret_cast<const uint32_t*>(x + ((size_t)sC << 7) + d);
            const uint32_t uD = *reinterpret_cast<const uint32_t*>(x + ((size_t)sD << 7) + d);
            ax += bf2f((uint16_t)(uA & 0xffff)); ay += bf2f((uint16_t)(uA >> 16));
            bx += bf2f((uint16_t)(uB & 0xffff)); by += bf2f((uint16_t)(uB >> 16));
            ax += bf2f((uint16_t)(uC & 0xffff)); ay += bf2f((uint16_t)(uC >> 16));
            bx += bf2f((uint16_t)(uD & 0xffff)); by += bf2f((uint16_t)(uD >> 16));
        }
        for (; j < cnt; ++j) {
            const int sA = __shfl(idx, j);
            const uint32_t uA = *reinterpret_cast<const uint32_t*>(x + ((size_t)sA << 7) + d);
            ax += bf2f((uint16_t)(uA & 0xffff)); ay += bf2f((uint16_t)(uA >> 16));
        }
    }
    const int deg = s1 - s0;
    const float sc = 1.0f / (float)(deg > 0 ? deg : 1);
    const uint32_t o = (uint32_t)f2bf((ax + bx) * sc) | ((uint32_t)f2bf((ay + by) * sc) << 16);
    *reinterpret_cast<uint32_t*>(buf + (size_t)node * 128 + d) = o;
}

// ---------------- MFMA GEMM: h = relu([A0|A1|A2] @ W + bias), bf16 in/out --------------
__global__ __launch_bounds__(256, 2) void k_gemm_bf16(
    const uint16_t* __restrict__ A0, const uint16_t* __restrict__ A1,
    const uint16_t* __restrict__ A2, const uint16_t* __restrict__ Wt,
    const float* __restrict__ bias, uint16_t* __restrict__ h, int N)
{
    __shared__ uint16_t Wlds[128 * 200];
    const int tid = threadIdx.x;
    const int wv = tid >> 6, lane = tid & 63;
    const int l15 = lane & 15, lg = lane >> 4;
    const int wrow = blockIdx.x * 128 + wv * 32;

    f32x4 acc[2][8];
    #pragma unroll
    for (int a = 0; a < 2; ++a)
        #pragma unroll
        for (int b = 0; b < 8; ++b) acc[a][b] = (f32x4){0.f, 0.f, 0.f, 0.f};

    const uint16_t* const Aslot[3] = { A0, A1, A2 };

    #pragma unroll 1
    for (int half = 0; half < 2; ++half) {
        __syncthreads();
        const char* src = (const char*)(Wt + (size_t)half * 25600);
        char* dstbase = (char*)Wlds + wv * 1024;
        #pragma unroll
        for (int it = 0; it < 13; ++it) {
            const int off = it * 4096 + tid * 16;
            if (off < 51200)
                __builtin_amdgcn_global_load_lds((const uint32_t*)(src + off),
                                                 (uint32_t*)(dstbase + it * 4096),
                                                 16, 0, 0);
        }
        asm volatile("s_waitcnt vmcnt(0)" ::: "memory");
        __syncthreads();
        #pragma unroll
        for (int ks = 0; ks < 6; ++ks) {
            const int kg = half * 192 + ks * 32;
            const uint16_t* Ap = Aslot[kg >> 7];
            const int kl = (kg & 127) + lg * 8;
            const int r0 = wrow + l15;
            const int r1 = r0 + 16;
            const int c0 = (r0 < N) ? r0 : (N - 1);
            const int c1 = (r1 < N) ? r1 : (N - 1);
            const bf16x8 af0 = *reinterpret_cast<const bf16x8*>(Ap + (size_t)c0 * 128 + kl);
            const bf16x8 af1 = *reinterpret_cast<const bf16x8*>(Ap + (size_t)c1 * 128 + kl);
            #pragma unroll
            for (int cb = 0; cb < 8; ++cb) {
                const bf16x8 bf = *reinterpret_cast<const bf16x8*>(
                    Wlds + (size_t)(cb * 16 + l15) * 200 + ks * 32 + lg * 8);
                acc[0][cb] = __builtin_amdgcn_mfma_f32_16x16x32_bf16(af0, bf, acc[0][cb], 0, 0, 0);
                acc[1][cb] = __builtin_amdgcn_mfma_f32_16x16x32_bf16(af1, bf, acc[1][cb], 0, 0, 0);
            }
        }
    }
    #pragma unroll
    for (int cb = 0; cb < 8; ++cb) {
        const int col = cb * 16 + l15;
        const float bcol = bias[col];
        #pragma unroll
        for (int rb = 0; rb < 2; ++rb) {
            #pragma unroll
            for (int r = 0; r < 4; ++r) {
                const int row = wrow + rb * 16 + lg * 4 + r;
                if (row < N)
                    h[(size_t)row * 128 + col] = f2bf(fmaxf(acc[rb][cb][r] + bcol, 0.f));
            }
        }
    }
}

// ---------------- layer-1 projection: h(bf16)[n] @ P([128][6]) -> pA, pB, r ------------
__global__ void k_proj(const uint16_t* __restrict__ h, const float* __restrict__ P,
                       const float* __restrict__ b2,
                       float* __restrict__ pA, float* __restrict__ pB,
                       float* __restrict__ r, int N)
{
    const int wv = threadIdx.x >> 6, lane = threadIdx.x & 63;
    const int node = blockIdx.x * 4 + wv;
    if (node >= N) return;
    const uint32_t u = *reinterpret_cast<const uint32_t*>(h + (size_t)node * 128 + lane * 2);
    const float hx = bf2f((uint16_t)(u & 0xffff));
    const float hy = bf2f((uint16_t)(u >> 16));
    float o[6];
    #pragma unroll
    for (int c = 0; c < 6; ++c)
        o[c] = hx * P[(lane * 2) * 6 + c] + hy * P[(lane * 2 + 1) * 6 + c];
    #pragma unroll
    for (int s = 32; s >= 1; s >>= 1) {
        #pragma unroll
        for (int c = 0; c < 6; ++c) o[c] += __shfl_xor(o[c], s, 64);
    }
    if (lane == 0) {
        *reinterpret_cast<float2*>(&pA[(size_t)node * 2]) = make_float2(o[0], o[1]);
        *reinterpret_cast<float2*>(&pB[(size_t)node * 2]) = make_float2(o[2], o[3]);
        *reinterpret_cast<float2*>(&r[(size_t)node * 2])  = make_float2(o[4] + b2[0], o[5] + b2[1]);
    }
}

// ---------------- final: out[n] = r[n] + mean_A(pA[src]) + mean_B(pB[src]) -------------
__global__ void k_final(const float* __restrict__ r,
                        const float* __restrict__ pA, const int* __restrict__ offA,
                        const int* __restrict__ lstA,
                        const float* __restrict__ pB, const int* __restrict__ offB,
                        const int* __restrict__ lstB,
                        float* __restrict__ out, int N)
{
    const int n = blockIdx.x * blockDim.x + threadIdx.x;
    if (n >= N) return;
    float2 v = *reinterpret_cast<const float2*>(&r[(size_t)n * 2]);
    {
        int s0 = offA[n], s1 = offA[n + 1];
        float sx = 0.f, sy = 0.f;
        for (int e = s0; e < s1; ++e) {
            float2 p = *reinterpret_cast<const float2*>(&pA[(size_t)lstA[e] * 2]);
            sx += p.x; sy += p.y;
        }
        int d = s1 - s0; float sc = 1.0f / (float)(d > 0 ? d : 1);
        v.x += sx * sc; v.y += sy * sc;
    }
    {
        int s0 = offB[n], s1 = offB[n + 1];
        float sx = 0.f, sy = 0.f;
        for (int e = s0; e < s1; ++e) {
            float2 p = *reinterpret_cast<const float2*>(&pB[(size_t)lstB[e] * 2]);
            sx += p.x; sy += p.y;
        }
        int d = s1 - s0; float sc = 1.0f / (float)(d > 0 ? d : 1);
        v.x += sx * sc; v.y += sy * sc;
    }
    *reinterpret_cast<float2*>(&out[(size_t)n * 2]) = v;
}

extern "C" void kernel_launch(void* const* d_in, const int* in_sizes, int n_in,
                              void* d_out, int out_size, void* d_ws, size_t ws_size,
                              hipStream_t stream)
{
    const float* x_tx = (const float*)d_in[0];
    const float* x_ad = (const float*)d_in[1];
    const float* Wl0  = (const float*)d_in[2];
    const float* bl0  = (const float*)d_in[3];
    const float* Wr0  = (const float*)d_in[4];
    const float* rel0 = (const float*)d_in[5];
    const float* Wl1  = (const float*)d_in[6];
    const float* bl1  = (const float*)d_in[7];
    const float* Wr1  = (const float*)d_in[8];
    const float* rel1 = (const float*)d_in[9];
    const int* e_tt = (const int*)d_in[10];
    const int* e_aa = (const int*)d_in[11];
    const int* e_at = (const int*)d_in[12];
    const int* e_ta = (const int*)d_in[13];

    const int N_tx = in_sizes[0] / 128;
    const int N_ad = in_sizes[1] / 128;
    const int E    = in_sizes[10] / 2;
    const int Nmax = N_tx > N_ad ? N_tx : N_ad;
    float* out = (float*)d_out;
    (void)n_in; (void)out_size;

    char* wsb = (char*)d_ws;
    size_t off_b = 0;
    auto wsalloc = [&](size_t bytes) -> void* {
        void* p = (void*)(wsb + off_b);
        off_b += (bytes + 255) & ~(size_t)255;
        return p;
    };
    int* cnt  = (int*)wsalloc(sizeof(int) * 4 * (size_t)Nmax);
    int* cur  = (int*)wsalloc(sizeof(int) * 4 * (size_t)Nmax);
    int* offs = (int*)wsalloc(sizeof(int) * 4 * ((size_t)Nmax + 1));
    int* lst  = (int*)wsalloc(sizeof(int) * 4 * (size_t)E);
    uint16_t* xbf_tx = (uint16_t*)wsalloc(sizeof(uint16_t) * (size_t)N_tx * 128);
    uint16_t* xbf_ad = (uint16_t*)wsalloc(sizeof(uint16_t) * (size_t)N_ad * 128);
    uint16_t* bufA = (uint16_t*)wsalloc(sizeof(uint16_t) * (size_t)Nmax * 128);
    uint16_t* bufB = (uint16_t*)wsalloc(sizeof(uint16_t) * (size_t)Nmax * 128);
    uint16_t* h_tx = (uint16_t*)wsalloc(sizeof(uint16_t) * (size_t)N_tx * 128);
    uint16_t* h_ad = (uint16_t*)wsalloc(sizeof(uint16_t) * (size_t)N_ad * 128);
    uint16_t* Wt   = (uint16_t*)wsalloc(sizeof(uint16_t) * 2 * 2 * 128 * 200);
    float* b0c  = (float*)wsalloc(sizeof(float) * 2 * 128);
    float* Pm   = (float*)wsalloc(sizeof(float) * 2 * 128 * 6);
    float* b1c  = (float*)wsalloc(sizeof(float) * 4);
    float* p_tt = (float*)wsalloc(sizeof(float) * (size_t)N_tx * 2);
    float* p_ta = (float*)wsalloc(sizeof(float) * (size_t)N_tx * 2);
    float* p_aa = (float*)wsalloc(sizeof(float) * (size_t)N_ad * 2);
    float* p_at = (float*)wsalloc(sizeof(float) * (size_t)N_ad * 2);
    float* r_tx = (float*)wsalloc(sizeof(float) * (size_t)N_tx * 2);
    float* r_ad = (float*)wsalloc(sizeof(float) * (size_t)N_ad * 2);
    int* bhist = (int*)wsalloc(sizeof(int) * 4 * NBMAX);
    int* bbase = (int*)wsalloc(sizeof(int) * 4 * (NBMAX + 1));
    int* gcur  = (int*)wsalloc(sizeof(int) * 4 * NBMAX);
    if (off_b > ws_size) return;
    // packed bucket-sort pairs buffer (25.6 MB); fallback if it doesn't fit
    size_t need_pairs = off_b + ((sizeof(uint32_t) * 4 * (size_t)E + 255) & ~(size_t)255);
    uint32_t* pairs = (need_pairs <= ws_size && Nmax <= (NBMAX << BUCKET_SH))
                    ? (uint32_t*)wsalloc(sizeof(uint32_t) * 4 * (size_t)E) : nullptr;

    const int* offT[4] = { offs, offs + (size_t)(Nmax + 1), offs + 2 * (size_t)(Nmax + 1),
                           offs + 3 * (size_t)(Nmax + 1) };
    int* lstT[4] = { lst, lst + (size_t)E, lst + 2 * (size_t)E, lst + 3 * (size_t)E };

    // 1. prep
    k_prep_small<<<8, 256, 0, stream>>>(bl0, rel0, Wl1, bl1, Wr1, rel1, b0c, Pm, b1c);
    k_prep_Wt<<<(2 * 128 * 384 + 255) / 256, 256, 0, stream>>>(Wl0, Wr0, rel0, Wt);

    // 2. bf16 feature tables
    k_cvt_bf16<<<((N_tx * 128 / 8) + 255) / 256, 256, 0, stream>>>(x_tx, xbf_tx, N_tx * 128 / 8);
    k_cvt_bf16<<<((N_ad * 128 / 8) + 255) / 256, 256, 0, stream>>>(x_ad, xbf_ad, N_ad * 128 / 8);

    // 3. CSR build
    if (pairs) {
        const int gEb = (E + 2047) / 2048;
        hipMemsetAsync(bhist, 0, sizeof(int) * 4 * NBMAX, stream);
        k_bhist<<<dim3(gEb, 4), 256, 0, stream>>>(e_tt + E, e_aa + E, e_at + E, e_ta + E,
                                                  bhist, E);
        k_bscan<<<1, 4, 0, stream>>>(bhist, bbase, gcur);
        k_bscatter<<<dim3(gEb, 4), 256, 0, stream>>>(e_tt, e_aa, e_at, e_ta,
                                                     gcur, pairs, E);
        k_bnodehist<<<dim3(NBMAX, 4), 256, 0, stream>>>(pairs, bbase, cnt, Nmax, E,
                                                        N_tx, N_ad);
        k_bscanoff<<<dim3(NBMAX, 4), 1024, 0, stream>>>(cnt, bbase, offs, Nmax,
                                                        N_tx, N_ad);
        k_bfill<<<dim3(NBMAX, 4), 256, 0, stream>>>(pairs, bbase, offs, lst, Nmax, E,
                                                    N_tx, N_ad);
    } else {
        hipMemsetAsync(cnt, 0, sizeof(int) * 4 * (size_t)Nmax, stream);
        hipMemsetAsync(cur, 0, sizeof(int) * 4 * (size_t)Nmax, stream);
        const int gE = (E + 255) / 256;
        k_hist4<<<dim3(gE, 4), 256, 0, stream>>>(e_tt + E, e_aa + E, e_at + E, e_ta + E,
                                                 cnt, Nmax, E);
        k_scan<<<4, 1024, 0, stream>>>(cnt, offs, Nmax, N_tx, N_ad);
        k_fill4<<<dim3(gE, 4), 256, 0, stream>>>(e_tt, e_aa, e_at, e_ta,
                                                 offs, cur, lst, Nmax, E);
    }

    const int gAggTx = (N_tx + 3) / 4, gAggAd = (N_ad + 3) / 4;
    const int gMMTx = (N_tx + 127) / 128, gMMAd = (N_ad + 127) / 128;

    // 4. layer 0 — tx (both agg streams in one dispatch)
    k_agg2<<<dim3(gAggTx, 2), 256, 0, stream>>>(xbf_tx, offT[0], lstT[0], bufA,
                                                xbf_ad, offT[2], lstT[2], bufB, N_tx);
    k_gemm_bf16<<<gMMTx, 256, 0, stream>>>(bufA, bufB, xbf_tx, Wt, b0c, h_tx, N_tx);
    // 5. layer 0 — addr
    k_agg2<<<dim3(gAggAd, 2), 256, 0, stream>>>(xbf_ad, offT[1], lstT[1], bufA,
                                                xbf_tx, offT[3], lstT[3], bufB, N_ad);
    k_gemm_bf16<<<gMMAd, 256, 0, stream>>>(bufA, bufB, xbf_ad, Wt + 2 * 128 * 200,
                                           b0c + 128, h_ad, N_ad);

    // 6. layer 1 projection
    k_proj<<<gAggTx, 256, 0, stream>>>(h_tx, Pm, b1c, p_tt, p_ta, r_tx, N_tx);
    k_proj<<<gAggAd, 256, 0, stream>>>(h_ad, Pm + 768, b1c + 2, p_aa, p_at, r_ad, N_ad);

    // 7. final 2-dim aggregation + combine
    k_final<<<(N_tx + 255) / 256, 256, 0, stream>>>(r_tx, p_tt, offT[0], lstT[0],
                                                    p_at, offT[2], lstT[2], out, N_tx);
    k_final<<<(N_ad + 255) / 256, 256, 0, stream>>>(r_ad, p_aa, offT[1], lstT[1],
                                                    p_ta, offT[3], lstT[3],
                                                    out + (size_t)N_tx * 2, N_ad);
}

// Round 7
// 642.970 us; speedup vs baseline: 5.6056x; 1.0451x over previous
//
#include <hip/hip_runtime.h>
#include <cstdint>

typedef __attribute__((ext_vector_type(4))) float f32x4;
typedef __attribute__((ext_vector_type(8))) short bf16x8;
typedef __attribute__((ext_vector_type(8))) uint16_t u16x8;

#define BUCKET_SH 10
#define NBMAX 128

static __device__ __forceinline__ float bf2f(uint16_t u) {
    union { uint32_t i; float f; } v; v.i = ((uint32_t)u) << 16; return v.f;
}
// round-to-nearest-even f32 -> bf16
static __device__ __forceinline__ uint16_t f2bf(float f) {
    uint32_t x = __float_as_uint(f);
    uint32_t r = (x + 0x7fffu + ((x >> 16) & 1u)) >> 16;
    return (uint16_t)r;
}

// ---------------- unified prep: Wt (bf16 transposed combined W0) + biases + P + b1c
//                  + zero bhist (saves a memset dispatch) ---------------------------
__global__ void k_prep(const float* __restrict__ Wl0, const float* __restrict__ bl0,
                       const float* __restrict__ Wr0, const float* __restrict__ rel0,
                       const float* __restrict__ Wl1, const float* __restrict__ bl1,
                       const float* __restrict__ Wr1, const float* __restrict__ rel1,
                       uint16_t* __restrict__ Wt, float* __restrict__ b0c,
                       float* __restrict__ P, float* __restrict__ b1c,
                       int* __restrict__ bhist)
{
    float rw0[4], rw1[4];
    {
        float m0 = fmaxf(fmaxf(rel0[0], rel0[1]), fmaxf(rel0[2], rel0[3]));
        float m1 = fmaxf(fmaxf(rel1[0], rel1[1]), fmaxf(rel1[2], rel1[3]));
        float s0 = 0.f, s1 = 0.f;
        #pragma unroll
        for (int c = 0; c < 4; ++c) {
            rw0[c] = expf(rel0[c] - m0); s0 += rw0[c];
            rw1[c] = expf(rel1[c] - m1); s1 += rw1[c];
        }
        #pragma unroll
        for (int c = 0; c < 4; ++c) { rw0[c] /= s0; rw1[c] /= s1; }
    }
    const int i = blockIdx.x * blockDim.x + threadIdx.x;
    const int NWT = 2 * 128 * 384;
    if (i < NWT) {
        const int side = i / 49152;
        const int rem  = i % 49152;
        const int col = rem / 384, k = rem % 384;
        const int tA = side ? 1 : 0, tB = side ? 3 : 2;
        float v;
        if (k < 128)      v = rw0[tA] * Wl0[tA * 16384 + k * 128 + col];
        else if (k < 256) v = rw0[tB] * Wl0[tB * 16384 + (k - 128) * 128 + col];
        else              v = rw0[tA] * Wr0[tA * 16384 + (k - 256) * 128 + col]
                            + rw0[tB] * Wr0[tB * 16384 + (k - 256) * 128 + col];
        const int half = (k >= 192) ? 1 : 0;
        Wt[((size_t)(side * 2 + half) * 128 + col) * 200 + (k - half * 192)] = f2bf(v);
        return;
    }
    const int j = i - NWT;
    if (j < 256) {
        int side = j / 128, col = j % 128;
        int tA = side ? 1 : 0, tB = side ? 3 : 2;
        b0c[j] = rw0[tA] * bl0[tA * 128 + col] + rw0[tB] * bl0[tB * 128 + col];
    } else if (j < 256 + 1536) {
        int ip = j - 256;
        int side = ip / 768, rem = ip % 768;
        int k = rem / 6, c = rem % 6;
        float v;
        if (side == 0) {
            if (c < 2)      v = rw1[0] * Wl1[0 * 256 + k * 2 + c];
            else if (c < 4) v = rw1[3] * Wl1[3 * 256 + k * 2 + (c - 2)];
            else            v = rw1[0] * Wr1[0 * 256 + k * 2 + (c - 4)]
                              + rw1[2] * Wr1[2 * 256 + k * 2 + (c - 4)];
        } else {
            if (c < 2)      v = rw1[1] * Wl1[1 * 256 + k * 2 + c];
            else if (c < 4) v = rw1[2] * Wl1[2 * 256 + k * 2 + (c - 2)];
            else            v = rw1[1] * Wr1[1 * 256 + k * 2 + (c - 4)]
                              + rw1[3] * Wr1[3 * 256 + k * 2 + (c - 4)];
        }
        P[ip] = v;
    } else if (j < 1792 + 4) {
        int i4 = j - 1792;
        int side = i4 / 2, c = i4 % 2;
        b1c[i4] = side ? (rw1[1] * bl1[1 * 2 + c] + rw1[3] * bl1[3 * 2 + c])
                       : (rw1[0] * bl1[0 * 2 + c] + rw1[2] * bl1[2 * 2 + c]);
    } else if (j < 1796 + 4 * NBMAX) {
        bhist[j - 1796] = 0;
    }
}

// ---------------- fp32 -> bf16 table conversion, both tables in one dispatch -----------
__global__ void k_cvt2(const float* __restrict__ xA, uint16_t* __restrict__ yA, int n8A,
                       const float* __restrict__ xB, uint16_t* __restrict__ yB, int n8B)
{
    const float* x; uint16_t* y; int n8;
    if (blockIdx.y == 0) { x = xA; y = yA; n8 = n8A; }
    else                 { x = xB; y = yB; n8 = n8B; }
    const int i = blockIdx.x * blockDim.x + threadIdx.x;
    if (i >= n8) return;
    const float4* p = reinterpret_cast<const float4*>(x + (size_t)i * 8);
    float4 a = p[0], b = p[1];
    u16x8 o;
    o[0] = f2bf(a.x); o[1] = f2bf(a.y); o[2] = f2bf(a.z); o[3] = f2bf(a.w);
    o[4] = f2bf(b.x); o[5] = f2bf(b.y); o[6] = f2bf(b.z); o[7] = f2bf(b.w);
    *reinterpret_cast<u16x8*>(y + (size_t)i * 8) = o;
}

// ================= bucket-sorted CSR build =================
// 1) bucket histogram
__global__ void k_bhist(const int* __restrict__ d0, const int* __restrict__ d1,
                        const int* __restrict__ d2, const int* __restrict__ d3,
                        int* __restrict__ bhist, int E)
{
    const int t = blockIdx.y;
    const int* dst = t == 0 ? d0 : (t == 1 ? d1 : (t == 2 ? d2 : d3));
    __shared__ int h[NBMAX];
    const int tid = threadIdx.x;
    if (tid < NBMAX) h[tid] = 0;
    __syncthreads();
    const int base = blockIdx.x * 2048;
    #pragma unroll
    for (int q = 0; q < 8; ++q) {
        const int i = base + q * 256 + tid;
        if (i < E) atomicAdd(&h[dst[i] >> BUCKET_SH], 1);
    }
    __syncthreads();
    if (tid < NBMAX && h[tid]) atomicAdd(&bhist[t * NBMAX + tid], h[tid]);
}

// 2) tiny scan over 4 x NBMAX buckets
__global__ void k_bscan(const int* __restrict__ bhist, int* __restrict__ bbase,
                        int* __restrict__ gcur)
{
    const int t = threadIdx.x;
    if (t >= 4) return;
    int run = 0;
    for (int b = 0; b < NBMAX; ++b) {
        bbase[t * (NBMAX + 1) + b] = run;
        gcur[t * NBMAX + b] = run;
        run += bhist[t * NBMAX + b];
    }
    bbase[t * (NBMAX + 1) + NBMAX] = run;
}

// 3) scatter packed (src<<10 | dst_local) to bucket-contiguous storage
__global__ void k_bscatter(const int* __restrict__ e0, const int* __restrict__ e1,
                           const int* __restrict__ e2, const int* __restrict__ e3,
                           int* __restrict__ gcur, uint32_t* __restrict__ pairs, int E)
{
    const int t = blockIdx.y;
    const int* ep = t == 0 ? e0 : (t == 1 ? e1 : (t == 2 ? e2 : e3));
    __shared__ int rank[NBMAX];
    __shared__ int chunk[NBMAX];
    const int tid = threadIdx.x;
    if (tid < NBMAX) rank[tid] = 0;
    __syncthreads();
    const int base = blockIdx.x * 2048;
    int s[8], d[8], r[8], b[8];
    #pragma unroll
    for (int q = 0; q < 8; ++q) {
        const int i = base + q * 256 + tid;
        if (i < E) {
            s[q] = ep[i];
            d[q] = ep[E + i];
            b[q] = d[q] >> BUCKET_SH;
            r[q] = atomicAdd(&rank[b[q]], 1);
        } else b[q] = -1;
    }
    __syncthreads();
    if (tid < NBMAX && rank[tid]) chunk[tid] = atomicAdd(&gcur[t * NBMAX + tid], rank[tid]);
    __syncthreads();
    #pragma unroll
    for (int q = 0; q < 8; ++q) {
        if (b[q] >= 0)
            pairs[(size_t)t * E + chunk[b[q]] + r[q]] =
                ((uint32_t)s[q] << BUCKET_SH) | ((uint32_t)d[q] & ((1u << BUCKET_SH) - 1));
    }
}

// 4) FUSED per-bucket CSR: count (LDS) -> in-LDS scan -> write off -> place lst.
//    Replaces R6's bnodehist + bscanoff + bfill (3 dispatches + global cnt round-trip).
__global__ void k_bcsr(const uint32_t* __restrict__ pairs, const int* __restrict__ bbase,
                       int* __restrict__ off, int* __restrict__ lst,
                       int Nmax, int E, int N_tx, int N_ad)
{
    const int t = blockIdx.y, b = blockIdx.x;
    const int Nt = (t & 1) ? N_ad : N_tx;
    const int dlo = b << BUCKET_SH;
    if (dlo >= Nt) return;
    __shared__ int h[1 << BUCKET_SH];
    __shared__ int wtot[4];
    __shared__ int woff[4];
    const int tid = threadIdx.x;
    const int lane = tid & 63, wv = tid >> 6;
    #pragma unroll
    for (int q = 0; q < 4; ++q) h[tid + q * 256] = 0;
    __syncthreads();
    const int i0 = bbase[t * (NBMAX + 1) + b], i1 = bbase[t * (NBMAX + 1) + b + 1];
    const uint32_t* pr = pairs + (size_t)t * E;
    for (int i = i0 + tid; i < i1; i += 256)
        atomicAdd(&h[pr[i] & ((1u << BUCKET_SH) - 1)], 1);
    __syncthreads();
    // in-LDS exclusive scan; thread owns elements [tid*4, tid*4+4)
    const int a0 = h[tid * 4 + 0], a1 = h[tid * 4 + 1],
              a2 = h[tid * 4 + 2], a3 = h[tid * 4 + 3];
    const int s = a0 + a1 + a2 + a3;
    int incl = s;
    #pragma unroll
    for (int sh = 1; sh < 64; sh <<= 1) {
        int u = __shfl_up(incl, sh, 64);
        if (lane >= sh) incl += u;
    }
    if (lane == 63) wtot[wv] = incl;
    __syncthreads();
    if (tid == 0) {
        int r = 0;
        #pragma unroll
        for (int w = 0; w < 4; ++w) { woff[w] = r; r += wtot[w]; }
    }
    __syncthreads();
    const int excl = woff[wv] + incl - s;
    const int o0 = i0 + excl, o1 = o0 + a0, o2 = o1 + a1, o3 = o2 + a2;
    const int lim = min(1 << BUCKET_SH, Nt - dlo);
    int* offT = off + (size_t)t * (Nmax + 1) + dlo;
    const int base4 = tid * 4;
    if (base4 + 0 < lim) offT[base4 + 0] = o0;
    if (base4 + 1 < lim) offT[base4 + 1] = o1;
    if (base4 + 2 < lim) offT[base4 + 2] = o2;
    if (base4 + 3 < lim) offT[base4 + 3] = o3;
    if (tid == 0 && dlo + lim == Nt)
        off[(size_t)t * (Nmax + 1) + Nt] = bbase[t * (NBMAX + 1) + NBMAX];
    // reuse h as running per-node cursors (bucket-local)
    h[base4 + 0] = o0 - i0; h[base4 + 1] = o1 - i0;
    h[base4 + 2] = o2 - i0; h[base4 + 3] = o3 - i0;
    __syncthreads();
    int* lstT = lst + (size_t)t * E;
    for (int i = i0 + tid; i < i1; i += 256) {
        const uint32_t p = pr[i];
        const int dl = (int)(p & ((1u << BUCKET_SH) - 1));
        const int pos = atomicAdd(&h[dl], 1);
        lstT[i0 + pos] = (int)(p >> BUCKET_SH);
    }
}

// ---------------- fallback CSR build (if pairs buffer doesn't fit ws) ------------------
__global__ void k_hist4(const int* __restrict__ d0, const int* __restrict__ d1,
                        const int* __restrict__ d2, const int* __restrict__ d3,
                        int* __restrict__ cnt, int Nmax, int E)
{
    const int t = blockIdx.y;
    const int* dst = t == 0 ? d0 : (t == 1 ? d1 : (t == 2 ? d2 : d3));
    const int i = blockIdx.x * blockDim.x + threadIdx.x;
    if (i < E) atomicAdd(&cnt[(size_t)t * Nmax + dst[i]], 1);
}

__global__ void k_fill4(const int* __restrict__ e0, const int* __restrict__ e1,
                        const int* __restrict__ e2, const int* __restrict__ e3,
                        const int* __restrict__ off, int* __restrict__ cur,
                        int* __restrict__ lst, int Nmax, int E)
{
    const int t = blockIdx.y;
    const int* ep = t == 0 ? e0 : (t == 1 ? e1 : (t == 2 ? e2 : e3));
    const int i = blockIdx.x * blockDim.x + threadIdx.x;
    if (i < E) {
        const int s = ep[i];
        const int d = ep[E + i];
        const int p = atomicAdd(&cur[(size_t)t * Nmax + d], 1);
        lst[(size_t)t * E + off[(size_t)t * (Nmax + 1) + d] + p] = s;
    }
}

__global__ void k_scan(const int* __restrict__ cnt, int* __restrict__ off,
                       int Nmax, int N_tx, int N_ad)
{
    const int t = blockIdx.x;
    const int N = (t & 1) ? N_ad : N_tx;
    cnt += (size_t)t * Nmax;
    off += (size_t)t * (Nmax + 1);
    const int tid = threadIdx.x;
    const int lane = tid & 63, wv = tid >> 6;
    __shared__ int wtot[16];
    __shared__ int woff[16];
    __shared__ int running;
    if (tid == 0) running = 0;
    __syncthreads();
    for (int base = 0; base < N; base += 1024) {
        int i = base + tid;
        int v = (i < N) ? cnt[i] : 0;
        int incl = v;
        #pragma unroll
        for (int s = 1; s < 64; s <<= 1) {
            int u = __shfl_up(incl, s, 64);
            if (lane >= s) incl += u;
        }
        if (lane == 63) wtot[wv] = incl;
        __syncthreads();
        if (tid == 0) {
            int r = running;
            #pragma unroll
            for (int w = 0; w < 16; ++w) { woff[w] = r; r += wtot[w]; }
            running = r;
        }
        __syncthreads();
        if (i < N) off[i] = woff[wv] + incl - v;
        __syncthreads();
    }
    if (tid == 0) off[N] = running;
}

// ---------------- mean aggregation, 16B gathers: 16 lanes/edge, 4 edges/iter -----------
// R6 used 4B/lane gathers: 64 loads + ~8 VALU/edge -> mixed VALU/BW regime (50%/45%).
// Now each lane loads uint4 (8 bf16); lane group (lane>>4) selects the edge; per edge:
// 1/4 load, ~5 VALU (hi-half cvt is a single AND). End: shfl_xor(16,32) reduce,
// lane<16 packed 16B store.
__global__ void k_agg2(const uint16_t* __restrict__ xA, const int* __restrict__ offA,
                       const int* __restrict__ lstA, uint16_t* __restrict__ bufA,
                       const uint16_t* __restrict__ xB, const int* __restrict__ offB,
                       const int* __restrict__ lstB, uint16_t* __restrict__ bufB,
                       int N)
{
    const uint16_t* x; const int* off; const int* lst; uint16_t* buf;
    if (blockIdx.y == 0) { x = xA; off = offA; lst = lstA; buf = bufA; }
    else                 { x = xB; off = offB; lst = lstB; buf = bufB; }
    const int wv = threadIdx.x >> 6;
    const int lane = threadIdx.x & 63;
    const int node = blockIdx.x * 4 + wv;
    if (node >= N) return;
    const int s0 = off[node], s1 = off[node + 1];
    const int grp = lane >> 4;          // edge slot 0..3
    const int sub = lane & 15;          // dim chunk: dims [sub*8, sub*8+8)
    float acc[8];
    #pragma unroll
    for (int k = 0; k < 8; ++k) acc[k] = 0.f;

    for (int base = s0; base < s1; base += 64) {
        const int cnt = min(64, s1 - base);
        int idx = 0;
        if (lane < cnt) idx = lst[base + lane];
        for (int j = 0; j < cnt; j += 4) {
            const int e = j + grp;
            const int srcn = __shfl(idx, e);
            if (e < cnt) {
                const uint4 u = *reinterpret_cast<const uint4*>(
                    x + ((size_t)srcn << 7) + (sub << 3));
                acc[0] += __uint_as_float(u.x << 16);
                acc[1] += __uint_as_float(u.x & 0xffff0000u);
                acc[2] += __uint_as_float(u.y << 16);
                acc[3] += __uint_as_float(u.y & 0xffff0000u);
                acc[4] += __uint_as_float(u.z << 16);
                acc[5] += __uint_as_float(u.z & 0xffff0000u);
                acc[6] += __uint_as_float(u.w << 16);
                acc[7] += __uint_as_float(u.w & 0xffff0000u);
            }
        }
    }
    // combine the 4 edge slots (lanes sub, sub+16, sub+32, sub+48)
    #pragma unroll
    for (int k = 0; k < 8; ++k) {
        acc[k] += __shfl_xor(acc[k], 16, 64);
        acc[k] += __shfl_xor(acc[k], 32, 64);
    }
    const int deg = s1 - s0;
    const float sc = 1.0f / (float)(deg > 0 ? deg : 1);
    if (lane < 16) {
        uint4 w;
        w.x = (uint32_t)f2bf(acc[0] * sc) | ((uint32_t)f2bf(acc[1] * sc) << 16);
        w.y = (uint32_t)f2bf(acc[2] * sc) | ((uint32_t)f2bf(acc[3] * sc) << 16);
        w.z = (uint32_t)f2bf(acc[4] * sc) | ((uint32_t)f2bf(acc[5] * sc) << 16);
        w.w = (uint32_t)f2bf(acc[6] * sc) | ((uint32_t)f2bf(acc[7] * sc) << 16);
        *reinterpret_cast<uint4*>(buf + ((size_t)node << 7) + (sub << 3)) = w;
    }
}

// ---------------- MFMA GEMM: h = relu([A0|A1|A2] @ W + bias), bf16 in/out --------------
__global__ __launch_bounds__(256, 2) void k_gemm_bf16(
    const uint16_t* __restrict__ A0, const uint16_t* __restrict__ A1,
    const uint16_t* __restrict__ A2, const uint16_t* __restrict__ Wt,
    const float* __restrict__ bias, uint16_t* __restrict__ h, int N)
{
    __shared__ uint16_t Wlds[128 * 200];
    const int tid = threadIdx.x;
    const int wv = tid >> 6, lane = tid & 63;
    const int l15 = lane & 15, lg = lane >> 4;
    const int wrow = blockIdx.x * 128 + wv * 32;

    f32x4 acc[2][8];
    #pragma unroll
    for (int a = 0; a < 2; ++a)
        #pragma unroll
        for (int b = 0; b < 8; ++b) acc[a][b] = (f32x4){0.f, 0.f, 0.f, 0.f};

    const uint16_t* const Aslot[3] = { A0, A1, A2 };

    #pragma unroll 1
    for (int half = 0; half < 2; ++half) {
        __syncthreads();
        const char* src = (const char*)(Wt + (size_t)half * 25600);
        char* dstbase = (char*)Wlds + wv * 1024;
        #pragma unroll
        for (int it = 0; it < 13; ++it) {
            const int off = it * 4096 + tid * 16;
            if (off < 51200)
                __builtin_amdgcn_global_load_lds((const uint32_t*)(src + off),
                                                 (uint32_t*)(dstbase + it * 4096),
                                                 16, 0, 0);
        }
        asm volatile("s_waitcnt vmcnt(0)" ::: "memory");
        __syncthreads();
        #pragma unroll
        for (int ks = 0; ks < 6; ++ks) {
            const int kg = half * 192 + ks * 32;
            const uint16_t* Ap = Aslot[kg >> 7];
            const int kl = (kg & 127) + lg * 8;
            const int r0 = wrow + l15;
            const int r1 = r0 + 16;
            const int c0 = (r0 < N) ? r0 : (N - 1);
            const int c1 = (r1 < N) ? r1 : (N - 1);
            const bf16x8 af0 = *reinterpret_cast<const bf16x8*>(Ap + (size_t)c0 * 128 + kl);
            const bf16x8 af1 = *reinterpret_cast<const bf16x8*>(Ap + (size_t)c1 * 128 + kl);
            #pragma unroll
            for (int cb = 0; cb < 8; ++cb) {
                const bf16x8 bf = *reinterpret_cast<const bf16x8*>(
                    Wlds + (size_t)(cb * 16 + l15) * 200 + ks * 32 + lg * 8);
                acc[0][cb] = __builtin_amdgcn_mfma_f32_16x16x32_bf16(af0, bf, acc[0][cb], 0, 0, 0);
                acc[1][cb] = __builtin_amdgcn_mfma_f32_16x16x32_bf16(af1, bf, acc[1][cb], 0, 0, 0);
            }
        }
    }
    #pragma unroll
    for (int cb = 0; cb < 8; ++cb) {
        const int col = cb * 16 + l15;
        const float bcol = bias[col];
        #pragma unroll
        for (int rb = 0; rb < 2; ++rb) {
            #pragma unroll
            for (int r = 0; r < 4; ++r) {
                const int row = wrow + rb * 16 + lg * 4 + r;
                if (row < N)
                    h[(size_t)row * 128 + col] = f2bf(fmaxf(acc[rb][cb][r] + bcol, 0.f));
            }
        }
    }
}

// ---------------- layer-1 projection (both sides, y selects) ---------------------------
__global__ void k_proj2(const uint16_t* __restrict__ hA, const float* __restrict__ PA,
                        const float* __restrict__ b2A, float* __restrict__ pAA,
                        float* __restrict__ pBA, float* __restrict__ rA, int NA,
                        const uint16_t* __restrict__ hB, const float* __restrict__ PB,
                        const float* __restrict__ b2B, float* __restrict__ pAB,
                        float* __restrict__ pBB, float* __restrict__ rB, int NB)
{
    const uint16_t* h; const float* P; const float* b2;
    float* pA; float* pB; float* r; int N;
    if (blockIdx.y == 0) { h = hA; P = PA; b2 = b2A; pA = pAA; pB = pBA; r = rA; N = NA; }
    else                 { h = hB; P = PB; b2 = b2B; pA = pAB; pB = pBB; r = rB; N = NB; }
    const int wv = threadIdx.x >> 6, lane = threadIdx.x & 63;
    const int node = blockIdx.x * 4 + wv;
    if (node >= N) return;
    const uint32_t u = *reinterpret_cast<const uint32_t*>(h + (size_t)node * 128 + lane * 2);
    const float hx = bf2f((uint16_t)(u & 0xffff));
    const float hy = bf2f((uint16_t)(u >> 16));
    float o[6];
    #pragma unroll
    for (int c = 0; c < 6; ++c)
        o[c] = hx * P[(lane * 2) * 6 + c] + hy * P[(lane * 2 + 1) * 6 + c];
    #pragma unroll
    for (int s = 32; s >= 1; s >>= 1) {
        #pragma unroll
        for (int c = 0; c < 6; ++c) o[c] += __shfl_xor(o[c], s, 64);
    }
    if (lane == 0) {
        *reinterpret_cast<float2*>(&pA[(size_t)node * 2]) = make_float2(o[0], o[1]);
        *reinterpret_cast<float2*>(&pB[(size_t)node * 2]) = make_float2(o[2], o[3]);
        *reinterpret_cast<float2*>(&r[(size_t)node * 2])  = make_float2(o[4] + b2[0], o[5] + b2[1]);
    }
}

// ---------------- final (both sides, y selects) ----------------------------------------
__global__ void k_final2(const float* __restrict__ rA,
                         const float* __restrict__ pAA, const int* __restrict__ offAA,
                         const int* __restrict__ lstAA,
                         const float* __restrict__ pBA, const int* __restrict__ offBA,
                         const int* __restrict__ lstBA, float* __restrict__ outA, int NA,
                         const float* __restrict__ rB,
                         const float* __restrict__ pAB, const int* __restrict__ offAB,
                         const int* __restrict__ lstAB,
                         const float* __restrict__ pBB, const int* __restrict__ offBB,
                         const int* __restrict__ lstBB, float* __restrict__ outB, int NB)
{
    const float* r; const float* pA; const int* offA; const int* lstA;
    const float* pB; const int* offB; const int* lstB; float* out; int N;
    if (blockIdx.y == 0) { r = rA; pA = pAA; offA = offAA; lstA = lstAA;
                           pB = pBA; offB = offBA; lstB = lstBA; out = outA; N = NA; }
    else                 { r = rB; pA = pAB; offA = offAB; lstA = lstAB;
                           pB = pBB; offB = offBB; lstB = lstBB; out = outB; N = NB; }
    const int n = blockIdx.x * blockDim.x + threadIdx.x;
    if (n >= N) return;
    float2 v = *reinterpret_cast<const float2*>(&r[(size_t)n * 2]);
    {
        int s0 = offA[n], s1 = offA[n + 1];
        float sx = 0.f, sy = 0.f;
        for (int e = s0; e < s1; ++e) {
            float2 p = *reinterpret_cast<const float2*>(&pA[(size_t)lstA[e] * 2]);
            sx += p.x; sy += p.y;
        }
        int d = s1 - s0; float sc = 1.0f / (float)(d > 0 ? d : 1);
        v.x += sx * sc; v.y += sy * sc;
    }
    {
        int s0 = offB[n], s1 = offB[n + 1];
        float sx = 0.f, sy = 0.f;
        for (int e = s0; e < s1; ++e) {
            float2 p = *reinterpret_cast<const float2*>(&pB[(size_t)lstB[e] * 2]);
            sx += p.x; sy += p.y;
        }
        int d = s1 - s0; float sc = 1.0f / (float)(d > 0 ? d : 1);
        v.x += sx * sc; v.y += sy * sc;
    }
    *reinterpret_cast<float2*>(&out[(size_t)n * 2]) = v;
}

extern "C" void kernel_launch(void* const* d_in, const int* in_sizes, int n_in,
                              void* d_out, int out_size, void* d_ws, size_t ws_size,
                              hipStream_t stream)
{
    const float* x_tx = (const float*)d_in[0];
    const float* x_ad = (const float*)d_in[1];
    const float* Wl0  = (const float*)d_in[2];
    const float* bl0  = (const float*)d_in[3];
    const float* Wr0  = (const float*)d_in[4];
    const float* rel0 = (const float*)d_in[5];
    const float* Wl1  = (const float*)d_in[6];
    const float* bl1  = (const float*)d_in[7];
    const float* Wr1  = (const float*)d_in[8];
    const float* rel1 = (const float*)d_in[9];
    const int* e_tt = (const int*)d_in[10];
    const int* e_aa = (const int*)d_in[11];
    const int* e_at = (const int*)d_in[12];
    const int* e_ta = (const int*)d_in[13];

    const int N_tx = in_sizes[0] / 128;
    const int N_ad = in_sizes[1] / 128;
    const int E    = in_sizes[10] / 2;
    const int Nmax = N_tx > N_ad ? N_tx : N_ad;
    float* out = (float*)d_out;
    (void)n_in; (void)out_size;

    char* wsb = (char*)d_ws;
    size_t off_b = 0;
    auto wsalloc = [&](size_t bytes) -> void* {
        void* p = (void*)(wsb + off_b);
        off_b += (bytes + 255) & ~(size_t)255;
        return p;
    };
    int* cnt  = (int*)wsalloc(sizeof(int) * 4 * (size_t)Nmax);
    int* cur  = (int*)wsalloc(sizeof(int) * 4 * (size_t)Nmax);
    int* offs = (int*)wsalloc(sizeof(int) * 4 * ((size_t)Nmax + 1));
    int* lst  = (int*)wsalloc(sizeof(int) * 4 * (size_t)E);
    uint16_t* xbf_tx = (uint16_t*)wsalloc(sizeof(uint16_t) * (size_t)N_tx * 128);
    uint16_t* xbf_ad = (uint16_t*)wsalloc(sizeof(uint16_t) * (size_t)N_ad * 128);
    uint16_t* bufA = (uint16_t*)wsalloc(sizeof(uint16_t) * (size_t)Nmax * 128);
    uint16_t* bufB = (uint16_t*)wsalloc(sizeof(uint16_t) * (size_t)Nmax * 128);
    uint16_t* h_tx = (uint16_t*)wsalloc(sizeof(uint16_t) * (size_t)N_tx * 128);
    uint16_t* h_ad = (uint16_t*)wsalloc(sizeof(uint16_t) * (size_t)N_ad * 128);
    uint16_t* Wt   = (uint16_t*)wsalloc(sizeof(uint16_t) * 2 * 2 * 128 * 200);
    float* b0c  = (float*)wsalloc(sizeof(float) * 2 * 128);
    float* Pm   = (float*)wsalloc(sizeof(float) * 2 * 128 * 6);
    float* b1c  = (float*)wsalloc(sizeof(float) * 4);
    float* p_tt = (float*)wsalloc(sizeof(float) * (size_t)N_tx * 2);
    float* p_ta = (float*)wsalloc(sizeof(float) * (size_t)N_tx * 2);
    float* p_aa = (float*)wsalloc(sizeof(float) * (size_t)N_ad * 2);
    float* p_at = (float*)wsalloc(sizeof(float) * (size_t)N_ad * 2);
    float* r_tx = (float*)wsalloc(sizeof(float) * (size_t)N_tx * 2);
    float* r_ad = (float*)wsalloc(sizeof(float) * (size_t)N_ad * 2);
    int* bhist = (int*)wsalloc(sizeof(int) * 4 * NBMAX);
    int* bbase = (int*)wsalloc(sizeof(int) * 4 * (NBMAX + 1));
    int* gcur  = (int*)wsalloc(sizeof(int) * 4 * NBMAX);
    if (off_b > ws_size) return;
    size_t need_pairs = off_b + ((sizeof(uint32_t) * 4 * (size_t)E + 255) & ~(size_t)255);
    uint32_t* pairs = (need_pairs <= ws_size && Nmax <= (NBMAX << BUCKET_SH))
                    ? (uint32_t*)wsalloc(sizeof(uint32_t) * 4 * (size_t)E) : nullptr;

    const int* offT[4] = { offs, offs + (size_t)(Nmax + 1), offs + 2 * (size_t)(Nmax + 1),
                           offs + 3 * (size_t)(Nmax + 1) };
    int* lstT[4] = { lst, lst + (size_t)E, lst + 2 * (size_t)E, lst + 3 * (size_t)E };

    // 1. prep (weights, biases, P, b1c, zero bhist)
    {
        const int total = 2 * 128 * 384 + 1796 + 4 * NBMAX;
        k_prep<<<(total + 255) / 256, 256, 0, stream>>>(Wl0, bl0, Wr0, rel0,
                                                        Wl1, bl1, Wr1, rel1,
                                                        Wt, b0c, Pm, b1c, bhist);
    }
    // 2. bf16 feature tables (one dispatch)
    {
        const int n8t = N_tx * 16, n8a = N_ad * 16;
        const int gx = ((n8t > n8a ? n8t : n8a) + 255) / 256;
        k_cvt2<<<dim3(gx, 2), 256, 0, stream>>>(x_tx, xbf_tx, n8t, x_ad, xbf_ad, n8a);
    }
    // 3. CSR build
    if (pairs) {
        const int gEb = (E + 2047) / 2048;
        k_bhist<<<dim3(gEb, 4), 256, 0, stream>>>(e_tt + E, e_aa + E, e_at + E, e_ta + E,
                                                  bhist, E);
        k_bscan<<<1, 4, 0, stream>>>(bhist, bbase, gcur);
        k_bscatter<<<dim3(gEb, 4), 256, 0, stream>>>(e_tt, e_aa, e_at, e_ta,
                                                     gcur, pairs, E);
        k_bcsr<<<dim3(NBMAX, 4), 256, 0, stream>>>(pairs, bbase, offs, lst, Nmax, E,
                                                   N_tx, N_ad);
    } else {
        hipMemsetAsync(cnt, 0, sizeof(int) * 4 * (size_t)Nmax, stream);
        hipMemsetAsync(cur, 0, sizeof(int) * 4 * (size_t)Nmax, stream);
        const int gE = (E + 255) / 256;
        k_hist4<<<dim3(gE, 4), 256, 0, stream>>>(e_tt + E, e_aa + E, e_at + E, e_ta + E,
                                                 cnt, Nmax, E);
        k_scan<<<4, 1024, 0, stream>>>(cnt, offs, Nmax, N_tx, N_ad);
        k_fill4<<<dim3(gE, 4), 256, 0, stream>>>(e_tt, e_aa, e_at, e_ta,
                                                 offs, cur, lst, Nmax, E);
    }

    const int gAggTx = (N_tx + 3) / 4, gAggAd = (N_ad + 3) / 4;
    const int gMMTx = (N_tx + 127) / 128, gMMAd = (N_ad + 127) / 128;

    // 4. layer 0 — tx
    k_agg2<<<dim3(gAggTx, 2), 256, 0, stream>>>(xbf_tx, offT[0], lstT[0], bufA,
                                                xbf_ad, offT[2], lstT[2], bufB, N_tx);
    k_gemm_bf16<<<gMMTx, 256, 0, stream>>>(bufA, bufB, xbf_tx, Wt, b0c, h_tx, N_tx);
    // 5. layer 0 — addr
    k_agg2<<<dim3(gAggAd, 2), 256, 0, stream>>>(xbf_ad, offT[1], lstT[1], bufA,
                                                xbf_tx, offT[3], lstT[3], bufB, N_ad);
    k_gemm_bf16<<<gMMAd, 256, 0, stream>>>(bufA, bufB, xbf_ad, Wt + 2 * 128 * 200,
                                           b0c + 128, h_ad, N_ad);

    // 6. layer 1 projection (one dispatch)
    {
        const int gx = gAggTx > gAggAd ? gAggTx : gAggAd;
        k_proj2<<<dim3(gx, 2), 256, 0, stream>>>(h_tx, Pm, b1c, p_tt, p_ta, r_tx, N_tx,
                                                 h_ad, Pm + 768, b1c + 2, p_aa, p_at,
                                                 r_ad, N_ad);
    }
    // 7. final (one dispatch)
    {
        const int gx = ((N_tx > N_ad ? N_tx : N_ad) + 255) / 256;
        k_final2<<<dim3(gx, 2), 256, 0, stream>>>(
            r_tx, p_tt, offT[0], lstT[0], p_at, offT[2], lstT[2], out, N_tx,
            r_ad, p_aa, offT[1], lstT[1], p_ta, offT[3], lstT[3],
            out + (size_t)N_tx * 2, N_ad);
    }
}

// Round 8
// 543.341 us; speedup vs baseline: 6.6335x; 1.1834x over previous
//
#include <hip/hip_runtime.h>
#include <cstdint>

typedef __attribute__((ext_vector_type(4))) float f32x4;
typedef __attribute__((ext_vector_type(8))) short bf16x8;
typedef __attribute__((ext_vector_type(8))) uint16_t u16x8;

#define BUCKET_SH 10
#define NBMAX 128

static __device__ __forceinline__ float bf2f(uint16_t u) {
    union { uint32_t i; float f; } v; v.i = ((uint32_t)u) << 16; return v.f;
}
// round-to-nearest-even f32 -> bf16
static __device__ __forceinline__ uint16_t f2bf(float f) {
    uint32_t x = __float_as_uint(f);
    uint32_t r = (x + 0x7fffu + ((x >> 16) & 1u)) >> 16;
    return (uint16_t)r;
}

// ---------------- unified prep: Wt (bf16 transposed combined W0) + biases + P + b1c
//                  + zero bhist ------------------------------------------------------
__global__ void k_prep(const float* __restrict__ Wl0, const float* __restrict__ bl0,
                       const float* __restrict__ Wr0, const float* __restrict__ rel0,
                       const float* __restrict__ Wl1, const float* __restrict__ bl1,
                       const float* __restrict__ Wr1, const float* __restrict__ rel1,
                       uint16_t* __restrict__ Wt, float* __restrict__ b0c,
                       float* __restrict__ P, float* __restrict__ b1c,
                       int* __restrict__ bhist)
{
    float rw0[4], rw1[4];
    {
        float m0 = fmaxf(fmaxf(rel0[0], rel0[1]), fmaxf(rel0[2], rel0[3]));
        float m1 = fmaxf(fmaxf(rel1[0], rel1[1]), fmaxf(rel1[2], rel1[3]));
        float s0 = 0.f, s1 = 0.f;
        #pragma unroll
        for (int c = 0; c < 4; ++c) {
            rw0[c] = expf(rel0[c] - m0); s0 += rw0[c];
            rw1[c] = expf(rel1[c] - m1); s1 += rw1[c];
        }
        #pragma unroll
        for (int c = 0; c < 4; ++c) { rw0[c] /= s0; rw1[c] /= s1; }
    }
    const int i = blockIdx.x * blockDim.x + threadIdx.x;
    const int NWT = 2 * 128 * 384;
    if (i < NWT) {
        const int side = i / 49152;
        const int rem  = i % 49152;
        const int col = rem / 384, k = rem % 384;
        const int tA = side ? 1 : 0, tB = side ? 3 : 2;
        float v;
        if (k < 128)      v = rw0[tA] * Wl0[tA * 16384 + k * 128 + col];
        else if (k < 256) v = rw0[tB] * Wl0[tB * 16384 + (k - 128) * 128 + col];
        else              v = rw0[tA] * Wr0[tA * 16384 + (k - 256) * 128 + col]
                            + rw0[tB] * Wr0[tB * 16384 + (k - 256) * 128 + col];
        const int half = (k >= 192) ? 1 : 0;
        Wt[((size_t)(side * 2 + half) * 128 + col) * 200 + (k - half * 192)] = f2bf(v);
        return;
    }
    const int j = i - NWT;
    if (j < 256) {
        int side = j / 128, col = j % 128;
        int tA = side ? 1 : 0, tB = side ? 3 : 2;
        b0c[j] = rw0[tA] * bl0[tA * 128 + col] + rw0[tB] * bl0[tB * 128 + col];
    } else if (j < 256 + 1536) {
        int ip = j - 256;
        int side = ip / 768, rem = ip % 768;
        int k = rem / 6, c = rem % 6;
        float v;
        if (side == 0) {
            if (c < 2)      v = rw1[0] * Wl1[0 * 256 + k * 2 + c];
            else if (c < 4) v = rw1[3] * Wl1[3 * 256 + k * 2 + (c - 2)];
            else            v = rw1[0] * Wr1[0 * 256 + k * 2 + (c - 4)]
                              + rw1[2] * Wr1[2 * 256 + k * 2 + (c - 4)];
        } else {
            if (c < 2)      v = rw1[1] * Wl1[1 * 256 + k * 2 + c];
            else if (c < 4) v = rw1[2] * Wl1[2 * 256 + k * 2 + (c - 2)];
            else            v = rw1[1] * Wr1[1 * 256 + k * 2 + (c - 4)]
                              + rw1[3] * Wr1[3 * 256 + k * 2 + (c - 4)];
        }
        P[ip] = v;
    } else if (j < 1792 + 4) {
        int i4 = j - 1792;
        int side = i4 / 2, c = i4 % 2;
        b1c[i4] = side ? (rw1[1] * bl1[1 * 2 + c] + rw1[3] * bl1[3 * 2 + c])
                       : (rw1[0] * bl1[0 * 2 + c] + rw1[2] * bl1[2 * 2 + c]);
    } else if (j < 1796 + 4 * NBMAX) {
        bhist[j - 1796] = 0;
    }
}

// ---------------- fp32 -> bf16 table conversion, both tables in one dispatch -----------
__global__ void k_cvt2(const float* __restrict__ xA, uint16_t* __restrict__ yA, int n8A,
                       const float* __restrict__ xB, uint16_t* __restrict__ yB, int n8B)
{
    const float* x; uint16_t* y; int n8;
    if (blockIdx.y == 0) { x = xA; y = yA; n8 = n8A; }
    else                 { x = xB; y = yB; n8 = n8B; }
    const int i = blockIdx.x * blockDim.x + threadIdx.x;
    if (i >= n8) return;
    const float4* p = reinterpret_cast<const float4*>(x + (size_t)i * 8);
    float4 a = p[0], b = p[1];
    u16x8 o;
    o[0] = f2bf(a.x); o[1] = f2bf(a.y); o[2] = f2bf(a.z); o[3] = f2bf(a.w);
    o[4] = f2bf(b.x); o[5] = f2bf(b.y); o[6] = f2bf(b.z); o[7] = f2bf(b.w);
    *reinterpret_cast<u16x8*>(y + (size_t)i * 8) = o;
}

// ================= bucket-sorted CSR build =================
__global__ void k_bhist(const int* __restrict__ d0, const int* __restrict__ d1,
                        const int* __restrict__ d2, const int* __restrict__ d3,
                        int* __restrict__ bhist, int E)
{
    const int t = blockIdx.y;
    const int* dst = t == 0 ? d0 : (t == 1 ? d1 : (t == 2 ? d2 : d3));
    __shared__ int h[NBMAX];
    const int tid = threadIdx.x;
    if (tid < NBMAX) h[tid] = 0;
    __syncthreads();
    const int base = blockIdx.x * 2048;
    #pragma unroll
    for (int q = 0; q < 8; ++q) {
        const int i = base + q * 256 + tid;
        if (i < E) atomicAdd(&h[dst[i] >> BUCKET_SH], 1);
    }
    __syncthreads();
    if (tid < NBMAX && h[tid]) atomicAdd(&bhist[t * NBMAX + tid], h[tid]);
}

__global__ void k_bscan(const int* __restrict__ bhist, int* __restrict__ bbase,
                        int* __restrict__ gcur)
{
    const int t = threadIdx.x;
    if (t >= 4) return;
    int run = 0;
    for (int b = 0; b < NBMAX; ++b) {
        bbase[t * (NBMAX + 1) + b] = run;
        gcur[t * NBMAX + b] = run;
        run += bhist[t * NBMAX + b];
    }
    bbase[t * (NBMAX + 1) + NBMAX] = run;
}

__global__ void k_bscatter(const int* __restrict__ e0, const int* __restrict__ e1,
                           const int* __restrict__ e2, const int* __restrict__ e3,
                           int* __restrict__ gcur, uint32_t* __restrict__ pairs, int E)
{
    const int t = blockIdx.y;
    const int* ep = t == 0 ? e0 : (t == 1 ? e1 : (t == 2 ? e2 : e3));
    __shared__ int rank[NBMAX];
    __shared__ int chunk[NBMAX];
    const int tid = threadIdx.x;
    if (tid < NBMAX) rank[tid] = 0;
    __syncthreads();
    const int base = blockIdx.x * 2048;
    int s[8], d[8], r[8], b[8];
    #pragma unroll
    for (int q = 0; q < 8; ++q) {
        const int i = base + q * 256 + tid;
        if (i < E) {
            s[q] = ep[i];
            d[q] = ep[E + i];
            b[q] = d[q] >> BUCKET_SH;
            r[q] = atomicAdd(&rank[b[q]], 1);
        } else b[q] = -1;
    }
    __syncthreads();
    if (tid < NBMAX && rank[tid]) chunk[tid] = atomicAdd(&gcur[t * NBMAX + tid], rank[tid]);
    __syncthreads();
    #pragma unroll
    for (int q = 0; q < 8; ++q) {
        if (b[q] >= 0)
            pairs[(size_t)t * E + chunk[b[q]] + r[q]] =
                ((uint32_t)s[q] << BUCKET_SH) | ((uint32_t)d[q] & ((1u << BUCKET_SH) - 1));
    }
}

// FUSED per-bucket CSR: count (LDS) -> in-LDS scan -> write off -> place lst.
__global__ void k_bcsr(const uint32_t* __restrict__ pairs, const int* __restrict__ bbase,
                       int* __restrict__ off, int* __restrict__ lst,
                       int Nmax, int E, int N_tx, int N_ad)
{
    const int t = blockIdx.y, b = blockIdx.x;
    const int Nt = (t & 1) ? N_ad : N_tx;
    const int dlo = b << BUCKET_SH;
    if (dlo >= Nt) return;
    __shared__ int h[1 << BUCKET_SH];
    __shared__ int wtot[4];
    __shared__ int woff[4];
    const int tid = threadIdx.x;
    const int lane = tid & 63, wv = tid >> 6;
    #pragma unroll
    for (int q = 0; q < 4; ++q) h[tid + q * 256] = 0;
    __syncthreads();
    const int i0 = bbase[t * (NBMAX + 1) + b], i1 = bbase[t * (NBMAX + 1) + b + 1];
    const uint32_t* pr = pairs + (size_t)t * E;
    for (int i = i0 + tid; i < i1; i += 256)
        atomicAdd(&h[pr[i] & ((1u << BUCKET_SH) - 1)], 1);
    __syncthreads();
    const int a0 = h[tid * 4 + 0], a1 = h[tid * 4 + 1],
              a2 = h[tid * 4 + 2], a3 = h[tid * 4 + 3];
    const int s = a0 + a1 + a2 + a3;
    int incl = s;
    #pragma unroll
    for (int sh = 1; sh < 64; sh <<= 1) {
        int u = __shfl_up(incl, sh, 64);
        if (lane >= sh) incl += u;
    }
    if (lane == 63) wtot[wv] = incl;
    __syncthreads();
    if (tid == 0) {
        int r = 0;
        #pragma unroll
        for (int w = 0; w < 4; ++w) { woff[w] = r; r += wtot[w]; }
    }
    __syncthreads();
    const int excl = woff[wv] + incl - s;
    const int o0 = i0 + excl, o1 = o0 + a0, o2 = o1 + a1, o3 = o2 + a2;
    const int lim = min(1 << BUCKET_SH, Nt - dlo);
    int* offT = off + (size_t)t * (Nmax + 1) + dlo;
    const int base4 = tid * 4;
    if (base4 + 0 < lim) offT[base4 + 0] = o0;
    if (base4 + 1 < lim) offT[base4 + 1] = o1;
    if (base4 + 2 < lim) offT[base4 + 2] = o2;
    if (base4 + 3 < lim) offT[base4 + 3] = o3;
    if (tid == 0 && dlo + lim == Nt)
        off[(size_t)t * (Nmax + 1) + Nt] = bbase[t * (NBMAX + 1) + NBMAX];
    h[base4 + 0] = o0 - i0; h[base4 + 1] = o1 - i0;
    h[base4 + 2] = o2 - i0; h[base4 + 3] = o3 - i0;
    __syncthreads();
    int* lstT = lst + (size_t)t * E;
    for (int i = i0 + tid; i < i1; i += 256) {
        const uint32_t p = pr[i];
        const int dl = (int)(p & ((1u << BUCKET_SH) - 1));
        const int pos = atomicAdd(&h[dl], 1);
        lstT[i0 + pos] = (int)(p >> BUCKET_SH);
    }
}

// ---------------- fallback CSR build ---------------------------------------------------
__global__ void k_hist4(const int* __restrict__ d0, const int* __restrict__ d1,
                        const int* __restrict__ d2, const int* __restrict__ d3,
                        int* __restrict__ cnt, int Nmax, int E)
{
    const int t = blockIdx.y;
    const int* dst = t == 0 ? d0 : (t == 1 ? d1 : (t == 2 ? d2 : d3));
    const int i = blockIdx.x * blockDim.x + threadIdx.x;
    if (i < E) atomicAdd(&cnt[(size_t)t * Nmax + dst[i]], 1);
}

__global__ void k_fill4(const int* __restrict__ e0, const int* __restrict__ e1,
                        const int* __restrict__ e2, const int* __restrict__ e3,
                        const int* __restrict__ off, int* __restrict__ cur,
                        int* __restrict__ lst, int Nmax, int E)
{
    const int t = blockIdx.y;
    const int* ep = t == 0 ? e0 : (t == 1 ? e1 : (t == 2 ? e2 : e3));
    const int i = blockIdx.x * blockDim.x + threadIdx.x;
    if (i < E) {
        const int s = ep[i];
        const int d = ep[E + i];
        const int p = atomicAdd(&cur[(size_t)t * Nmax + d], 1);
        lst[(size_t)t * E + off[(size_t)t * (Nmax + 1) + d] + p] = s;
    }
}

__global__ void k_scan(const int* __restrict__ cnt, int* __restrict__ off,
                       int Nmax, int N_tx, int N_ad)
{
    const int t = blockIdx.x;
    const int N = (t & 1) ? N_ad : N_tx;
    cnt += (size_t)t * Nmax;
    off += (size_t)t * (Nmax + 1);
    const int tid = threadIdx.x;
    const int lane = tid & 63, wv = tid >> 6;
    __shared__ int wtot[16];
    __shared__ int woff[16];
    __shared__ int running;
    if (tid == 0) running = 0;
    __syncthreads();
    for (int base = 0; base < N; base += 1024) {
        int i = base + tid;
        int v = (i < N) ? cnt[i] : 0;
        int incl = v;
        #pragma unroll
        for (int s = 1; s < 64; s <<= 1) {
            int u = __shfl_up(incl, s, 64);
            if (lane >= s) incl += u;
        }
        if (lane == 63) wtot[wv] = incl;
        __syncthreads();
        if (tid == 0) {
            int r = running;
            #pragma unroll
            for (int w = 0; w < 16; ++w) { woff[w] = r; r += wtot[w]; }
            running = r;
        }
        __syncthreads();
        if (i < N) off[i] = woff[wv] + incl - v;
        __syncthreads();
    }
    if (tid == 0) off[N] = running;
}

// ---------------- mean aggregation, ALL 4 edge types in one dispatch -------------------
// y: 0=tt(x_tx->N_tx), 1=at(x_ad->N_tx), 2=aa(x_ad->N_ad), 3=ta(x_tx->N_ad).
// CSR type index: {0,2,1,3}. 16B gathers, 16 lanes/edge, 4 edges/iter.
// At the random-256B-read ceiling (~3.6 TB/s L2-fill) — measured identical across
// two different inner-loop shapes (R6/R7).
__global__ void k_agg4(const uint16_t* __restrict__ x_tx, const uint16_t* __restrict__ x_ad,
                       const int* __restrict__ offs, const int* __restrict__ lst,
                       uint16_t* __restrict__ bufs, int Nmax, int E,
                       int N_tx, int N_ad)
{
    const int y = blockIdx.y;
    const int csr_t = (y == 0) ? 0 : (y == 1) ? 2 : (y == 2) ? 1 : 3;
    const uint16_t* x = (y == 0 || y == 3) ? x_tx : x_ad;
    const int N = (y < 2) ? N_tx : N_ad;
    const int* off = offs + (size_t)csr_t * (Nmax + 1);
    const int* lstT = lst + (size_t)csr_t * E;
    uint16_t* buf = bufs + (size_t)y * Nmax * 128;

    const int wv = threadIdx.x >> 6;
    const int lane = threadIdx.x & 63;
    const int node = blockIdx.x * 4 + wv;
    if (node >= N) return;
    const int s0 = off[node], s1 = off[node + 1];
    const int grp = lane >> 4;
    const int sub = lane & 15;
    float acc[8];
    #pragma unroll
    for (int k = 0; k < 8; ++k) acc[k] = 0.f;

    for (int base = s0; base < s1; base += 64) {
        const int cnt = min(64, s1 - base);
        int idx = 0;
        if (lane < cnt) idx = lstT[base + lane];
        for (int j = 0; j < cnt; j += 4) {
            const int e = j + grp;
            const int srcn = __shfl(idx, e);
            if (e < cnt) {
                const uint4 u = *reinterpret_cast<const uint4*>(
                    x + ((size_t)srcn << 7) + (sub << 3));
                acc[0] += __uint_as_float(u.x << 16);
                acc[1] += __uint_as_float(u.x & 0xffff0000u);
                acc[2] += __uint_as_float(u.y << 16);
                acc[3] += __uint_as_float(u.y & 0xffff0000u);
                acc[4] += __uint_as_float(u.z << 16);
                acc[5] += __uint_as_float(u.z & 0xffff0000u);
                acc[6] += __uint_as_float(u.w << 16);
                acc[7] += __uint_as_float(u.w & 0xffff0000u);
            }
        }
    }
    #pragma unroll
    for (int k = 0; k < 8; ++k) {
        acc[k] += __shfl_xor(acc[k], 16, 64);
        acc[k] += __shfl_xor(acc[k], 32, 64);
    }
    const int deg = s1 - s0;
    const float sc = 1.0f / (float)(deg > 0 ? deg : 1);
    if (lane < 16) {
        uint4 w;
        w.x = (uint32_t)f2bf(acc[0] * sc) | ((uint32_t)f2bf(acc[1] * sc) << 16);
        w.y = (uint32_t)f2bf(acc[2] * sc) | ((uint32_t)f2bf(acc[3] * sc) << 16);
        w.z = (uint32_t)f2bf(acc[4] * sc) | ((uint32_t)f2bf(acc[5] * sc) << 16);
        w.w = (uint32_t)f2bf(acc[6] * sc) | ((uint32_t)f2bf(acc[7] * sc) << 16);
        *reinterpret_cast<uint4*>(buf + ((size_t)node << 7) + (sub << 3)) = w;
    }
}

// ---------------- MFMA GEMM + FUSED layer-1 projection ---------------------------------
// y selects side (0=tx, 1=addr). Computes hv = relu([A0|A1|A2]@W + bias) per row in
// registers, then o[6] = hv @ P (16-lane shfl_xor reduce) -> writes pA/pB/r directly.
// h is never materialized (R7 wrote 25.6MB + re-read it per side).
__global__ __launch_bounds__(256, 2) void k_gemmproj(
    const uint16_t* __restrict__ bufs, const uint16_t* __restrict__ x_tx,
    const uint16_t* __restrict__ x_ad, const uint16_t* __restrict__ Wt,
    const float* __restrict__ b0c, const float* __restrict__ Pm,
    const float* __restrict__ b1c,
    float* __restrict__ p_tt, float* __restrict__ p_ta, float* __restrict__ r_tx,
    float* __restrict__ p_aa, float* __restrict__ p_at, float* __restrict__ r_ad,
    int Nmax, int N_tx, int N_ad)
{
    const int side = blockIdx.y;
    const int N = side ? N_ad : N_tx;
    if (blockIdx.x * 128 >= N) return;
    const uint16_t* A0 = bufs + (size_t)(side ? 2 : 0) * Nmax * 128;
    const uint16_t* A1 = bufs + (size_t)(side ? 3 : 1) * Nmax * 128;
    const uint16_t* A2 = side ? x_ad : x_tx;
    const uint16_t* W  = Wt + (size_t)side * 2 * 128 * 200;
    const float* bias = b0c + side * 128;
    const float* P    = Pm + side * 768;
    float* pA = side ? p_aa : p_tt;
    float* pB = side ? p_at : p_ta;
    float* rr = side ? r_ad : r_tx;
    const float b2x = b1c[side * 2 + 0], b2y = b1c[side * 2 + 1];

    __shared__ uint16_t Wlds[128 * 200];
    __shared__ float Plds[768];
    const int tid = threadIdx.x;
    const int wv = tid >> 6, lane = tid & 63;
    const int l15 = lane & 15, lg = lane >> 4;
    const int wrow = blockIdx.x * 128 + wv * 32;

    f32x4 acc[2][8];
    #pragma unroll
    for (int a = 0; a < 2; ++a)
        #pragma unroll
        for (int b = 0; b < 8; ++b) acc[a][b] = (f32x4){0.f, 0.f, 0.f, 0.f};

    const uint16_t* const Aslot[3] = { A0, A1, A2 };

    #pragma unroll 1
    for (int half = 0; half < 2; ++half) {
        __syncthreads();
        const char* src = (const char*)(W + (size_t)half * 25600);
        char* dstbase = (char*)Wlds + wv * 1024;
        #pragma unroll
        for (int it = 0; it < 13; ++it) {
            const int off = it * 4096 + tid * 16;
            if (off < 51200)
                __builtin_amdgcn_global_load_lds((const uint32_t*)(src + off),
                                                 (uint32_t*)(dstbase + it * 4096),
                                                 16, 0, 0);
        }
        asm volatile("s_waitcnt vmcnt(0)" ::: "memory");
        __syncthreads();
        #pragma unroll
        for (int ks = 0; ks < 6; ++ks) {
            const int kg = half * 192 + ks * 32;
            const uint16_t* Ap = Aslot[kg >> 7];
            const int kl = (kg & 127) + lg * 8;
            const int r0 = wrow + l15;
            const int r1 = r0 + 16;
            const int c0 = (r0 < N) ? r0 : (N - 1);
            const int c1 = (r1 < N) ? r1 : (N - 1);
            const bf16x8 af0 = *reinterpret_cast<const bf16x8*>(Ap + (size_t)c0 * 128 + kl);
            const bf16x8 af1 = *reinterpret_cast<const bf16x8*>(Ap + (size_t)c1 * 128 + kl);
            #pragma unroll
            for (int cb = 0; cb < 8; ++cb) {
                const bf16x8 bf = *reinterpret_cast<const bf16x8*>(
                    Wlds + (size_t)(cb * 16 + l15) * 200 + ks * 32 + lg * 8);
                acc[0][cb] = __builtin_amdgcn_mfma_f32_16x16x32_bf16(af0, bf, acc[0][cb], 0, 0, 0);
                acc[1][cb] = __builtin_amdgcn_mfma_f32_16x16x32_bf16(af1, bf, acc[1][cb], 0, 0, 0);
            }
        }
    }
    // ---- fused epilogue: bias+relu -> project to 6 dims -> reduce -> store ----
    __syncthreads();
    #pragma unroll
    for (int q = 0; q < 3; ++q) {
        const int idx = q * 256 + tid;
        Plds[idx] = P[idx];
    }
    __syncthreads();
    float bias_v[8];
    #pragma unroll
    for (int cb = 0; cb < 8; ++cb) bias_v[cb] = bias[cb * 16 + l15];

    #pragma unroll
    for (int rb = 0; rb < 2; ++rb) {
        #pragma unroll
        for (int r = 0; r < 4; ++r) {
            const int row = wrow + rb * 16 + lg * 4 + r;
            float o0 = 0.f, o1 = 0.f, o2 = 0.f, o3 = 0.f, o4 = 0.f, o5 = 0.f;
            #pragma unroll
            for (int cb = 0; cb < 8; ++cb) {
                const float hv = fmaxf(acc[rb][cb][r] + bias_v[cb], 0.f);
                const float* Pr = &Plds[(cb * 16 + l15) * 6];
                o0 += hv * Pr[0]; o1 += hv * Pr[1]; o2 += hv * Pr[2];
                o3 += hv * Pr[3]; o4 += hv * Pr[4]; o5 += hv * Pr[5];
            }
            #pragma unroll
            for (int m = 1; m <= 8; m <<= 1) {
                o0 += __shfl_xor(o0, m, 64); o1 += __shfl_xor(o1, m, 64);
                o2 += __shfl_xor(o2, m, 64); o3 += __shfl_xor(o3, m, 64);
                o4 += __shfl_xor(o4, m, 64); o5 += __shfl_xor(o5, m, 64);
            }
            if (l15 == 0 && row < N) {
                *reinterpret_cast<float2*>(&pA[(size_t)row * 2]) = make_float2(o0, o1);
                *reinterpret_cast<float2*>(&pB[(size_t)row * 2]) = make_float2(o2, o3);
                *reinterpret_cast<float2*>(&rr[(size_t)row * 2]) = make_float2(o4 + b2x, o5 + b2y);
            }
        }
    }
}

// ---------------- final (both sides, y selects) ----------------------------------------
__global__ void k_final2(const float* __restrict__ rA,
                         const float* __restrict__ pAA, const int* __restrict__ offAA,
                         const int* __restrict__ lstAA,
                         const float* __restrict__ pBA, const int* __restrict__ offBA,
                         const int* __restrict__ lstBA, float* __restrict__ outA, int NA,
                         const float* __restrict__ rB,
                         const float* __restrict__ pAB, const int* __restrict__ offAB,
                         const int* __restrict__ lstAB,
                         const float* __restrict__ pBB, const int* __restrict__ offBB,
                         const int* __restrict__ lstBB, float* __restrict__ outB, int NB)
{
    const float* r; const float* pA; const int* offA; const int* lstA;
    const float* pB; const int* offB; const int* lstB; float* out; int N;
    if (blockIdx.y == 0) { r = rA; pA = pAA; offA = offAA; lstA = lstAA;
                           pB = pBA; offB = offBA; lstB = lstBA; out = outA; N = NA; }
    else                 { r = rB; pA = pAB; offA = offAB; lstA = lstAB;
                           pB = pBB; offB = offBB; lstB = lstBB; out = outB; N = NB; }
    const int n = blockIdx.x * blockDim.x + threadIdx.x;
    if (n >= N) return;
    float2 v = *reinterpret_cast<const float2*>(&r[(size_t)n * 2]);
    {
        int s0 = offA[n], s1 = offA[n + 1];
        float sx = 0.f, sy = 0.f;
        for (int e = s0; e < s1; ++e) {
            float2 p = *reinterpret_cast<const float2*>(&pA[(size_t)lstA[e] * 2]);
            sx += p.x; sy += p.y;
        }
        int d = s1 - s0; float sc = 1.0f / (float)(d > 0 ? d : 1);
        v.x += sx * sc; v.y += sy * sc;
    }
    {
        int s0 = offB[n], s1 = offB[n + 1];
        float sx = 0.f, sy = 0.f;
        for (int e = s0; e < s1; ++e) {
            float2 p = *reinterpret_cast<const float2*>(&pB[(size_t)lstB[e] * 2]);
            sx += p.x; sy += p.y;
        }
        int d = s1 - s0; float sc = 1.0f / (float)(d > 0 ? d : 1);
        v.x += sx * sc; v.y += sy * sc;
    }
    *reinterpret_cast<float2*>(&out[(size_t)n * 2]) = v;
}

extern "C" void kernel_launch(void* const* d_in, const int* in_sizes, int n_in,
                              void* d_out, int out_size, void* d_ws, size_t ws_size,
                              hipStream_t stream)
{
    const float* x_tx = (const float*)d_in[0];
    const float* x_ad = (const float*)d_in[1];
    const float* Wl0  = (const float*)d_in[2];
    const float* bl0  = (const float*)d_in[3];
    const float* Wr0  = (const float*)d_in[4];
    const float* rel0 = (const float*)d_in[5];
    const float* Wl1  = (const float*)d_in[6];
    const float* bl1  = (const float*)d_in[7];
    const float* Wr1  = (const float*)d_in[8];
    const float* rel1 = (const float*)d_in[9];
    const int* e_tt = (const int*)d_in[10];
    const int* e_aa = (const int*)d_in[11];
    const int* e_at = (const int*)d_in[12];
    const int* e_ta = (const int*)d_in[13];

    const int N_tx = in_sizes[0] / 128;
    const int N_ad = in_sizes[1] / 128;
    const int E    = in_sizes[10] / 2;
    const int Nmax = N_tx > N_ad ? N_tx : N_ad;
    float* out = (float*)d_out;
    (void)n_in; (void)out_size;

    char* wsb = (char*)d_ws;
    size_t off_b = 0;
    auto wsalloc = [&](size_t bytes) -> void* {
        void* p = (void*)(wsb + off_b);
        off_b += (bytes + 255) & ~(size_t)255;
        return p;
    };
    int* cnt  = (int*)wsalloc(sizeof(int) * 4 * (size_t)Nmax);
    int* cur  = (int*)wsalloc(sizeof(int) * 4 * (size_t)Nmax);
    int* offs = (int*)wsalloc(sizeof(int) * 4 * ((size_t)Nmax + 1));
    int* lst  = (int*)wsalloc(sizeof(int) * 4 * (size_t)E);
    uint16_t* xbf_tx = (uint16_t*)wsalloc(sizeof(uint16_t) * (size_t)N_tx * 128);
    uint16_t* xbf_ad = (uint16_t*)wsalloc(sizeof(uint16_t) * (size_t)N_ad * 128);
    uint16_t* bufs   = (uint16_t*)wsalloc(sizeof(uint16_t) * 4 * (size_t)Nmax * 128);
    uint16_t* Wt   = (uint16_t*)wsalloc(sizeof(uint16_t) * 2 * 2 * 128 * 200);
    float* b0c  = (float*)wsalloc(sizeof(float) * 2 * 128);
    float* Pm   = (float*)wsalloc(sizeof(float) * 2 * 128 * 6);
    float* b1c  = (float*)wsalloc(sizeof(float) * 4);
    float* p_tt = (float*)wsalloc(sizeof(float) * (size_t)N_tx * 2);
    float* p_ta = (float*)wsalloc(sizeof(float) * (size_t)N_tx * 2);
    float* p_aa = (float*)wsalloc(sizeof(float) * (size_t)N_ad * 2);
    float* p_at = (float*)wsalloc(sizeof(float) * (size_t)N_ad * 2);
    float* r_tx = (float*)wsalloc(sizeof(float) * (size_t)N_tx * 2);
    float* r_ad = (float*)wsalloc(sizeof(float) * (size_t)N_ad * 2);
    int* bhist = (int*)wsalloc(sizeof(int) * 4 * NBMAX);
    int* bbase = (int*)wsalloc(sizeof(int) * 4 * (NBMAX + 1));
    int* gcur  = (int*)wsalloc(sizeof(int) * 4 * NBMAX);
    if (off_b > ws_size) return;
    size_t need_pairs = off_b + ((sizeof(uint32_t) * 4 * (size_t)E + 255) & ~(size_t)255);
    uint32_t* pairs = (need_pairs <= ws_size && Nmax <= (NBMAX << BUCKET_SH))
                    ? (uint32_t*)wsalloc(sizeof(uint32_t) * 4 * (size_t)E) : nullptr;

    const int* offT[4] = { offs, offs + (size_t)(Nmax + 1), offs + 2 * (size_t)(Nmax + 1),
                           offs + 3 * (size_t)(Nmax + 1) };
    int* lstT[4] = { lst, lst + (size_t)E, lst + 2 * (size_t)E, lst + 3 * (size_t)E };

    // 1. prep
    {
        const int total = 2 * 128 * 384 + 1796 + 4 * NBMAX;
        k_prep<<<(total + 255) / 256, 256, 0, stream>>>(Wl0, bl0, Wr0, rel0,
                                                        Wl1, bl1, Wr1, rel1,
                                                        Wt, b0c, Pm, b1c, bhist);
    }
    // 2. bf16 feature tables
    {
        const int n8t = N_tx * 16, n8a = N_ad * 16;
        const int gx = ((n8t > n8a ? n8t : n8a) + 255) / 256;
        k_cvt2<<<dim3(gx, 2), 256, 0, stream>>>(x_tx, xbf_tx, n8t, x_ad, xbf_ad, n8a);
    }
    // 3. CSR build
    if (pairs) {
        const int gEb = (E + 2047) / 2048;
        k_bhist<<<dim3(gEb, 4), 256, 0, stream>>>(e_tt + E, e_aa + E, e_at + E, e_ta + E,
                                                  bhist, E);
        k_bscan<<<1, 4, 0, stream>>>(bhist, bbase, gcur);
        k_bscatter<<<dim3(gEb, 4), 256, 0, stream>>>(e_tt, e_aa, e_at, e_ta,
                                                     gcur, pairs, E);
        k_bcsr<<<dim3(NBMAX, 4), 256, 0, stream>>>(pairs, bbase, offs, lst, Nmax, E,
                                                   N_tx, N_ad);
    } else {
        hipMemsetAsync(cnt, 0, sizeof(int) * 4 * (size_t)Nmax, stream);
        hipMemsetAsync(cur, 0, sizeof(int) * 4 * (size_t)Nmax, stream);
        const int gE = (E + 255) / 256;
        k_hist4<<<dim3(gE, 4), 256, 0, stream>>>(e_tt + E, e_aa + E, e_at + E, e_ta + E,
                                                 cnt, Nmax, E);
        k_scan<<<4, 1024, 0, stream>>>(cnt, offs, Nmax, N_tx, N_ad);
        k_fill4<<<dim3(gE, 4), 256, 0, stream>>>(e_tt, e_aa, e_at, e_ta,
                                                 offs, cur, lst, Nmax, E);
    }

    // 4. all 4 aggregations, one dispatch
    {
        const int gx = ((N_tx > N_ad ? N_tx : N_ad) + 3) / 4;
        k_agg4<<<dim3(gx, 4), 256, 0, stream>>>(xbf_tx, xbf_ad, offs, lst, bufs,
                                                Nmax, E, N_tx, N_ad);
    }
    // 5. GEMM + fused layer-1 projection, both sides in one dispatch
    {
        const int gx = ((N_tx > N_ad ? N_tx : N_ad) + 127) / 128;
        k_gemmproj<<<dim3(gx, 2), 256, 0, stream>>>(bufs, xbf_tx, xbf_ad, Wt, b0c, Pm,
                                                    b1c, p_tt, p_ta, r_tx,
                                                    p_aa, p_at, r_ad,
                                                    Nmax, N_tx, N_ad);
    }
    // 6. final
    {
        const int gx = ((N_tx > N_ad ? N_tx : N_ad) + 255) / 256;
        k_final2<<<dim3(gx, 2), 256, 0, stream>>>(
            r_tx, p_tt, offT[0], lstT[0], p_at, offT[2], lstT[2], out, N_tx,
            r_ad, p_aa, offT[1], lstT[1], p_ta, offT[3], lstT[3],
            out + (size_t)N_tx * 2, N_ad);
    }
}